// Round 11
// baseline (190.513 us; speedup 1.0000x reference)
//
#include <hip/hip_runtime.h>
#include <hip/hip_bf16.h>
#include <stdint.h>

#define B_ 2
#define S_ 2048
#define D_ 2048
#define H_ 32
#define KV_ 8
#define HD_ 64
#define NQKV 3072   // D + 2*KV*HD

typedef __bf16 bf16_t;
typedef __bf16 bf16x8 __attribute__((ext_vector_type(8)));
typedef __bf16 bf16x4 __attribute__((ext_vector_type(4)));
typedef float  f32x4  __attribute__((ext_vector_type(4)));
typedef float  f32x16 __attribute__((ext_vector_type(16)));
typedef unsigned int u32;
typedef u32 u32x4 __attribute__((ext_vector_type(4)));

typedef const __attribute__((address_space(1))) uint32_t* gp1_t;
typedef __attribute__((address_space(3))) uint32_t* lp3_t;

// async global->LDS, 16B per lane. LDS dest is wave-uniform base + lane*16.
__device__ inline void gload_lds16(const void* g, void* l) {
  __builtin_amdgcn_global_load_lds((gp1_t)(uintptr_t)g, (lp3_t)(uint32_t)(uintptr_t)l,
                                   16, 0, 0);
}

__device__ inline u32 pkbf(float a, float b) {
  union { bf16_t h[2]; u32 u; } v;
  v.h[0] = (bf16_t)a; v.h[1] = (bf16_t)b;
  return v.u;
}

// v_permlane32_swap_b32: a = [a_lo, b_lo], b = [a_hi, b_hi]
__device__ inline void pl32swap(u32 &a, u32 &b) {
  asm("v_permlane32_swap_b32 %0, %1" : "+v"(a), "+v"(b));
}

// ---------------- converts ----------------
__global__ void cvt_f32_bf16(const float* __restrict__ in, bf16_t* __restrict__ out, int n4) {
  int i = blockIdx.x * blockDim.x + threadIdx.x;
  if (i < n4) {
    float4 v = ((const float4*)in)[i];
    bf16x4 o;
    o[0] = (bf16_t)v.x; o[1] = (bf16_t)v.y; o[2] = (bf16_t)v.z; o[3] = (bf16_t)v.w;
    ((bf16x4*)out)[i] = o;
  }
}

// transpose + cast: out[row_off + c][r] = in[r][c]
__global__ void transpose_cvt(const float* __restrict__ in, bf16_t* __restrict__ out,
                              int C, int row_off) {
  __shared__ float t[32][33];
  int tx = threadIdx.x, ty = threadIdx.y;       // (32,8)
  int c0 = blockIdx.x * 32, r0 = blockIdx.y * 32;
#pragma unroll
  for (int j = 0; j < 4; ++j)
    t[ty + j*8][tx] = in[(int64_t)(r0 + ty + j*8) * C + c0 + tx];
  __syncthreads();
#pragma unroll
  for (int j = 0; j < 4; ++j)
    out[(int64_t)(row_off + c0 + ty + j*8) * 2048 + r0 + tx] = (bf16_t)t[tx][ty + j*8];
}

// Vbuf[b][s][cc] -> Vt[b][cc][s]  (LDS-tiled transpose, coalesced both sides)
__global__ void v_transpose(const bf16_t* __restrict__ Vbuf, bf16_t* __restrict__ Vt) {
  __shared__ bf16_t t[32][34];
  const int tx = threadIdx.x, ty = threadIdx.y;   // (32,8)
  const int c0 = blockIdx.x * 32;                 // cc within 512
  const int s0 = blockIdx.y * 32;
  const int b  = blockIdx.z;
#pragma unroll
  for (int j = 0; j < 4; ++j)
    t[ty + j*8][tx] = Vbuf[(int64_t)(b * S_ + s0 + ty + j*8) * 512 + c0 + tx];
  __syncthreads();
#pragma unroll
  for (int j = 0; j < 4; ++j)
    Vt[(int64_t)(b * 512 + c0 + ty + j*8) * S_ + s0 + tx] = t[tx][ty + j*8];
}

// ---------------- 256-row phase-structured GEMM (8-phase-style schedule) ----------------
// BM=256, BK=64, 8 waves. Per K-tile: 4 quadrant-phases, each
// {ds_read frags | issue stage loads -> s_barrier -> lgkmcnt(0) -> MFMA -> s_barrier}.
// Quadrant order (0,0),(0,1),(1,1),(1,0): phase3 needs no LDS reads.
// Stage loads for tile t+1 all issue in phases 0-1; single vmcnt(0) at tile end
// (~2.5 phases after issue). Granule-XOR swizzle both sides (pre-swizzled source).
#define QSCALE 0.18033688011112042f
template <int BN, int EPI>
__global__ __launch_bounds__(512, 2) void gemm8p(const bf16_t* __restrict__ A,
                                                 const bf16_t* __restrict__ Bt,
                                                 const float* __restrict__ cosb,
                                                 const float* __restrict__ sinb,
                                                 bf16_t* __restrict__ Q,
                                                 bf16_t* __restrict__ Kr,
                                                 bf16_t* __restrict__ Vbuf,
                                                 float* __restrict__ Cout,
                                                 int N, int K) {
  constexpr int NB = BN / 64;          // B stage loads per tile
  constexpr int LT = 4 + NB;           // total stage loads per tile (8 or 6)
  constexpr int L0 = LT / 2;           // stage loads issued in phase 0
  constexpr int WCOLS = BN / 4;        // per-wave cols
  constexpr int NF = WCOLS / 16;       // per-wave n fragments (4 or 2)
  constexpr int NH = NF / 2;           // n frags per nh half (2 or 1)

  __shared__ bf16_t As[2][256 * 64];
  __shared__ bf16_t Bs[2][BN * 64];

  const int tid = threadIdx.x;
  const int w = tid >> 6, lane = tid & 63;
  const int l15 = lane & 15, l4 = lane >> 4;
  const int wr = w >> 2, wc = w & 3;
  const int bm = blockIdx.y * 256, bn = blockIdx.x * BN;

  // staging source (pre-swizzled): row = L*64 + w*8 + lane>>3; granule = (lane&7)^(row&7)
  const int rw = w * 8 + (lane >> 3);
  const int srcg = ((lane & 7) ^ ((lane >> 3) & 7)) << 3;   // element offset
  const bf16_t* PA[4];
  const bf16_t* PB[NB];
#pragma unroll
  for (int L = 0; L < 4; ++L)
    PA[L] = A + (int64_t)(bm + L * 64 + rw) * K + srcg;
#pragma unroll
  for (int L = 0; L < NB; ++L)
    PB[L] = Bt + (int64_t)(bn + L * 64 + rw) * K + srcg;

  const int NK = K >> 6;
  const int xr = l15 & 7;
  const int g0 = (l4 ^ xr) << 3;          // kk=0 slot, element offset
  const int g1 = ((4 + l4) ^ xr) << 3;    // kk=1 slot

  f32x4 acc[8][NF] = {};
  bf16x8 aH[4][2];                        // A frags, current mh half
  bf16x8 bAll[NF][2];                     // B frags, both nh halves (live whole tile)

  auto stage = [&](int s, int buf, int toff) {
    if (s < 4) gload_lds16(PA[s] + toff, &As[buf][s * 4096 + w * 512]);
    else       gload_lds16(PB[s - 4] + toff, &Bs[buf][(s - 4) * 4096 + w * 512]);
  };
  auto ldA = [&](const bf16_t* Ab, int mh) {
#pragma unroll
    for (int mm = 0; mm < 4; ++mm) {
      const int ra = wr * 128 + (mh * 4 + mm) * 16 + l15;
      aH[mm][0] = *(const bf16x8*)(Ab + ra * 64 + g0);
      aH[mm][1] = *(const bf16x8*)(Ab + ra * 64 + g1);
    }
  };
  auto ldB = [&](const bf16_t* Bb, int nh) {
#pragma unroll
    for (int nn = 0; nn < NH; ++nn) {
      const int rb = wc * WCOLS + (nh * NH + nn) * 16 + l15;
      bAll[nh * NH + nn][0] = *(const bf16x8*)(Bb + rb * 64 + g0);
      bAll[nh * NH + nn][1] = *(const bf16x8*)(Bb + rb * 64 + g1);
    }
  };
  auto mfma_quad = [&](int mh, int nh) {
    __builtin_amdgcn_s_setprio(1);
#pragma unroll
    for (int mm = 0; mm < 4; ++mm)
#pragma unroll
      for (int nn = 0; nn < NH; ++nn) {
        acc[mh*4+mm][nh*NH+nn] = __builtin_amdgcn_mfma_f32_16x16x32_bf16(
            aH[mm][0], bAll[nh*NH+nn][0], acc[mh*4+mm][nh*NH+nn], 0, 0, 0);
        acc[mh*4+mm][nh*NH+nn] = __builtin_amdgcn_mfma_f32_16x16x32_bf16(
            aH[mm][1], bAll[nh*NH+nn][1], acc[mh*4+mm][nh*NH+nn], 0, 0, 0);
      }
    __builtin_amdgcn_s_setprio(0);
  };
  auto wait_lds = [&]() {
    asm volatile("s_waitcnt lgkmcnt(0)" ::: "memory");
    __builtin_amdgcn_sched_barrier(0);    // rule #18: pin MFMA after the wait
  };

  // prologue: stage tile 0 into buf 0
#pragma unroll
  for (int s = 0; s < LT; ++s) stage(s, 0, 0);
  asm volatile("s_waitcnt vmcnt(0)" ::: "memory");
  __syncthreads();

  for (int t = 0; t < NK; ++t) {
    const int p = t & 1;
    const bool more = (t + 1) < NK;
    const int toff = (t + 1) << 6;
    const bf16_t* Ab = &As[p][0];
    const bf16_t* Bb = &Bs[p][0];

    // ---- phase 0: A[mh0] + B[nh0] reads | stage first half ----
    ldA(Ab, 0);
    ldB(Bb, 0);
    if (more) {
#pragma unroll
      for (int s = 0; s < L0; ++s) stage(s, p ^ 1, toff);
    }
    __builtin_amdgcn_s_barrier();
    wait_lds();
    mfma_quad(0, 0);
    __builtin_amdgcn_s_barrier();

    // ---- phase 1: B[nh1] reads | stage second half ----
    ldB(Bb, 1);
    if (more) {
#pragma unroll
      for (int s = L0; s < LT; ++s) stage(s, p ^ 1, toff);
    }
    __builtin_amdgcn_s_barrier();
    wait_lds();
    mfma_quad(0, 1);
    __builtin_amdgcn_s_barrier();

    // ---- phase 2: A[mh1] reads ----
    ldA(Ab, 1);
    __builtin_amdgcn_s_barrier();
    wait_lds();
    mfma_quad(1, 1);
    __builtin_amdgcn_s_barrier();

    // ---- phase 3: no LDS reads (A[mh1], B[nh0] live) ----
    mfma_quad(1, 0);
    if (more) {
      asm volatile("s_waitcnt vmcnt(0)" ::: "memory");   // own stage loads, ~2.5 phases old
    }
    __builtin_amdgcn_s_barrier();
  }

  if constexpr (EPI == 0) {             // plain float C
#pragma unroll
    for (int m = 0; m < 8; ++m) {
      const int row = bm + wr * 128 + m * 16 + l4 * 4;
#pragma unroll
      for (int n = 0; n < NF; ++n) {
        const int col = bn + wc * WCOLS + n * 16 + l15;
#pragma unroll
        for (int r = 0; r < 4; ++r)
          Cout[(int64_t)(row + r) * N + col] = acc[m][n][r];
      }
    }
  } else {                              // fused RoPE / scatter epilogue (BN=256)
    const int colbase = bn + wc * 64;   // wave-uniform, 64-aligned -> one head
    if (colbase < 2048) {               // Q region (RoPE + scale)
      const int h = colbase >> 6;
#pragma unroll
      for (int m = 0; m < 8; ++m) {
#pragma unroll
        for (int r = 0; r < 4; ++r) {
          const int srow = bm + wr * 128 + m * 16 + l4 * 4 + r;
          const int b = srow >> 11, s = srow & 2047;
          const float* cs = cosb + s * HD_;
          const float* sn = sinb + s * HD_;
          bf16_t* qp = Q + ((int64_t)(b * H_ + h) * S_ + s) * HD_;
#pragma unroll
          for (int n = 0; n < 4; ++n) {
            const int d = n * 16 + l15;
            const float sgn = (n & 2) ? 1.f : -1.f;
            float o = (acc[m][n][r] * cs[d] + sgn * acc[m][n ^ 2][r] * sn[d]) * QSCALE;
            qp[d] = (bf16_t)o;
          }
        }
      }
    } else if (colbase < 2560) {        // K region (RoPE)
      const int kvh = (colbase - 2048) >> 6;
#pragma unroll
      for (int m = 0; m < 8; ++m) {
#pragma unroll
        for (int r = 0; r < 4; ++r) {
          const int srow = bm + wr * 128 + m * 16 + l4 * 4 + r;
          const int b = srow >> 11, s = srow & 2047;
          const float* cs = cosb + s * HD_;
          const float* sn = sinb + s * HD_;
          bf16_t* kp = Kr + ((int64_t)(b * KV_ + kvh) * S_ + s) * HD_;
#pragma unroll
          for (int n = 0; n < 4; ++n) {
            const int d = n * 16 + l15;
            const float sgn = (n & 2) ? 1.f : -1.f;
            float o = acc[m][n][r] * cs[d] + sgn * acc[m][n ^ 2][r] * sn[d];
            kp[d] = (bf16_t)o;
          }
        }
      }
    } else {                            // V region (row-major, coalesced)
      const int ccb = colbase - 2560;
#pragma unroll
      for (int m = 0; m < 8; ++m) {
#pragma unroll
        for (int r = 0; r < 4; ++r) {
          const int srow = bm + wr * 128 + m * 16 + l4 * 4 + r;
          bf16_t* vp = Vbuf + (int64_t)srow * 512 + ccb;
#pragma unroll
          for (int n = 0; n < 4; ++n)
            vp[n * 16 + l15] = (bf16_t)acc[m][n][r];
        }
      }
    }
  }
}

// ---------------- flash attention: paired-chunk waves, 2x K/V reuse ----------------
#define SHIFT_ 8.0f
__global__ __launch_bounds__(256, 2) void attn7(const bf16_t* __restrict__ Q,
                                                const bf16_t* __restrict__ Kr,
                                                const bf16_t* __restrict__ Vt,
                                                bf16_t* __restrict__ AO) {
  const int bk = blockIdx.x;
  const int b = bk >> 3, kvh = bk & 7;
  const int y = blockIdx.y;               // 0..31
  const int q0A = y * 32, q0B = (63 - y) * 32;
  const int tid = threadIdx.x;
  const int w = tid >> 6, lane = tid & 63;
  const int l31 = lane & 31, hi = lane >> 5;
  const int h = kvh * 4 + w;

  __shared__ __align__(16) bf16_t Ks[3][64 * 64];   // [buf][kv][d] (swizzled granules)
  __shared__ __align__(16) bf16_t Vs[3][64 * 64];   // [buf][d][kv]

  const bf16_t* Kg = Kr + (int64_t)(b * KV_ + kvh) * S_ * HD_;
  const bf16_t* Vg = Vt + (int64_t)(b * KV_ + kvh) * HD_ * S_;   // [d][s]

  const int rL = (w << 3) + (lane >> 3);
  const int sgr = ((lane & 7) ^ (rL & 7)) << 3;     // element offset
  const bf16_t* Ksrc = Kg + (int64_t)rL * HD_ + sgr;
  const bf16_t* Vsrc = Vg + (int64_t)rL * S_ + sgr;

  const int NT = (63 - y) / 2 + 1;        // 64-kv tiles (chunk B reach)

  auto stage = [&](int t) {               // exactly 4 loads per wave (uniform vmcnt)
    const int tc = (t < NT) ? t : (NT - 1);
    char* Kd = (char*)Ks + (t % 3) * 8192 + w * 1024;
    char* Vd = (char*)Vs + (t % 3) * 8192 + w * 1024;
    gload_lds16(Ksrc + (int64_t)tc * 64 * HD_, Kd);
    gload_lds16(Ksrc + (int64_t)(tc * 64 + 32) * HD_, Kd + 4096);
    gload_lds16(Vsrc + tc * 64, Vd);
    gload_lds16(Vsrc + (int64_t)32 * S_ + tc * 64, Vd + 4096);
  };

  const bf16_t* QbA = Q + ((int64_t)(b * H_ + h) * S_ + q0A) * HD_;
  const bf16_t* QbB = Q + ((int64_t)(b * H_ + h) * S_ + q0B) * HD_;
  bf16x8 qfA[4], qfB[4];
#pragma unroll
  for (int ds = 0; ds < 4; ++ds) {
    qfA[ds] = *(const bf16x8*)(QbA + l31 * HD_ + ds * 16 + hi * 8);
    qfB[ds] = *(const bf16x8*)(QbB + l31 * HD_ + ds * 16 + hi * 8);
  }

  f32x16 aA0 = {}, aA1 = {}, aB0 = {}, aB1 = {};    // O^T partials per chunk
  float lhA = 0.f, lhB = 0.f;
  const int xorb = l31 & 7;

  const f32x16 sinit = {-SHIFT_, -SHIFT_, -SHIFT_, -SHIFT_,
                        -SHIFT_, -SHIFT_, -SHIFT_, -SHIFT_,
                        -SHIFT_, -SHIFT_, -SHIFT_, -SHIFT_,
                        -SHIFT_, -SHIFT_, -SHIFT_, -SHIFT_};

  auto softmax_pack = [&](const f32x16 &sacc, bool diag, float &lh,
                          bf16x8 &pf0, bf16x8 &pf1) {
    float p[16];
#pragma unroll
    for (int r = 0; r < 16; ++r) {
      float sc = sacc[r];
      if (diag) {
        int kvpos = (r & 3) + 8 * (r >> 2) + 4 * hi;
        if (kvpos > l31) sc = -1e30f;
      }
      p[r] = __builtin_amdgcn_exp2f(sc);
    }
    float t0 = (p[0] + p[1]) + (p[2] + p[3]);
    float t1 = (p[4] + p[5]) + (p[6] + p[7]);
    float t2 = (p[8] + p[9]) + (p[10] + p[11]);
    float t3 = (p[12] + p[13]) + (p[14] + p[15]);
    lh += (t0 + t1) + (t2 + t3);
    u32 pk[8];
#pragma unroll
    for (int i = 0; i < 8; ++i) pk[i] = pkbf(p[2*i], p[2*i+1]);
    u32 a0 = pk[0], b0 = pk[2]; pl32swap(a0, b0);
    u32 a1 = pk[1], b1 = pk[3]; pl32swap(a1, b1);
    u32 a2 = pk[4], b2 = pk[6]; pl32swap(a2, b2);
    u32 a3 = pk[5], b3 = pk[7]; pl32swap(a3, b3);
    pf0 = __builtin_bit_cast(bf16x8, (u32x4){a0, a1, b0, b1});
    pf1 = __builtin_bit_cast(bf16x8, (u32x4){a2, a3, b2, b3});
  };

  stage(0);
  stage(1);

  for (int t = 0; t < NT; ++t) {
    asm volatile("s_waitcnt vmcnt(4)" ::: "memory");
    __syncthreads();
    stage(t + 2);
    const char* KsB = (const char*)Ks + (t % 3) * 8192;
    const char* VsB = (const char*)Vs + (t % 3) * 8192;
#pragma unroll
    for (int sub = 0; sub < 2; ++sub) {
      const int kvbase = t * 64 + sub * 32;
      if (kvbase <= q0B) {
        const bool actA = (kvbase <= q0A);
        const char* Kbase = KsB + (sub * 32 + l31) * 128;
        bf16x8 kf[4];
#pragma unroll
        for (int ds = 0; ds < 4; ++ds)
          kf[ds] = *(const bf16x8*)(Kbase + ((((ds << 1) + hi) ^ xorb) << 4));
        f32x16 sA = sinit, sB = sinit;
        __builtin_amdgcn_s_setprio(1);
#pragma unroll
        for (int ds = 0; ds < 4; ++ds)
          sB = __builtin_amdgcn_mfma_f32_32x32x16_bf16(kf[ds], qfB[ds], sB, 0, 0, 0);
        if (actA) {
#pragma unroll
          for (int ds = 0; ds < 4; ++ds)
            sA = __builtin_amdgcn_mfma_f32_32x32x16_bf16(kf[ds], qfA[ds], sA, 0, 0, 0);
        }
        __builtin_amdgcn_s_setprio(0);
        bf16x8 pA0, pA1, pB0, pB1;
        softmax_pack(sB, kvbase == q0B, lhB, pB0, pB1);
        if (actA) softmax_pack(sA, kvbase == q0A, lhA, pA0, pA1);
        const char* Vb0 = VsB + l31 * 128;
        const char* Vb1 = VsB + (32 + l31) * 128;
        const int c0 = (sub << 2) + hi;
        const int c1 = c0 + 2;
        bf16x8 v00 = *(const bf16x8*)(Vb0 + ((c0 ^ xorb) << 4));
        bf16x8 v01 = *(const bf16x8*)(Vb0 + ((c1 ^ xorb) << 4));
        bf16x8 v10 = *(const bf16x8*)(Vb1 + ((c0 ^ xorb) << 4));
        bf16x8 v11 = *(const bf16x8*)(Vb1 + ((c1 ^ xorb) << 4));
        __builtin_amdgcn_s_setprio(1);
        aB0 = __builtin_amdgcn_mfma_f32_32x32x16_bf16(v00, pB0, aB0, 0, 0, 0);
        aB1 = __builtin_amdgcn_mfma_f32_32x32x16_bf16(v10, pB0, aB1, 0, 0, 0);
        aB0 = __builtin_amdgcn_mfma_f32_32x32x16_bf16(v01, pB1, aB0, 0, 0, 0);
        aB1 = __builtin_amdgcn_mfma_f32_32x32x16_bf16(v11, pB1, aB1, 0, 0, 0);
        if (actA) {
          aA0 = __builtin_amdgcn_mfma_f32_32x32x16_bf16(v00, pA0, aA0, 0, 0, 0);
          aA1 = __builtin_amdgcn_mfma_f32_32x32x16_bf16(v10, pA0, aA1, 0, 0, 0);
          aA0 = __builtin_amdgcn_mfma_f32_32x32x16_bf16(v01, pA1, aA0, 0, 0, 0);
          aA1 = __builtin_amdgcn_mfma_f32_32x32x16_bf16(v11, pA1, aA1, 0, 0, 0);
        }
        __builtin_amdgcn_s_setprio(0);
      }
    }
  }

  asm volatile("s_waitcnt vmcnt(0)" ::: "memory");

  auto epi = [&](const f32x16 &a0, const f32x16 &a1, float lh, int q0) {
    float l = lh + __shfl_xor(lh, 32);
    const float rl = 1.f / l;
    const int64_t row = (int64_t)(b * S_ + q0 + l31);
#pragma unroll
    for (int dt = 0; dt < 2; ++dt) {
#pragma unroll
      for (int g = 0; g < 4; ++g) {
        bf16x4 ov;
#pragma unroll
        for (int j = 0; j < 4; ++j) {
          float val = (dt ? a1[4*g + j] : a0[4*g + j]) * rl;
          ov[j] = (bf16_t)val;
        }
        const int d0 = dt * 32 + g * 8 + hi * 4;
        *(bf16x4*)(AO + row * D_ + h * HD_ + d0) = ov;
      }
    }
  };
  epi(aA0, aA1, lhA, q0A);
  epi(aB0, aB1, lhB, q0B);
}

// ---------------- launcher ----------------
extern "C" void kernel_launch(void* const* d_in, const int* in_sizes, int n_in,
                              void* d_out, int out_size, void* d_ws, size_t ws_size,
                              hipStream_t stream) {
  const float* x    = (const float*)d_in[0];
  const float* cosb = (const float*)d_in[1];
  const float* sinb = (const float*)d_in[2];
  const float* Wq   = (const float*)d_in[3];
  const float* Wk   = (const float*)d_in[4];
  const float* Wv   = (const float*)d_in[5];
  const float* Wo   = (const float*)d_in[6];
  float* out = (float*)d_out;

  bf16_t* ws = (bf16_t*)d_ws;
  size_t o = 0;
  bf16_t* xb    = ws + o; o += (size_t)4096 * 2048;
  bf16_t* Wqkvt = ws + o; o += (size_t)3072 * 2048;
  bf16_t* Wot   = ws + o; o += (size_t)2048 * 2048;
  bf16_t* Qr    = ws + o; o += (size_t)B_ * H_ * S_ * HD_;
  bf16_t* Krb   = ws + o; o += (size_t)B_ * KV_ * S_ * HD_;
  bf16_t* Vtb   = ws + o; o += (size_t)B_ * KV_ * S_ * HD_;
  bf16_t* Vbuf  = ws + o; o += (size_t)B_ * S_ * 512;
  bf16_t* AO    = ws + o; o += (size_t)4096 * 2048;

  cvt_f32_bf16<<<(8388608/4 + 255)/256, 256, 0, stream>>>(x, xb, 8388608/4);
  transpose_cvt<<<dim3(2048/32, 2048/32), dim3(32, 8), 0, stream>>>(Wq, Wqkvt, 2048, 0);
  transpose_cvt<<<dim3(512/32, 2048/32),  dim3(32, 8), 0, stream>>>(Wk, Wqkvt, 512, 2048);
  transpose_cvt<<<dim3(512/32, 2048/32),  dim3(32, 8), 0, stream>>>(Wv, Wqkvt, 512, 2560);
  transpose_cvt<<<dim3(2048/32, 2048/32), dim3(32, 8), 0, stream>>>(Wo, Wot, 2048, 0);
  // fused QKV projection + RoPE + scatter (phase-structured 256x256)
  gemm8p<256, 1><<<dim3(3072/256, 4096/256), 512, 0, stream>>>(
      xb, Wqkvt, cosb, sinb, Qr, Krb, Vbuf, nullptr, 3072, 2048);
  // V transpose to [b][d][s]
  v_transpose<<<dim3(16, 64, 2), dim3(32, 8), 0, stream>>>(Vbuf, Vtb);
  // paired-chunk attention (4-wave blocks, 2x K/V reuse, equal-work blocks)
  attn7<<<dim3(16, 32), 256, 0, stream>>>(Qr, Krb, Vtb, AO);
  // output projection -> f32 (phase-structured 256x128, 256 blocks = 1/CU)
  gemm8p<128, 0><<<dim3(2048/128, 4096/256), 512, 0, stream>>>(
      AO, Wot, nullptr, nullptr, nullptr, nullptr, nullptr, out, 2048, 2048);
}

// Round 12
// 188.001 us; speedup vs baseline: 1.0134x; 1.0134x over previous
//
#include <hip/hip_runtime.h>
#include <hip/hip_bf16.h>
#include <stdint.h>

#define B_ 2
#define S_ 2048
#define D_ 2048
#define H_ 32
#define KV_ 8
#define HD_ 64
#define NQKV 3072   // D + 2*KV*HD

typedef __bf16 bf16_t;
typedef __bf16 bf16x8 __attribute__((ext_vector_type(8)));
typedef __bf16 bf16x4 __attribute__((ext_vector_type(4)));
typedef float  f32x4  __attribute__((ext_vector_type(4)));
typedef float  f32x16 __attribute__((ext_vector_type(16)));
typedef unsigned int u32;
typedef u32 u32x4 __attribute__((ext_vector_type(4)));

typedef const __attribute__((address_space(1))) uint32_t* gp1_t;
typedef __attribute__((address_space(3))) uint32_t* lp3_t;

// async global->LDS, 16B per lane. LDS dest is wave-uniform base + lane*16.
__device__ inline void gload_lds16(const void* g, void* l) {
  __builtin_amdgcn_global_load_lds((gp1_t)(uintptr_t)g, (lp3_t)(uint32_t)(uintptr_t)l,
                                   16, 0, 0);
}

__device__ inline u32 pkbf(float a, float b) {
  union { bf16_t h[2]; u32 u; } v;
  v.h[0] = (bf16_t)a; v.h[1] = (bf16_t)b;
  return v.u;
}

// v_permlane32_swap_b32: a = [a_lo, b_lo], b = [a_hi, b_hi]
__device__ inline void pl32swap(u32 &a, u32 &b) {
  asm("v_permlane32_swap_b32 %0, %1" : "+v"(a), "+v"(b));
}

// ---------------- converts ----------------
__global__ void cvt_f32_bf16(const float* __restrict__ in, bf16_t* __restrict__ out, int n4) {
  int i = blockIdx.x * blockDim.x + threadIdx.x;
  if (i < n4) {
    float4 v = ((const float4*)in)[i];
    bf16x4 o;
    o[0] = (bf16_t)v.x; o[1] = (bf16_t)v.y; o[2] = (bf16_t)v.z; o[3] = (bf16_t)v.w;
    ((bf16x4*)out)[i] = o;
  }
}

// transpose + cast: out[row_off + c][r] = in[r][c]
__global__ void transpose_cvt(const float* __restrict__ in, bf16_t* __restrict__ out,
                              int C, int row_off) {
  __shared__ float t[32][33];
  int tx = threadIdx.x, ty = threadIdx.y;       // (32,8)
  int c0 = blockIdx.x * 32, r0 = blockIdx.y * 32;
#pragma unroll
  for (int j = 0; j < 4; ++j)
    t[ty + j*8][tx] = in[(int64_t)(r0 + ty + j*8) * C + c0 + tx];
  __syncthreads();
#pragma unroll
  for (int j = 0; j < 4; ++j)
    out[(int64_t)(row_off + c0 + ty + j*8) * 2048 + r0 + tx] = (bf16_t)t[tx][ty + j*8];
}

// Vbuf[b][s][cc] -> Vt[b][cc][s]  (LDS-tiled transpose, coalesced both sides)
__global__ void v_transpose(const bf16_t* __restrict__ Vbuf, bf16_t* __restrict__ Vt) {
  __shared__ bf16_t t[32][34];
  const int tx = threadIdx.x, ty = threadIdx.y;   // (32,8)
  const int c0 = blockIdx.x * 32;                 // cc within 512
  const int s0 = blockIdx.y * 32;
  const int b  = blockIdx.z;
#pragma unroll
  for (int j = 0; j < 4; ++j)
    t[ty + j*8][tx] = Vbuf[(int64_t)(b * S_ + s0 + ty + j*8) * 512 + c0 + tx];
  __syncthreads();
#pragma unroll
  for (int j = 0; j < 4; ++j)
    Vt[(int64_t)(b * 512 + c0 + ty + j*8) * S_ + s0 + tx] = t[tx][ty + j*8];
}

// ---------------- counted-vmcnt deep-pipelined GEMM ----------------
// BM=256, BK=32, 8 waves, 4 LDS buffers. Per iter s: stage(s+2) -> 12 ds_read ->
// 32 MFMA -> s_waitcnt vmcnt(LT) [loads issued 1 full iter ago] -> s_barrier.
// Never vmcnt(0) in the main loop (T4). Buffer (s+2)&3 was read at iter s-2
// (barrier-protected). Granule-XOR swizzle both sides (64B rows, 4 granules).
#define QSCALE 0.18033688011112042f
template <int BN, int EPI>
__global__ __launch_bounds__(512, 2) void gemm_cnt(const bf16_t* __restrict__ A,
                                                   const bf16_t* __restrict__ Bt,
                                                   const float* __restrict__ cosb,
                                                   const float* __restrict__ sinb,
                                                   bf16_t* __restrict__ Q,
                                                   bf16_t* __restrict__ Kr,
                                                   bf16_t* __restrict__ Vbuf,
                                                   float* __restrict__ Cout,
                                                   int N, int K) {
  constexpr int NBC = BN / 128;        // B stage calls per chunk (2 or 1)
  constexpr int LT = 2 + NBC;          // stage loads per chunk per wave (4 or 3)
  constexpr int WCOLS = BN / 4;        // per-wave cols (64 or 32)
  constexpr int NF = WCOLS / 16;       // per-wave n fragments (4 or 2)

  __shared__ bf16_t As[4][256 * 32];
  __shared__ bf16_t Bs[4][BN * 32];

  const int tid = threadIdx.x;
  const int w = tid >> 6, lane = tid & 63;
  const int l15 = lane & 15, l4 = lane >> 4;
  const int wr = w >> 2, wc = w & 3;
  const int bm = blockIdx.y * 256, bn = blockIdx.x * BN;

  // staging: call c stages rows [c*128, c*128+128); wave w -> rows w*16 + lane>>2,
  // granule pre-swizzled: (lane&3) ^ (row&3), row&3 = (lane>>2)&3
  const int rw = w * 16 + (lane >> 2);
  const int srcg = ((lane & 3) ^ ((lane >> 2) & 3)) << 3;   // element offset
  const bf16_t* PA[2];
  const bf16_t* PB[NBC];
#pragma unroll
  for (int c = 0; c < 2; ++c)
    PA[c] = A + (int64_t)(bm + c * 128 + rw) * K + srcg;
#pragma unroll
  for (int c = 0; c < NBC; ++c)
    PB[c] = Bt + (int64_t)(bn + c * 128 + rw) * K + srcg;

  const int NS = K >> 5;               // K chunks of 32
  const int gg = ((l4 ^ (l15 & 3)) << 4);   // swizzled byte offset within 64B row

  f32x4 acc[8][NF] = {};

  auto stage = [&](int s, int buf) {
    const int off = s << 5;            // K element offset
#pragma unroll
    for (int c = 0; c < 2; ++c)
      gload_lds16(PA[c] + off, (char*)&As[buf][0] + c * 8192 + w * 1024);
#pragma unroll
    for (int c = 0; c < NBC; ++c)
      gload_lds16(PB[c] + off, (char*)&Bs[buf][0] + c * 8192 + w * 1024);
  };

  auto wait_cnt = [&]() {
    if constexpr (LT == 4) asm volatile("s_waitcnt vmcnt(4)" ::: "memory");
    else                   asm volatile("s_waitcnt vmcnt(3)" ::: "memory");
    asm volatile("s_barrier" ::: "memory");
  };

  auto compute = [&](int buf) {
    const char* Ab = (const char*)&As[buf][0];
    const char* Bb = (const char*)&Bs[buf][0];
    bf16x8 bfv[NF];
#pragma unroll
    for (int nn = 0; nn < NF; ++nn) {
      const int rb = wc * WCOLS + nn * 16 + l15;
      bfv[nn] = *(const bf16x8*)(Bb + rb * 64 + gg);
    }
    bf16x8 af[8];
#pragma unroll
    for (int mm = 0; mm < 8; ++mm) {
      const int ra = wr * 128 + mm * 16 + l15;
      af[mm] = *(const bf16x8*)(Ab + ra * 64 + gg);
    }
    __builtin_amdgcn_s_setprio(1);
#pragma unroll
    for (int mm = 0; mm < 8; ++mm)
#pragma unroll
      for (int nn = 0; nn < NF; ++nn)
        acc[mm][nn] = __builtin_amdgcn_mfma_f32_16x16x32_bf16(
            af[mm], bfv[nn], acc[mm][nn], 0, 0, 0);
    __builtin_amdgcn_s_setprio(0);
  };

  // prologue: stage chunks 0,1; wait chunk 0 (chunk 1 stays in flight)
  stage(0, 0);
  stage(1, 1);
  wait_cnt();

  for (int s0 = 0; s0 < NS; s0 += 4) {
#pragma unroll
    for (int u = 0; u < 4; ++u) {
      const int s = s0 + u;
      const int t2 = (s + 2 < NS) ? (s + 2) : (NS - 1);   // clamped: uniform count
      stage(t2, (u + 2) & 3);
      compute(u);
      wait_cnt();
    }
  }
  asm volatile("s_waitcnt vmcnt(0)" ::: "memory");   // drain before exit

  if constexpr (EPI == 0) {             // plain float C
#pragma unroll
    for (int m = 0; m < 8; ++m) {
      const int row = bm + wr * 128 + m * 16 + l4 * 4;
#pragma unroll
      for (int n = 0; n < NF; ++n) {
        const int col = bn + wc * WCOLS + n * 16 + l15;
#pragma unroll
        for (int r = 0; r < 4; ++r)
          Cout[(int64_t)(row + r) * N + col] = acc[m][n][r];
      }
    }
  } else {                              // fused RoPE / scatter epilogue (BN=256)
    const int colbase = bn + wc * 64;   // wave-uniform, 64-aligned -> one head
    if (colbase < 2048) {               // Q region (RoPE + scale)
      const int h = colbase >> 6;
#pragma unroll
      for (int m = 0; m < 8; ++m) {
#pragma unroll
        for (int r = 0; r < 4; ++r) {
          const int srow = bm + wr * 128 + m * 16 + l4 * 4 + r;
          const int b = srow >> 11, s = srow & 2047;
          const float* cs = cosb + s * HD_;
          const float* sn = sinb + s * HD_;
          bf16_t* qp = Q + ((int64_t)(b * H_ + h) * S_ + s) * HD_;
#pragma unroll
          for (int n = 0; n < 4; ++n) {
            const int d = n * 16 + l15;
            const float sgn = (n & 2) ? 1.f : -1.f;
            float o = (acc[m][n][r] * cs[d] + sgn * acc[m][n ^ 2][r] * sn[d]) * QSCALE;
            qp[d] = (bf16_t)o;
          }
        }
      }
    } else if (colbase < 2560) {        // K region (RoPE)
      const int kvh = (colbase - 2048) >> 6;
#pragma unroll
      for (int m = 0; m < 8; ++m) {
#pragma unroll
        for (int r = 0; r < 4; ++r) {
          const int srow = bm + wr * 128 + m * 16 + l4 * 4 + r;
          const int b = srow >> 11, s = srow & 2047;
          const float* cs = cosb + s * HD_;
          const float* sn = sinb + s * HD_;
          bf16_t* kp = Kr + ((int64_t)(b * KV_ + kvh) * S_ + s) * HD_;
#pragma unroll
          for (int n = 0; n < 4; ++n) {
            const int d = n * 16 + l15;
            const float sgn = (n & 2) ? 1.f : -1.f;
            float o = acc[m][n][r] * cs[d] + sgn * acc[m][n ^ 2][r] * sn[d];
            kp[d] = (bf16_t)o;
          }
        }
      }
    } else {                            // V region (row-major, coalesced)
      const int ccb = colbase - 2560;
#pragma unroll
      for (int m = 0; m < 8; ++m) {
#pragma unroll
        for (int r = 0; r < 4; ++r) {
          const int srow = bm + wr * 128 + m * 16 + l4 * 4 + r;
          bf16_t* vp = Vbuf + (int64_t)srow * 512 + ccb;
#pragma unroll
          for (int n = 0; n < 4; ++n)
            vp[n * 16 + l15] = (bf16_t)acc[m][n][r];
        }
      }
    }
  }
}

// ---------------- flash attention: paired-chunk waves, 2x K/V reuse ----------------
#define SHIFT_ 8.0f
__global__ __launch_bounds__(256, 2) void attn7(const bf16_t* __restrict__ Q,
                                                const bf16_t* __restrict__ Kr,
                                                const bf16_t* __restrict__ Vt,
                                                bf16_t* __restrict__ AO) {
  const int bk = blockIdx.x;
  const int b = bk >> 3, kvh = bk & 7;
  const int y = blockIdx.y;               // 0..31
  const int q0A = y * 32, q0B = (63 - y) * 32;
  const int tid = threadIdx.x;
  const int w = tid >> 6, lane = tid & 63;
  const int l31 = lane & 31, hi = lane >> 5;
  const int h = kvh * 4 + w;

  __shared__ __align__(16) bf16_t Ks[3][64 * 64];   // [buf][kv][d] (swizzled granules)
  __shared__ __align__(16) bf16_t Vs[3][64 * 64];   // [buf][d][kv]

  const bf16_t* Kg = Kr + (int64_t)(b * KV_ + kvh) * S_ * HD_;
  const bf16_t* Vg = Vt + (int64_t)(b * KV_ + kvh) * HD_ * S_;   // [d][s]

  const int rL = (w << 3) + (lane >> 3);
  const int sgr = ((lane & 7) ^ (rL & 7)) << 3;     // element offset
  const bf16_t* Ksrc = Kg + (int64_t)rL * HD_ + sgr;
  const bf16_t* Vsrc = Vg + (int64_t)rL * S_ + sgr;

  const int NT = (63 - y) / 2 + 1;        // 64-kv tiles (chunk B reach)

  auto stage = [&](int t) {               // exactly 4 loads per wave (uniform vmcnt)
    const int tc = (t < NT) ? t : (NT - 1);
    char* Kd = (char*)Ks + (t % 3) * 8192 + w * 1024;
    char* Vd = (char*)Vs + (t % 3) * 8192 + w * 1024;
    gload_lds16(Ksrc + (int64_t)tc * 64 * HD_, Kd);
    gload_lds16(Ksrc + (int64_t)(tc * 64 + 32) * HD_, Kd + 4096);
    gload_lds16(Vsrc + tc * 64, Vd);
    gload_lds16(Vsrc + (int64_t)32 * S_ + tc * 64, Vd + 4096);
  };

  const bf16_t* QbA = Q + ((int64_t)(b * H_ + h) * S_ + q0A) * HD_;
  const bf16_t* QbB = Q + ((int64_t)(b * H_ + h) * S_ + q0B) * HD_;
  bf16x8 qfA[4], qfB[4];
#pragma unroll
  for (int ds = 0; ds < 4; ++ds) {
    qfA[ds] = *(const bf16x8*)(QbA + l31 * HD_ + ds * 16 + hi * 8);
    qfB[ds] = *(const bf16x8*)(QbB + l31 * HD_ + ds * 16 + hi * 8);
  }

  f32x16 aA0 = {}, aA1 = {}, aB0 = {}, aB1 = {};    // O^T partials per chunk
  float lhA = 0.f, lhB = 0.f;
  const int xorb = l31 & 7;

  const f32x16 sinit = {-SHIFT_, -SHIFT_, -SHIFT_, -SHIFT_,
                        -SHIFT_, -SHIFT_, -SHIFT_, -SHIFT_,
                        -SHIFT_, -SHIFT_, -SHIFT_, -SHIFT_,
                        -SHIFT_, -SHIFT_, -SHIFT_, -SHIFT_};

  auto softmax_pack = [&](const f32x16 &sacc, bool diag, float &lh,
                          bf16x8 &pf0, bf16x8 &pf1) {
    float p[16];
#pragma unroll
    for (int r = 0; r < 16; ++r) {
      float sc = sacc[r];
      if (diag) {
        int kvpos = (r & 3) + 8 * (r >> 2) + 4 * hi;
        if (kvpos > l31) sc = -1e30f;
      }
      p[r] = __builtin_amdgcn_exp2f(sc);
    }
    float t0 = (p[0] + p[1]) + (p[2] + p[3]);
    float t1 = (p[4] + p[5]) + (p[6] + p[7]);
    float t2 = (p[8] + p[9]) + (p[10] + p[11]);
    float t3 = (p[12] + p[13]) + (p[14] + p[15]);
    lh += (t0 + t1) + (t2 + t3);
    u32 pk[8];
#pragma unroll
    for (int i = 0; i < 8; ++i) pk[i] = pkbf(p[2*i], p[2*i+1]);
    u32 a0 = pk[0], b0 = pk[2]; pl32swap(a0, b0);
    u32 a1 = pk[1], b1 = pk[3]; pl32swap(a1, b1);
    u32 a2 = pk[4], b2 = pk[6]; pl32swap(a2, b2);
    u32 a3 = pk[5], b3 = pk[7]; pl32swap(a3, b3);
    pf0 = __builtin_bit_cast(bf16x8, (u32x4){a0, a1, b0, b1});
    pf1 = __builtin_bit_cast(bf16x8, (u32x4){a2, a3, b2, b3});
  };

  stage(0);
  stage(1);

  for (int t = 0; t < NT; ++t) {
    asm volatile("s_waitcnt vmcnt(4)" ::: "memory");
    __syncthreads();
    stage(t + 2);
    const char* KsB = (const char*)Ks + (t % 3) * 8192;
    const char* VsB = (const char*)Vs + (t % 3) * 8192;
#pragma unroll
    for (int sub = 0; sub < 2; ++sub) {
      const int kvbase = t * 64 + sub * 32;
      if (kvbase <= q0B) {
        const bool actA = (kvbase <= q0A);
        const char* Kbase = KsB + (sub * 32 + l31) * 128;
        bf16x8 kf[4];
#pragma unroll
        for (int ds = 0; ds < 4; ++ds)
          kf[ds] = *(const bf16x8*)(Kbase + ((((ds << 1) + hi) ^ xorb) << 4));
        f32x16 sA = sinit, sB = sinit;
        __builtin_amdgcn_s_setprio(1);
#pragma unroll
        for (int ds = 0; ds < 4; ++ds)
          sB = __builtin_amdgcn_mfma_f32_32x32x16_bf16(kf[ds], qfB[ds], sB, 0, 0, 0);
        if (actA) {
#pragma unroll
          for (int ds = 0; ds < 4; ++ds)
            sA = __builtin_amdgcn_mfma_f32_32x32x16_bf16(kf[ds], qfA[ds], sA, 0, 0, 0);
        }
        __builtin_amdgcn_s_setprio(0);
        bf16x8 pA0, pA1, pB0, pB1;
        softmax_pack(sB, kvbase == q0B, lhB, pB0, pB1);
        if (actA) softmax_pack(sA, kvbase == q0A, lhA, pA0, pA1);
        const char* Vb0 = VsB + l31 * 128;
        const char* Vb1 = VsB + (32 + l31) * 128;
        const int c0 = (sub << 2) + hi;
        const int c1 = c0 + 2;
        bf16x8 v00 = *(const bf16x8*)(Vb0 + ((c0 ^ xorb) << 4));
        bf16x8 v01 = *(const bf16x8*)(Vb0 + ((c1 ^ xorb) << 4));
        bf16x8 v10 = *(const bf16x8*)(Vb1 + ((c0 ^ xorb) << 4));
        bf16x8 v11 = *(const bf16x8*)(Vb1 + ((c1 ^ xorb) << 4));
        __builtin_amdgcn_s_setprio(1);
        aB0 = __builtin_amdgcn_mfma_f32_32x32x16_bf16(v00, pB0, aB0, 0, 0, 0);
        aB1 = __builtin_amdgcn_mfma_f32_32x32x16_bf16(v10, pB0, aB1, 0, 0, 0);
        aB0 = __builtin_amdgcn_mfma_f32_32x32x16_bf16(v01, pB1, aB0, 0, 0, 0);
        aB1 = __builtin_amdgcn_mfma_f32_32x32x16_bf16(v11, pB1, aB1, 0, 0, 0);
        if (actA) {
          aA0 = __builtin_amdgcn_mfma_f32_32x32x16_bf16(v00, pA0, aA0, 0, 0, 0);
          aA1 = __builtin_amdgcn_mfma_f32_32x32x16_bf16(v10, pA0, aA1, 0, 0, 0);
          aA0 = __builtin_amdgcn_mfma_f32_32x32x16_bf16(v01, pA1, aA0, 0, 0, 0);
          aA1 = __builtin_amdgcn_mfma_f32_32x32x16_bf16(v11, pA1, aA1, 0, 0, 0);
        }
        __builtin_amdgcn_s_setprio(0);
      }
    }
  }

  asm volatile("s_waitcnt vmcnt(0)" ::: "memory");

  auto epi = [&](const f32x16 &a0, const f32x16 &a1, float lh, int q0) {
    float l = lh + __shfl_xor(lh, 32);
    const float rl = 1.f / l;
    const int64_t row = (int64_t)(b * S_ + q0 + l31);
#pragma unroll
    for (int dt = 0; dt < 2; ++dt) {
#pragma unroll
      for (int g = 0; g < 4; ++g) {
        bf16x4 ov;
#pragma unroll
        for (int j = 0; j < 4; ++j) {
          float val = (dt ? a1[4*g + j] : a0[4*g + j]) * rl;
          ov[j] = (bf16_t)val;
        }
        const int d0 = dt * 32 + g * 8 + hi * 4;
        *(bf16x4*)(AO + row * D_ + h * HD_ + d0) = ov;
      }
    }
  };
  epi(aA0, aA1, lhA, q0A);
  epi(aB0, aB1, lhB, q0B);
}

// ---------------- launcher ----------------
extern "C" void kernel_launch(void* const* d_in, const int* in_sizes, int n_in,
                              void* d_out, int out_size, void* d_ws, size_t ws_size,
                              hipStream_t stream) {
  const float* x    = (const float*)d_in[0];
  const float* cosb = (const float*)d_in[1];
  const float* sinb = (const float*)d_in[2];
  const float* Wq   = (const float*)d_in[3];
  const float* Wk   = (const float*)d_in[4];
  const float* Wv   = (const float*)d_in[5];
  const float* Wo   = (const float*)d_in[6];
  float* out = (float*)d_out;

  bf16_t* ws = (bf16_t*)d_ws;
  size_t o = 0;
  bf16_t* xb    = ws + o; o += (size_t)4096 * 2048;
  bf16_t* Wqkvt = ws + o; o += (size_t)3072 * 2048;
  bf16_t* Wot   = ws + o; o += (size_t)2048 * 2048;
  bf16_t* Qr    = ws + o; o += (size_t)B_ * H_ * S_ * HD_;
  bf16_t* Krb   = ws + o; o += (size_t)B_ * KV_ * S_ * HD_;
  bf16_t* Vtb   = ws + o; o += (size_t)B_ * KV_ * S_ * HD_;
  bf16_t* Vbuf  = ws + o; o += (size_t)B_ * S_ * 512;
  bf16_t* AO    = ws + o; o += (size_t)4096 * 2048;

  cvt_f32_bf16<<<(8388608/4 + 255)/256, 256, 0, stream>>>(x, xb, 8388608/4);
  transpose_cvt<<<dim3(2048/32, 2048/32), dim3(32, 8), 0, stream>>>(Wq, Wqkvt, 2048, 0);
  transpose_cvt<<<dim3(512/32, 2048/32),  dim3(32, 8), 0, stream>>>(Wk, Wqkvt, 512, 2048);
  transpose_cvt<<<dim3(512/32, 2048/32),  dim3(32, 8), 0, stream>>>(Wv, Wqkvt, 512, 2560);
  transpose_cvt<<<dim3(2048/32, 2048/32), dim3(32, 8), 0, stream>>>(Wo, Wot, 2048, 0);
  // fused QKV projection + RoPE + scatter (counted-vmcnt 256x256)
  gemm_cnt<256, 1><<<dim3(3072/256, 4096/256), 512, 0, stream>>>(
      xb, Wqkvt, cosb, sinb, Qr, Krb, Vbuf, nullptr, 3072, 2048);
  // V transpose to [b][d][s]
  v_transpose<<<dim3(16, 64, 2), dim3(32, 8), 0, stream>>>(Vbuf, Vtb);
  // paired-chunk attention (4-wave blocks, 2x K/V reuse, equal-work blocks)
  attn7<<<dim3(16, 32), 256, 0, stream>>>(Qr, Krb, Vtb, AO);
  // output projection -> f32 (counted-vmcnt 256x128, 256 blocks = 1/CU)
  gemm_cnt<128, 0><<<dim3(2048/128, 4096/256), 512, 0, stream>>>(
      AO, Wot, nullptr, nullptr, nullptr, nullptr, nullptr, out, 2048, 2048);
}

// Round 13
// 180.243 us; speedup vs baseline: 1.0570x; 1.0430x over previous
//
#include <hip/hip_runtime.h>
#include <hip/hip_bf16.h>
#include <stdint.h>

#define B_ 2
#define S_ 2048
#define D_ 2048
#define H_ 32
#define KV_ 8
#define HD_ 64
#define NQKV 3072   // D + 2*KV*HD

typedef __bf16 bf16_t;
typedef __bf16 bf16x8 __attribute__((ext_vector_type(8)));
typedef __bf16 bf16x4 __attribute__((ext_vector_type(4)));
typedef float  f32x4  __attribute__((ext_vector_type(4)));
typedef float  f32x16 __attribute__((ext_vector_type(16)));
typedef unsigned int u32;
typedef u32 u32x4 __attribute__((ext_vector_type(4)));

typedef const __attribute__((address_space(1))) uint32_t* gp1_t;
typedef __attribute__((address_space(3))) uint32_t* lp3_t;

// async global->LDS, 16B per lane. LDS dest is wave-uniform base + lane*16.
__device__ inline void gload_lds16(const void* g, void* l) {
  __builtin_amdgcn_global_load_lds((gp1_t)(uintptr_t)g, (lp3_t)(uint32_t)(uintptr_t)l,
                                   16, 0, 0);
}

__device__ inline u32 pkbf(float a, float b) {
  union { bf16_t h[2]; u32 u; } v;
  v.h[0] = (bf16_t)a; v.h[1] = (bf16_t)b;
  return v.u;
}

// v_permlane32_swap_b32: a = [a_lo, b_lo], b = [a_hi, b_hi]
__device__ inline void pl32swap(u32 &a, u32 &b) {
  asm("v_permlane32_swap_b32 %0, %1" : "+v"(a), "+v"(b));
}

// ---------------- converts ----------------
__global__ void cvt_f32_bf16(const float* __restrict__ in, bf16_t* __restrict__ out, int n4) {
  int i = blockIdx.x * blockDim.x + threadIdx.x;
  if (i < n4) {
    float4 v = ((const float4*)in)[i];
    bf16x4 o;
    o[0] = (bf16_t)v.x; o[1] = (bf16_t)v.y; o[2] = (bf16_t)v.z; o[3] = (bf16_t)v.w;
    ((bf16x4*)out)[i] = o;
  }
}

// transpose + cast: out[row_off + c][r] = in[r][c]
__global__ void transpose_cvt(const float* __restrict__ in, bf16_t* __restrict__ out,
                              int C, int row_off) {
  __shared__ float t[32][33];
  int tx = threadIdx.x, ty = threadIdx.y;       // (32,8)
  int c0 = blockIdx.x * 32, r0 = blockIdx.y * 32;
#pragma unroll
  for (int j = 0; j < 4; ++j)
    t[ty + j*8][tx] = in[(int64_t)(r0 + ty + j*8) * C + c0 + tx];
  __syncthreads();
#pragma unroll
  for (int j = 0; j < 4; ++j)
    out[(int64_t)(row_off + c0 + ty + j*8) * 2048 + r0 + tx] = (bf16_t)t[tx][ty + j*8];
}

// V region of qkv -> Vt[b][kvh][d][s]  (LDS-tiled transpose, coalesced both sides)
__global__ void v_transpose(const bf16_t* __restrict__ qkv, bf16_t* __restrict__ Vt) {
  __shared__ bf16_t t[32][34];
  const int tx = threadIdx.x, ty = threadIdx.y;   // (32,8)
  const int c0 = blockIdx.x * 32;                 // V col within 512
  const int s0 = blockIdx.y * 32;
  const int b  = blockIdx.z;
#pragma unroll
  for (int j = 0; j < 4; ++j)
    t[ty + j*8][tx] = qkv[(int64_t)(b * S_ + s0 + ty + j*8) * NQKV + 2560 + c0 + tx];
  __syncthreads();
#pragma unroll
  for (int j = 0; j < 4; ++j)
    Vt[(int64_t)(b * 512 + c0 + ty + j*8) * S_ + s0 + tx] = t[tx][ty + j*8];
}

// ---------------- vectorized RoPE scatter (Q scaled by 0.125*log2e) ----------------
#define QSCALE 0.18033688011112042f
__global__ __launch_bounds__(256) void rope_scatter2(const bf16_t* __restrict__ qkv,
                                                     const float* __restrict__ cosb,
                                                     const float* __restrict__ sinb,
                                                     bf16_t* __restrict__ Q,
                                                     bf16_t* __restrict__ Kr) {
  const int row = blockIdx.x;            // b*S + s
  const int b = row >> 11, s = row & 2047;
  const bf16_t* src = qkv + (int64_t)row * NQKV;
  const float* cs = cosb + s * HD_;
  const float* sn = sinb + s * HD_;
  const int tid = threadIdx.x;
  {                                      // Q: 2048 elems = 256 vectors
    const int c0 = tid * 8;
    const int d0 = c0 & 63, h = c0 >> 6;
    bf16x8 own = *(const bf16x8*)(src + c0);
    bf16x8 par = *(const bf16x8*)(src + (c0 ^ 32));
    const float sgn = (d0 & 32) ? 1.f : -1.f;
    bf16x8 o;
#pragma unroll
    for (int j = 0; j < 8; ++j) {
      const int d = d0 + j;
      float val = (float)own[j] * cs[d] + sgn * (float)par[j] * sn[d];
      o[j] = (bf16_t)(val * QSCALE);
    }
    *(bf16x8*)(Q + ((int64_t)(b * H_ + h) * S_ + s) * HD_ + d0) = o;
  }
  if (tid < 64) {                        // K: 512 elems = 64 vectors
    const int c0 = 2048 + tid * 8;
    const int d0 = (tid * 8) & 63, kvh = tid >> 3;
    bf16x8 own = *(const bf16x8*)(src + c0);
    bf16x8 par = *(const bf16x8*)(src + (c0 ^ 32));
    const float sgn = (d0 & 32) ? 1.f : -1.f;
    bf16x8 o;
#pragma unroll
    for (int j = 0; j < 8; ++j) {
      const int d = d0 + j;
      float val = (float)own[j] * cs[d] + sgn * (float)par[j] * sn[d];
      o[j] = (bf16_t)val;
    }
    *(bf16x8*)(Kr + ((int64_t)(b * KV_ + kvh) * S_ + s) * HD_ + d0) = o;
  }
}

// ---------------- 256-row deep-pipelined GEMM (dedup'd LDS reads) ----------------
// BM=256, BK=64, 8 waves (2M x 4N). EPI=0: f32 C. EPI=2: bf16 row-major C.
// Granule-XOR swizzle both sides; per-tile: hoist all B frags, A per mh-half,
// stage t+1 inside the two mh halves, one vmcnt(0)+barrier per K-tile.
template <int BN, int EPI, typename OutT>
__global__ __launch_bounds__(512, 2) void gemm256(const bf16_t* __restrict__ A,
                                                  const bf16_t* __restrict__ Bt,
                                                  OutT* __restrict__ Cout,
                                                  int N, int K) {
  constexpr int NB = BN / 64;          // B stage loads per tile (3 or 2)
  constexpr int LT = 4 + NB;           // total stage loads per tile (7 or 6)
  constexpr int WCOLS = BN / 4;        // per-wave cols (48 or 32)
  constexpr int NF = WCOLS / 16;       // per-wave n fragments (3 or 2)

  __shared__ bf16_t As[2][256 * 64];
  __shared__ bf16_t Bs[2][BN * 64];

  const int tid = threadIdx.x;
  const int w = tid >> 6, lane = tid & 63;
  const int l15 = lane & 15, l4 = lane >> 4;
  const int wr = w >> 2, wc = w & 3;
  const int bm = blockIdx.y * 256, bn = blockIdx.x * BN;

  // staging source (pre-swizzled): row = L*64 + w*8 + lane>>3; granule = (lane&7)^(row&7)
  const int rw = w * 8 + (lane >> 3);
  const int srcg = ((lane & 7) ^ ((lane >> 3) & 7)) << 3;   // element offset
  const bf16_t* PA[4];
  const bf16_t* PB[NB];
#pragma unroll
  for (int L = 0; L < 4; ++L)
    PA[L] = A + (int64_t)(bm + L * 64 + rw) * K + srcg;
#pragma unroll
  for (int L = 0; L < NB; ++L)
    PB[L] = Bt + (int64_t)(bn + L * 64 + rw) * K + srcg;

  const int NK = K >> 6;
  const int xr = l15 & 7;
  const int g0 = (l4 ^ xr) << 3;          // kk=0 slot, element offset
  const int g1 = ((4 + l4) ^ xr) << 3;    // kk=1 slot

  f32x4 acc[8][NF] = {};

  auto stage = [&](int s, int buf, int toff) {
    if (s < 4) gload_lds16(PA[s] + toff, &As[buf][s * 4096 + w * 512]);
    else       gload_lds16(PB[s - 4] + toff, &Bs[buf][(s - 4) * 4096 + w * 512]);
  };

  // prologue: stage tile 0 into buf 0
#pragma unroll
  for (int s = 0; s < LT; ++s) stage(s, 0, 0);
  asm volatile("s_waitcnt vmcnt(0)" ::: "memory");
  __syncthreads();

  for (int t = 0; t < NK; ++t) {
    const int p = t & 1;
    const bool more = (t + 1) < NK;
    const int toff = (t + 1) << 6;
    const bf16_t* Ab = &As[p][0];
    const bf16_t* Bb = &Bs[p][0];

    // hoist ALL B fragments for this tile
    bf16x8 ball[NF][2];
#pragma unroll
    for (int nn = 0; nn < NF; ++nn) {
      const int rb = wc * WCOLS + nn * 16 + l15;
      ball[nn][0] = *(const bf16x8*)(Bb + rb * 64 + g0);
      ball[nn][1] = *(const bf16x8*)(Bb + rb * 64 + g1);
    }

#pragma unroll
    for (int mh = 0; mh < 2; ++mh) {
      if (more) {
        const int sb = mh * (LT / 2);
        const int se = (mh == 0) ? (LT / 2) : LT;
#pragma unroll
        for (int s = sb; s < se; ++s) stage(s, p ^ 1, toff);
      }
      bf16x8 af[4][2];
#pragma unroll
      for (int mm = 0; mm < 4; ++mm) {
        const int ra = wr * 128 + (mh * 4 + mm) * 16 + l15;
        af[mm][0] = *(const bf16x8*)(Ab + ra * 64 + g0);
        af[mm][1] = *(const bf16x8*)(Ab + ra * 64 + g1);
      }
      __builtin_amdgcn_s_setprio(1);
#pragma unroll
      for (int mm = 0; mm < 4; ++mm)
#pragma unroll
        for (int nn = 0; nn < NF; ++nn) {
          acc[mh*4+mm][nn] = __builtin_amdgcn_mfma_f32_16x16x32_bf16(
              af[mm][0], ball[nn][0], acc[mh*4+mm][nn], 0, 0, 0);
          acc[mh*4+mm][nn] = __builtin_amdgcn_mfma_f32_16x16x32_bf16(
              af[mm][1], ball[nn][1], acc[mh*4+mm][nn], 0, 0, 0);
        }
      __builtin_amdgcn_s_setprio(0);
    }
    if (more) {
      asm volatile("s_waitcnt vmcnt(0)" ::: "memory");
      __syncthreads();
    }
  }

#pragma unroll
  for (int m = 0; m < 8; ++m) {
    const int row = bm + wr * 128 + m * 16 + l4 * 4;
#pragma unroll
    for (int n = 0; n < NF; ++n) {
      const int col = bn + wc * WCOLS + n * 16 + l15;
#pragma unroll
      for (int r = 0; r < 4; ++r)
        Cout[(int64_t)(row + r) * N + col] = (OutT)acc[m][n][r];
    }
  }
}

// ---------------- flash attention: paired-chunk waves, 2x K/V reuse ----------------
#define SHIFT_ 8.0f
__global__ __launch_bounds__(256, 2) void attn7(const bf16_t* __restrict__ Q,
                                                const bf16_t* __restrict__ Kr,
                                                const bf16_t* __restrict__ Vt,
                                                bf16_t* __restrict__ AO) {
  const int bk = blockIdx.x;
  const int b = bk >> 3, kvh = bk & 7;
  const int y = blockIdx.y;               // 0..31
  const int q0A = y * 32, q0B = (63 - y) * 32;
  const int tid = threadIdx.x;
  const int w = tid >> 6, lane = tid & 63;
  const int l31 = lane & 31, hi = lane >> 5;
  const int h = kvh * 4 + w;

  __shared__ __align__(16) bf16_t Ks[3][64 * 64];   // [buf][kv][d] (swizzled granules)
  __shared__ __align__(16) bf16_t Vs[3][64 * 64];   // [buf][d][kv]

  const bf16_t* Kg = Kr + (int64_t)(b * KV_ + kvh) * S_ * HD_;
  const bf16_t* Vg = Vt + (int64_t)(b * KV_ + kvh) * HD_ * S_;   // [d][s]

  const int rL = (w << 3) + (lane >> 3);
  const int sgr = ((lane & 7) ^ (rL & 7)) << 3;     // element offset
  const bf16_t* Ksrc = Kg + (int64_t)rL * HD_ + sgr;
  const bf16_t* Vsrc = Vg + (int64_t)rL * S_ + sgr;

  const int NT = (63 - y) / 2 + 1;        // 64-kv tiles (chunk B reach)

  auto stage = [&](int t) {               // exactly 4 loads per wave (uniform vmcnt)
    const int tc = (t < NT) ? t : (NT - 1);
    char* Kd = (char*)Ks + (t % 3) * 8192 + w * 1024;
    char* Vd = (char*)Vs + (t % 3) * 8192 + w * 1024;
    gload_lds16(Ksrc + (int64_t)tc * 64 * HD_, Kd);
    gload_lds16(Ksrc + (int64_t)(tc * 64 + 32) * HD_, Kd + 4096);
    gload_lds16(Vsrc + tc * 64, Vd);
    gload_lds16(Vsrc + (int64_t)32 * S_ + tc * 64, Vd + 4096);
  };

  const bf16_t* QbA = Q + ((int64_t)(b * H_ + h) * S_ + q0A) * HD_;
  const bf16_t* QbB = Q + ((int64_t)(b * H_ + h) * S_ + q0B) * HD_;
  bf16x8 qfA[4], qfB[4];
#pragma unroll
  for (int ds = 0; ds < 4; ++ds) {
    qfA[ds] = *(const bf16x8*)(QbA + l31 * HD_ + ds * 16 + hi * 8);
    qfB[ds] = *(const bf16x8*)(QbB + l31 * HD_ + ds * 16 + hi * 8);
  }

  f32x16 aA0 = {}, aA1 = {}, aB0 = {}, aB1 = {};    // O^T partials per chunk
  float lhA = 0.f, lhB = 0.f;
  const int xorb = l31 & 7;

  const f32x16 sinit = {-SHIFT_, -SHIFT_, -SHIFT_, -SHIFT_,
                        -SHIFT_, -SHIFT_, -SHIFT_, -SHIFT_,
                        -SHIFT_, -SHIFT_, -SHIFT_, -SHIFT_,
                        -SHIFT_, -SHIFT_, -SHIFT_, -SHIFT_};

  auto softmax_pack = [&](const f32x16 &sacc, bool diag, float &lh,
                          bf16x8 &pf0, bf16x8 &pf1) {
    float p[16];
#pragma unroll
    for (int r = 0; r < 16; ++r) {
      float sc = sacc[r];
      if (diag) {
        int kvpos = (r & 3) + 8 * (r >> 2) + 4 * hi;
        if (kvpos > l31) sc = -1e30f;
      }
      p[r] = __builtin_amdgcn_exp2f(sc);
    }
    float t0 = (p[0] + p[1]) + (p[2] + p[3]);
    float t1 = (p[4] + p[5]) + (p[6] + p[7]);
    float t2 = (p[8] + p[9]) + (p[10] + p[11]);
    float t3 = (p[12] + p[13]) + (p[14] + p[15]);
    lh += (t0 + t1) + (t2 + t3);
    u32 pk[8];
#pragma unroll
    for (int i = 0; i < 8; ++i) pk[i] = pkbf(p[2*i], p[2*i+1]);
    u32 a0 = pk[0], b0 = pk[2]; pl32swap(a0, b0);
    u32 a1 = pk[1], b1 = pk[3]; pl32swap(a1, b1);
    u32 a2 = pk[4], b2 = pk[6]; pl32swap(a2, b2);
    u32 a3 = pk[5], b3 = pk[7]; pl32swap(a3, b3);
    pf0 = __builtin_bit_cast(bf16x8, (u32x4){a0, a1, b0, b1});
    pf1 = __builtin_bit_cast(bf16x8, (u32x4){a2, a3, b2, b3});
  };

  stage(0);
  stage(1);

  for (int t = 0; t < NT; ++t) {
    asm volatile("s_waitcnt vmcnt(4)" ::: "memory");
    __syncthreads();
    stage(t + 2);
    const char* KsB = (const char*)Ks + (t % 3) * 8192;
    const char* VsB = (const char*)Vs + (t % 3) * 8192;
#pragma unroll
    for (int sub = 0; sub < 2; ++sub) {
      const int kvbase = t * 64 + sub * 32;
      if (kvbase <= q0B) {
        const bool actA = (kvbase <= q0A);
        const char* Kbase = KsB + (sub * 32 + l31) * 128;
        bf16x8 kf[4];
#pragma unroll
        for (int ds = 0; ds < 4; ++ds)
          kf[ds] = *(const bf16x8*)(Kbase + ((((ds << 1) + hi) ^ xorb) << 4));
        f32x16 sA = sinit, sB = sinit;
        __builtin_amdgcn_s_setprio(1);
#pragma unroll
        for (int ds = 0; ds < 4; ++ds)
          sB = __builtin_amdgcn_mfma_f32_32x32x16_bf16(kf[ds], qfB[ds], sB, 0, 0, 0);
        if (actA) {
#pragma unroll
          for (int ds = 0; ds < 4; ++ds)
            sA = __builtin_amdgcn_mfma_f32_32x32x16_bf16(kf[ds], qfA[ds], sA, 0, 0, 0);
        }
        __builtin_amdgcn_s_setprio(0);
        bf16x8 pA0, pA1, pB0, pB1;
        softmax_pack(sB, kvbase == q0B, lhB, pB0, pB1);
        if (actA) softmax_pack(sA, kvbase == q0A, lhA, pA0, pA1);
        const char* Vb0 = VsB + l31 * 128;
        const char* Vb1 = VsB + (32 + l31) * 128;
        const int c0 = (sub << 2) + hi;
        const int c1 = c0 + 2;
        bf16x8 v00 = *(const bf16x8*)(Vb0 + ((c0 ^ xorb) << 4));
        bf16x8 v01 = *(const bf16x8*)(Vb0 + ((c1 ^ xorb) << 4));
        bf16x8 v10 = *(const bf16x8*)(Vb1 + ((c0 ^ xorb) << 4));
        bf16x8 v11 = *(const bf16x8*)(Vb1 + ((c1 ^ xorb) << 4));
        __builtin_amdgcn_s_setprio(1);
        aB0 = __builtin_amdgcn_mfma_f32_32x32x16_bf16(v00, pB0, aB0, 0, 0, 0);
        aB1 = __builtin_amdgcn_mfma_f32_32x32x16_bf16(v10, pB0, aB1, 0, 0, 0);
        aB0 = __builtin_amdgcn_mfma_f32_32x32x16_bf16(v01, pB1, aB0, 0, 0, 0);
        aB1 = __builtin_amdgcn_mfma_f32_32x32x16_bf16(v11, pB1, aB1, 0, 0, 0);
        if (actA) {
          aA0 = __builtin_amdgcn_mfma_f32_32x32x16_bf16(v00, pA0, aA0, 0, 0, 0);
          aA1 = __builtin_amdgcn_mfma_f32_32x32x16_bf16(v10, pA0, aA1, 0, 0, 0);
          aA0 = __builtin_amdgcn_mfma_f32_32x32x16_bf16(v01, pA1, aA0, 0, 0, 0);
          aA1 = __builtin_amdgcn_mfma_f32_32x32x16_bf16(v11, pA1, aA1, 0, 0, 0);
        }
        __builtin_amdgcn_s_setprio(0);
      }
    }
  }

  asm volatile("s_waitcnt vmcnt(0)" ::: "memory");

  auto epi = [&](const f32x16 &a0, const f32x16 &a1, float lh, int q0) {
    float l = lh + __shfl_xor(lh, 32);
    const float rl = 1.f / l;
    const int64_t row = (int64_t)(b * S_ + q0 + l31);
#pragma unroll
    for (int dt = 0; dt < 2; ++dt) {
#pragma unroll
      for (int g = 0; g < 4; ++g) {
        bf16x4 ov;
#pragma unroll
        for (int j = 0; j < 4; ++j) {
          float val = (dt ? a1[4*g + j] : a0[4*g + j]) * rl;
          ov[j] = (bf16_t)val;
        }
        const int d0 = dt * 32 + g * 8 + hi * 4;
        *(bf16x4*)(AO + row * D_ + h * HD_ + d0) = ov;
      }
    }
  };
  epi(aA0, aA1, lhA, q0A);
  epi(aB0, aB1, lhB, q0B);
}

// ---------------- launcher ----------------
extern "C" void kernel_launch(void* const* d_in, const int* in_sizes, int n_in,
                              void* d_out, int out_size, void* d_ws, size_t ws_size,
                              hipStream_t stream) {
  const float* x    = (const float*)d_in[0];
  const float* cosb = (const float*)d_in[1];
  const float* sinb = (const float*)d_in[2];
  const float* Wq   = (const float*)d_in[3];
  const float* Wk   = (const float*)d_in[4];
  const float* Wv   = (const float*)d_in[5];
  const float* Wo   = (const float*)d_in[6];
  float* out = (float*)d_out;

  bf16_t* ws = (bf16_t*)d_ws;
  size_t o = 0;
  bf16_t* xb    = ws + o; o += (size_t)4096 * 2048;
  bf16_t* Wqkvt = ws + o; o += (size_t)3072 * 2048;
  bf16_t* Wot   = ws + o; o += (size_t)2048 * 2048;
  bf16_t* qkv   = ws + o; o += (size_t)4096 * 3072;
  bf16_t* Qr    = ws + o; o += (size_t)B_ * H_ * S_ * HD_;
  bf16_t* Krb   = ws + o; o += (size_t)B_ * KV_ * S_ * HD_;
  bf16_t* Vtb   = ws + o; o += (size_t)B_ * KV_ * S_ * HD_;
  bf16_t* AO    = ws + o; o += (size_t)4096 * 2048;

  cvt_f32_bf16<<<(8388608/4 + 255)/256, 256, 0, stream>>>(x, xb, 8388608/4);
  transpose_cvt<<<dim3(2048/32, 2048/32), dim3(32, 8), 0, stream>>>(Wq, Wqkvt, 2048, 0);
  transpose_cvt<<<dim3(512/32, 2048/32),  dim3(32, 8), 0, stream>>>(Wk, Wqkvt, 512, 2048);
  transpose_cvt<<<dim3(512/32, 2048/32),  dim3(32, 8), 0, stream>>>(Wv, Wqkvt, 512, 2560);
  transpose_cvt<<<dim3(2048/32, 2048/32), dim3(32, 8), 0, stream>>>(Wo, Wot, 2048, 0);
  // QKV projection: BN=192 -> grid 16x16 = 256 blocks = exactly 1/CU
  gemm256<192, 2, bf16_t><<<dim3(3072/192, 4096/256), 512, 0, stream>>>(
      xb, Wqkvt, qkv, 3072, 2048);
  // RoPE + scatter (vectorized), V transpose
  rope_scatter2<<<4096, 256, 0, stream>>>(qkv, cosb, sinb, Qr, Krb);
  v_transpose<<<dim3(16, 64, 2), dim3(32, 8), 0, stream>>>(qkv, Vtb);
  // paired-chunk attention (4-wave blocks, 2x K/V reuse, equal-work blocks)
  attn7<<<dim3(16, 32), 256, 0, stream>>>(Qr, Krb, Vtb, AO);
  // output projection -> f32 (BN=128 -> 256 blocks = 1/CU)
  gemm256<128, 0, float><<<dim3(2048/128, 4096/256), 512, 0, stream>>>(
      AO, Wot, out, 2048, 2048);
}

// Round 14
// 178.823 us; speedup vs baseline: 1.0654x; 1.0079x over previous
//
#include <hip/hip_runtime.h>
#include <hip/hip_bf16.h>
#include <stdint.h>

#define B_ 2
#define S_ 2048
#define D_ 2048
#define H_ 32
#define KV_ 8
#define HD_ 64
#define NQKV 3072   // D + 2*KV*HD

typedef __bf16 bf16_t;
typedef __bf16 bf16x8 __attribute__((ext_vector_type(8)));
typedef __bf16 bf16x4 __attribute__((ext_vector_type(4)));
typedef float  f32x4  __attribute__((ext_vector_type(4)));
typedef float  f32x16 __attribute__((ext_vector_type(16)));
typedef unsigned int u32;
typedef u32 u32x4 __attribute__((ext_vector_type(4)));

typedef const __attribute__((address_space(1))) uint32_t* gp1_t;
typedef __attribute__((address_space(3))) uint32_t* lp3_t;

// async global->LDS, 16B per lane. LDS dest is wave-uniform base + lane*16.
__device__ inline void gload_lds16(const void* g, void* l) {
  __builtin_amdgcn_global_load_lds((gp1_t)(uintptr_t)g, (lp3_t)(uint32_t)(uintptr_t)l,
                                   16, 0, 0);
}

__device__ inline u32 pkbf(float a, float b) {
  union { bf16_t h[2]; u32 u; } v;
  v.h[0] = (bf16_t)a; v.h[1] = (bf16_t)b;
  return v.u;
}

// v_permlane32_swap_b32: a = [a_lo, b_lo], b = [a_hi, b_hi]
__device__ inline void pl32swap(u32 &a, u32 &b) {
  asm("v_permlane32_swap_b32 %0, %1" : "+v"(a), "+v"(b));
}

// ---------------- converts ----------------
__global__ void cvt_f32_bf16(const float* __restrict__ in, bf16_t* __restrict__ out, int n4) {
  int i = blockIdx.x * blockDim.x + threadIdx.x;
  if (i < n4) {
    float4 v = ((const float4*)in)[i];
    bf16x4 o;
    o[0] = (bf16_t)v.x; o[1] = (bf16_t)v.y; o[2] = (bf16_t)v.z; o[3] = (bf16_t)v.w;
    ((bf16x4*)out)[i] = o;
  }
}

// transpose + cast: out[row_off + c][r] = in[r][c]
__global__ void transpose_cvt(const float* __restrict__ in, bf16_t* __restrict__ out,
                              int C, int row_off) {
  __shared__ float t[32][33];
  int tx = threadIdx.x, ty = threadIdx.y;       // (32,8)
  int c0 = blockIdx.x * 32, r0 = blockIdx.y * 32;
#pragma unroll
  for (int j = 0; j < 4; ++j)
    t[ty + j*8][tx] = in[(int64_t)(r0 + ty + j*8) * C + c0 + tx];
  __syncthreads();
#pragma unroll
  for (int j = 0; j < 4; ++j)
    out[(int64_t)(row_off + c0 + ty + j*8) * 2048 + r0 + tx] = (bf16_t)t[tx][ty + j*8];
}

// V region of qkv -> Vt[b][kvh][d][s]  (LDS-tiled transpose, coalesced both sides)
__global__ void v_transpose(const bf16_t* __restrict__ qkv, bf16_t* __restrict__ Vt) {
  __shared__ bf16_t t[32][34];
  const int tx = threadIdx.x, ty = threadIdx.y;   // (32,8)
  const int c0 = blockIdx.x * 32;                 // V col within 512
  const int s0 = blockIdx.y * 32;
  const int b  = blockIdx.z;
#pragma unroll
  for (int j = 0; j < 4; ++j)
    t[ty + j*8][tx] = qkv[(int64_t)(b * S_ + s0 + ty + j*8) * NQKV + 2560 + c0 + tx];
  __syncthreads();
#pragma unroll
  for (int j = 0; j < 4; ++j)
    Vt[(int64_t)(b * 512 + c0 + ty + j*8) * S_ + s0 + tx] = t[tx][ty + j*8];
}

// ---------------- vectorized RoPE scatter (Q scaled by 0.125*log2e) ----------------
#define QSCALE 0.18033688011112042f
__global__ __launch_bounds__(256) void rope_scatter2(const bf16_t* __restrict__ qkv,
                                                     const float* __restrict__ cosb,
                                                     const float* __restrict__ sinb,
                                                     bf16_t* __restrict__ Q,
                                                     bf16_t* __restrict__ Kr) {
  const int row = blockIdx.x;            // b*S + s
  const int b = row >> 11, s = row & 2047;
  const bf16_t* src = qkv + (int64_t)row * NQKV;
  const float* cs = cosb + s * HD_;
  const float* sn = sinb + s * HD_;
  const int tid = threadIdx.x;
  {                                      // Q: 2048 elems = 256 vectors
    const int c0 = tid * 8;
    const int d0 = c0 & 63, h = c0 >> 6;
    bf16x8 own = *(const bf16x8*)(src + c0);
    bf16x8 par = *(const bf16x8*)(src + (c0 ^ 32));
    const float sgn = (d0 & 32) ? 1.f : -1.f;
    bf16x8 o;
#pragma unroll
    for (int j = 0; j < 8; ++j) {
      const int d = d0 + j;
      float val = (float)own[j] * cs[d] + sgn * (float)par[j] * sn[d];
      o[j] = (bf16_t)(val * QSCALE);
    }
    *(bf16x8*)(Q + ((int64_t)(b * H_ + h) * S_ + s) * HD_ + d0) = o;
  }
  if (tid < 64) {                        // K: 512 elems = 64 vectors
    const int c0 = 2048 + tid * 8;
    const int d0 = (tid * 8) & 63, kvh = tid >> 3;
    bf16x8 own = *(const bf16x8*)(src + c0);
    bf16x8 par = *(const bf16x8*)(src + (c0 ^ 32));
    const float sgn = (d0 & 32) ? 1.f : -1.f;
    bf16x8 o;
#pragma unroll
    for (int j = 0; j < 8; ++j) {
      const int d = d0 + j;
      float val = (float)own[j] * cs[d] + sgn * (float)par[j] * sn[d];
      o[j] = (bf16_t)val;
    }
    *(bf16x8*)(Kr + ((int64_t)(b * KV_ + kvh) * S_ + s) * HD_ + d0) = o;
  }
}

// ---------------- 256-row deep-pipelined GEMM (dedup'd reads + XCD swizzle) ----------------
// BM=256, BK=64, 8 waves (2M x 4N). EPI=0: f32 C. EPI=2: bf16 row-major C.
// Grid must have (gridDim.x*gridDim.y) % 8 == 0 for the bijective XCD swizzle.
template <int BN, int EPI, typename OutT>
__global__ __launch_bounds__(512, 2) void gemm256(const bf16_t* __restrict__ A,
                                                  const bf16_t* __restrict__ Bt,
                                                  OutT* __restrict__ Cout,
                                                  int N, int K) {
  constexpr int NB = BN / 64;          // B stage loads per tile (3 or 2)
  constexpr int LT = 4 + NB;           // total stage loads per tile (7 or 6)
  constexpr int WCOLS = BN / 4;        // per-wave cols (48 or 32)
  constexpr int NF = WCOLS / 16;       // per-wave n fragments (3 or 2)

  __shared__ bf16_t As[2][256 * 64];
  __shared__ bf16_t Bs[2][BN * 64];

  const int tid = threadIdx.x;
  const int w = tid >> 6, lane = tid & 63;
  const int l15 = lane & 15, l4 = lane >> 4;
  const int wr = w >> 2, wc = w & 3;

  // XCD-bijective swizzle: blocks with orig%8 == j (XCD j) get a contiguous tile range
  const int nX = gridDim.x;
  const int lin = blockIdx.y * nX + blockIdx.x;
  const int cpx = (nX * gridDim.y) >> 3;
  const int swz = (lin & 7) * cpx + (lin >> 3);
  const int bm = (swz / nX) * 256, bn = (swz % nX) * BN;

  // staging source (pre-swizzled): row = L*64 + w*8 + lane>>3; granule = (lane&7)^(row&7)
  const int rw = w * 8 + (lane >> 3);
  const int srcg = ((lane & 7) ^ ((lane >> 3) & 7)) << 3;   // element offset
  const bf16_t* PA[4];
  const bf16_t* PB[NB];
#pragma unroll
  for (int L = 0; L < 4; ++L)
    PA[L] = A + (int64_t)(bm + L * 64 + rw) * K + srcg;
#pragma unroll
  for (int L = 0; L < NB; ++L)
    PB[L] = Bt + (int64_t)(bn + L * 64 + rw) * K + srcg;

  const int NK = K >> 6;
  const int xr = l15 & 7;
  const int g0 = (l4 ^ xr) << 3;          // kk=0 slot, element offset
  const int g1 = ((4 + l4) ^ xr) << 3;    // kk=1 slot

  f32x4 acc[8][NF] = {};

  auto stage = [&](int s, int buf, int toff) {
    if (s < 4) gload_lds16(PA[s] + toff, &As[buf][s * 4096 + w * 512]);
    else       gload_lds16(PB[s - 4] + toff, &Bs[buf][(s - 4) * 4096 + w * 512]);
  };

  // prologue: stage tile 0 into buf 0
#pragma unroll
  for (int s = 0; s < LT; ++s) stage(s, 0, 0);
  asm volatile("s_waitcnt vmcnt(0)" ::: "memory");
  __syncthreads();

  for (int t = 0; t < NK; ++t) {
    const int p = t & 1;
    const bool more = (t + 1) < NK;
    const int toff = (t + 1) << 6;
    const bf16_t* Ab = &As[p][0];
    const bf16_t* Bb = &Bs[p][0];

    // hoist ALL B fragments for this tile
    bf16x8 ball[NF][2];
#pragma unroll
    for (int nn = 0; nn < NF; ++nn) {
      const int rb = wc * WCOLS + nn * 16 + l15;
      ball[nn][0] = *(const bf16x8*)(Bb + rb * 64 + g0);
      ball[nn][1] = *(const bf16x8*)(Bb + rb * 64 + g1);
    }

#pragma unroll
    for (int mh = 0; mh < 2; ++mh) {
      if (more) {
        const int sb = mh * (LT / 2);
        const int se = (mh == 0) ? (LT / 2) : LT;
#pragma unroll
        for (int s = sb; s < se; ++s) stage(s, p ^ 1, toff);
      }
      bf16x8 af[4][2];
#pragma unroll
      for (int mm = 0; mm < 4; ++mm) {
        const int ra = wr * 128 + (mh * 4 + mm) * 16 + l15;
        af[mm][0] = *(const bf16x8*)(Ab + ra * 64 + g0);
        af[mm][1] = *(const bf16x8*)(Ab + ra * 64 + g1);
      }
      __builtin_amdgcn_s_setprio(1);
#pragma unroll
      for (int mm = 0; mm < 4; ++mm)
#pragma unroll
        for (int nn = 0; nn < NF; ++nn) {
          acc[mh*4+mm][nn] = __builtin_amdgcn_mfma_f32_16x16x32_bf16(
              af[mm][0], ball[nn][0], acc[mh*4+mm][nn], 0, 0, 0);
          acc[mh*4+mm][nn] = __builtin_amdgcn_mfma_f32_16x16x32_bf16(
              af[mm][1], ball[nn][1], acc[mh*4+mm][nn], 0, 0, 0);
        }
      __builtin_amdgcn_s_setprio(0);
    }
    if (more) {
      asm volatile("s_waitcnt vmcnt(0)" ::: "memory");
      __syncthreads();
    }
  }

#pragma unroll
  for (int m = 0; m < 8; ++m) {
    const int row = bm + wr * 128 + m * 16 + l4 * 4;
#pragma unroll
    for (int n = 0; n < NF; ++n) {
      const int col = bn + wc * WCOLS + n * 16 + l15;
#pragma unroll
      for (int r = 0; r < 4; ++r)
        Cout[(int64_t)(row + r) * N + col] = (OutT)acc[m][n][r];
    }
  }
}

// ---------------- flash attention: paired chunks + MFMA-computed denominators ----------------
// grid (16 = b*8+kvh, 32 = y). 4 waves; wave w = head kvh*4+w, chunks {y, 63-y}.
// Denominator sum_k P[k][q] computed on the MFMA pipe via mfma(ones, P_frag, acc)
// (VALU was the critical pipe at 51%). Softmax_A issues while PV_B MFMAs in flight.
#define SHIFT_ 8.0f
__global__ __launch_bounds__(256, 2) void attn8(const bf16_t* __restrict__ Q,
                                                const bf16_t* __restrict__ Kr,
                                                const bf16_t* __restrict__ Vt,
                                                bf16_t* __restrict__ AO) {
  const int bk = blockIdx.x;
  const int b = bk >> 3, kvh = bk & 7;
  const int y = blockIdx.y;               // 0..31
  const int q0A = y * 32, q0B = (63 - y) * 32;
  const int tid = threadIdx.x;
  const int w = tid >> 6, lane = tid & 63;
  const int l31 = lane & 31, hi = lane >> 5;
  const int h = kvh * 4 + w;

  __shared__ __align__(16) bf16_t Ks[3][64 * 64];   // [buf][kv][d] (swizzled granules)
  __shared__ __align__(16) bf16_t Vs[3][64 * 64];   // [buf][d][kv]

  const bf16_t* Kg = Kr + (int64_t)(b * KV_ + kvh) * S_ * HD_;
  const bf16_t* Vg = Vt + (int64_t)(b * KV_ + kvh) * HD_ * S_;   // [d][s]

  const int rL = (w << 3) + (lane >> 3);
  const int sgr = ((lane & 7) ^ (rL & 7)) << 3;     // element offset
  const bf16_t* Ksrc = Kg + (int64_t)rL * HD_ + sgr;
  const bf16_t* Vsrc = Vg + (int64_t)rL * S_ + sgr;

  const int NT = (63 - y) / 2 + 1;        // 64-kv tiles (chunk B reach)

  auto stage = [&](int t) {               // exactly 4 loads per wave (uniform vmcnt)
    const int tc = (t < NT) ? t : (NT - 1);
    char* Kd = (char*)Ks + (t % 3) * 8192 + w * 1024;
    char* Vd = (char*)Vs + (t % 3) * 8192 + w * 1024;
    gload_lds16(Ksrc + (int64_t)tc * 64 * HD_, Kd);
    gload_lds16(Ksrc + (int64_t)(tc * 64 + 32) * HD_, Kd + 4096);
    gload_lds16(Vsrc + tc * 64, Vd);
    gload_lds16(Vsrc + (int64_t)32 * S_ + tc * 64, Vd + 4096);
  };

  const bf16_t* QbA = Q + ((int64_t)(b * H_ + h) * S_ + q0A) * HD_;
  const bf16_t* QbB = Q + ((int64_t)(b * H_ + h) * S_ + q0B) * HD_;
  bf16x8 qfA[4], qfB[4];
#pragma unroll
  for (int ds = 0; ds < 4; ++ds) {
    qfA[ds] = *(const bf16x8*)(QbA + l31 * HD_ + ds * 16 + hi * 8);
    qfB[ds] = *(const bf16x8*)(QbB + l31 * HD_ + ds * 16 + hi * 8);
  }

  bf16x8 onesf;
#pragma unroll
  for (int i = 0; i < 8; ++i) onesf[i] = (bf16_t)1.0f;

  f32x16 aA0 = {}, aA1 = {}, aB0 = {}, aB1 = {};    // O^T partials per chunk
  f32x16 lA = {}, lB = {};                          // denominators (all regs equal)
  const int xorb = l31 & 7;

  const f32x16 sinit = {-SHIFT_, -SHIFT_, -SHIFT_, -SHIFT_,
                        -SHIFT_, -SHIFT_, -SHIFT_, -SHIFT_,
                        -SHIFT_, -SHIFT_, -SHIFT_, -SHIFT_,
                        -SHIFT_, -SHIFT_, -SHIFT_, -SHIFT_};

  auto softmax_pack = [&](const f32x16 &sacc, bool diag,
                          bf16x8 &pf0, bf16x8 &pf1) {
    float p[16];
#pragma unroll
    for (int r = 0; r < 16; ++r) {
      float sc = sacc[r];
      if (diag) {
        int kvpos = (r & 3) + 8 * (r >> 2) + 4 * hi;
        if (kvpos > l31) sc = -1e30f;
      }
      p[r] = __builtin_amdgcn_exp2f(sc);
    }
    u32 pk[8];
#pragma unroll
    for (int i = 0; i < 8; ++i) pk[i] = pkbf(p[2*i], p[2*i+1]);
    u32 a0 = pk[0], b0 = pk[2]; pl32swap(a0, b0);
    u32 a1 = pk[1], b1 = pk[3]; pl32swap(a1, b1);
    u32 a2 = pk[4], b2 = pk[6]; pl32swap(a2, b2);
    u32 a3 = pk[5], b3 = pk[7]; pl32swap(a3, b3);
    pf0 = __builtin_bit_cast(bf16x8, (u32x4){a0, a1, b0, b1});
    pf1 = __builtin_bit_cast(bf16x8, (u32x4){a2, a3, b2, b3});
  };

  stage(0);
  stage(1);

  for (int t = 0; t < NT; ++t) {
    asm volatile("s_waitcnt vmcnt(4)" ::: "memory");
    __syncthreads();
    stage(t + 2);
    const char* KsB = (const char*)Ks + (t % 3) * 8192;
    const char* VsB = (const char*)Vs + (t % 3) * 8192;
#pragma unroll
    for (int sub = 0; sub < 2; ++sub) {
      const int kvbase = t * 64 + sub * 32;
      if (kvbase <= q0B) {
        const bool actA = (kvbase <= q0A);
        // ---- shared K fragments + both QK chains (MFMA in flight) ----
        const char* Kbase = KsB + (sub * 32 + l31) * 128;
        bf16x8 kf[4];
#pragma unroll
        for (int ds = 0; ds < 4; ++ds)
          kf[ds] = *(const bf16x8*)(Kbase + ((((ds << 1) + hi) ^ xorb) << 4));
        f32x16 sA = sinit, sB = sinit;
        __builtin_amdgcn_s_setprio(1);
#pragma unroll
        for (int ds = 0; ds < 4; ++ds)
          sB = __builtin_amdgcn_mfma_f32_32x32x16_bf16(kf[ds], qfB[ds], sB, 0, 0, 0);
        if (actA) {
#pragma unroll
          for (int ds = 0; ds < 4; ++ds)
            sA = __builtin_amdgcn_mfma_f32_32x32x16_bf16(kf[ds], qfA[ds], sA, 0, 0, 0);
        }
        __builtin_amdgcn_s_setprio(0);
        // ---- V fragments (issue early; latency hides under softmax VALU) ----
        const char* Vb0 = VsB + l31 * 128;
        const char* Vb1 = VsB + (32 + l31) * 128;
        const int c0 = (sub << 2) + hi;
        const int c1 = c0 + 2;
        bf16x8 v00 = *(const bf16x8*)(Vb0 + ((c0 ^ xorb) << 4));
        bf16x8 v01 = *(const bf16x8*)(Vb0 + ((c1 ^ xorb) << 4));
        bf16x8 v10 = *(const bf16x8*)(Vb1 + ((c0 ^ xorb) << 4));
        bf16x8 v11 = *(const bf16x8*)(Vb1 + ((c1 ^ xorb) << 4));
        // ---- softmax_B (VALU, overlaps QK_A latency) -> PV_B (MFMA) ----
        bf16x8 pB0, pB1;
        softmax_pack(sB, kvbase == q0B, pB0, pB1);
        __builtin_amdgcn_s_setprio(1);
        aB0 = __builtin_amdgcn_mfma_f32_32x32x16_bf16(v00, pB0, aB0, 0, 0, 0);
        aB1 = __builtin_amdgcn_mfma_f32_32x32x16_bf16(v10, pB0, aB1, 0, 0, 0);
        aB0 = __builtin_amdgcn_mfma_f32_32x32x16_bf16(v01, pB1, aB0, 0, 0, 0);
        aB1 = __builtin_amdgcn_mfma_f32_32x32x16_bf16(v11, pB1, aB1, 0, 0, 0);
        lB  = __builtin_amdgcn_mfma_f32_32x32x16_bf16(onesf, pB0, lB, 0, 0, 0);
        lB  = __builtin_amdgcn_mfma_f32_32x32x16_bf16(onesf, pB1, lB, 0, 0, 0);
        __builtin_amdgcn_s_setprio(0);
        // ---- softmax_A (VALU, overlaps PV_B) -> PV_A (MFMA) ----
        if (actA) {
          bf16x8 pA0, pA1;
          softmax_pack(sA, kvbase == q0A, pA0, pA1);
          __builtin_amdgcn_s_setprio(1);
          aA0 = __builtin_amdgcn_mfma_f32_32x32x16_bf16(v00, pA0, aA0, 0, 0, 0);
          aA1 = __builtin_amdgcn_mfma_f32_32x32x16_bf16(v10, pA0, aA1, 0, 0, 0);
          aA0 = __builtin_amdgcn_mfma_f32_32x32x16_bf16(v01, pA1, aA0, 0, 0, 0);
          aA1 = __builtin_amdgcn_mfma_f32_32x32x16_bf16(v11, pA1, aA1, 0, 0, 0);
          lA  = __builtin_amdgcn_mfma_f32_32x32x16_bf16(onesf, pA0, lA, 0, 0, 0);
          lA  = __builtin_amdgcn_mfma_f32_32x32x16_bf16(onesf, pA1, lA, 0, 0, 0);
          __builtin_amdgcn_s_setprio(0);
        }
      }
    }
  }

  asm volatile("s_waitcnt vmcnt(0)" ::: "memory");

  auto epi = [&](const f32x16 &a0, const f32x16 &a1, float denom, int q0) {
    const float rl = 1.f / denom;
    const int64_t row = (int64_t)(b * S_ + q0 + l31);
#pragma unroll
    for (int dt = 0; dt < 2; ++dt) {
#pragma unroll
      for (int g = 0; g < 4; ++g) {
        bf16x4 ov;
#pragma unroll
        for (int j = 0; j < 4; ++j) {
          float val = (dt ? a1[4*g + j] : a0[4*g + j]) * rl;
          ov[j] = (bf16_t)val;
        }
        const int d0 = dt * 32 + g * 8 + hi * 4;
        *(bf16x4*)(AO + row * D_ + h * HD_ + d0) = ov;
      }
    }
  };
  epi(aA0, aA1, lA[0], q0A);
  epi(aB0, aB1, lB[0], q0B);
}

// ---------------- launcher ----------------
extern "C" void kernel_launch(void* const* d_in, const int* in_sizes, int n_in,
                              void* d_out, int out_size, void* d_ws, size_t ws_size,
                              hipStream_t stream) {
  const float* x    = (const float*)d_in[0];
  const float* cosb = (const float*)d_in[1];
  const float* sinb = (const float*)d_in[2];
  const float* Wq   = (const float*)d_in[3];
  const float* Wk   = (const float*)d_in[4];
  const float* Wv   = (const float*)d_in[5];
  const float* Wo   = (const float*)d_in[6];
  float* out = (float*)d_out;

  bf16_t* ws = (bf16_t*)d_ws;
  size_t o = 0;
  bf16_t* xb    = ws + o; o += (size_t)4096 * 2048;
  bf16_t* Wqkvt = ws + o; o += (size_t)3072 * 2048;
  bf16_t* Wot   = ws + o; o += (size_t)2048 * 2048;
  bf16_t* qkv   = ws + o; o += (size_t)4096 * 3072;
  bf16_t* Qr    = ws + o; o += (size_t)B_ * H_ * S_ * HD_;
  bf16_t* Krb   = ws + o; o += (size_t)B_ * KV_ * S_ * HD_;
  bf16_t* Vtb   = ws + o; o += (size_t)B_ * KV_ * S_ * HD_;
  bf16_t* AO    = ws + o; o += (size_t)4096 * 2048;

  cvt_f32_bf16<<<(8388608/4 + 255)/256, 256, 0, stream>>>(x, xb, 8388608/4);
  transpose_cvt<<<dim3(2048/32, 2048/32), dim3(32, 8), 0, stream>>>(Wq, Wqkvt, 2048, 0);
  transpose_cvt<<<dim3(512/32, 2048/32),  dim3(32, 8), 0, stream>>>(Wk, Wqkvt, 512, 2048);
  transpose_cvt<<<dim3(512/32, 2048/32),  dim3(32, 8), 0, stream>>>(Wv, Wqkvt, 512, 2560);
  transpose_cvt<<<dim3(2048/32, 2048/32), dim3(32, 8), 0, stream>>>(Wo, Wot, 2048, 0);
  // QKV projection: BN=192 -> grid 16x16 = 256 blocks = exactly 1/CU, XCD-swizzled
  gemm256<192, 2, bf16_t><<<dim3(3072/192, 4096/256), 512, 0, stream>>>(
      xb, Wqkvt, qkv, 3072, 2048);
  // RoPE + scatter (vectorized), V transpose
  rope_scatter2<<<4096, 256, 0, stream>>>(qkv, cosb, sinb, Qr, Krb);
  v_transpose<<<dim3(16, 64, 2), dim3(32, 8), 0, stream>>>(qkv, Vtb);
  // paired-chunk attention with MFMA denominators
  attn8<<<dim3(16, 32), 256, 0, stream>>>(Qr, Krb, Vtb, AO);
  // output projection -> f32 (BN=128 -> 256 blocks = 1/CU, XCD-swizzled)
  gemm256<128, 0, float><<<dim3(2048/128, 4096/256), 512, 0, stream>>>(
      AO, Wot, out, 2048, 2048);
}

// Round 15
// 174.812 us; speedup vs baseline: 1.0898x; 1.0229x over previous
//
#include <hip/hip_runtime.h>
#include <hip/hip_bf16.h>
#include <stdint.h>

#define B_ 2
#define S_ 2048
#define D_ 2048
#define H_ 32
#define KV_ 8
#define HD_ 64
#define NQKV 3072   // D + 2*KV*HD

typedef __bf16 bf16_t;
typedef __bf16 bf16x8 __attribute__((ext_vector_type(8)));
typedef __bf16 bf16x4 __attribute__((ext_vector_type(4)));
typedef float  f32x4  __attribute__((ext_vector_type(4)));
typedef float  f32x16 __attribute__((ext_vector_type(16)));
typedef unsigned int u32;
typedef u32 u32x4 __attribute__((ext_vector_type(4)));

typedef const __attribute__((address_space(1))) uint32_t* gp1_t;
typedef __attribute__((address_space(3))) uint32_t* lp3_t;

// async global->LDS, 16B per lane. LDS dest is wave-uniform base + lane*16.
__device__ inline void gload_lds16(const void* g, void* l) {
  __builtin_amdgcn_global_load_lds((gp1_t)(uintptr_t)g, (lp3_t)(uint32_t)(uintptr_t)l,
                                   16, 0, 0);
}

__device__ inline u32 pkbf(float a, float b) {
  union { bf16_t h[2]; u32 u; } v;
  v.h[0] = (bf16_t)a; v.h[1] = (bf16_t)b;
  return v.u;
}

// v_permlane32_swap_b32: a = [a_lo, b_lo], b = [a_hi, b_hi]
__device__ inline void pl32swap(u32 &a, u32 &b) {
  asm("v_permlane32_swap_b32 %0, %1" : "+v"(a), "+v"(b));
}

// ---------------- converts ----------------
__global__ void cvt_f32_bf16(const float* __restrict__ in, bf16_t* __restrict__ out, int n4) {
  int i = blockIdx.x * blockDim.x + threadIdx.x;
  if (i < n4) {
    float4 v = ((const float4*)in)[i];
    bf16x4 o;
    o[0] = (bf16_t)v.x; o[1] = (bf16_t)v.y; o[2] = (bf16_t)v.z; o[3] = (bf16_t)v.w;
    ((bf16x4*)out)[i] = o;
  }
}

// all 4 weight transposes in one launch: out[row_off + c][r] = in[r][c]
__global__ void transpose_cvt_all(const float* __restrict__ Wq, const float* __restrict__ Wk,
                                  const float* __restrict__ Wv, const float* __restrict__ Wo,
                                  bf16_t* __restrict__ Wqkvt, bf16_t* __restrict__ Wot) {
  __shared__ float t[32][33];
  const int id = blockIdx.x;
  const float* in; bf16_t* out; int C, roff, bx, by;
  if (id < 4096)      { in = Wq; out = Wqkvt; C = 2048; roff = 0;    bx = id & 63;          by = id >> 6; }
  else if (id < 5120) { in = Wk; out = Wqkvt; C = 512;  roff = 2048; bx = (id - 4096) & 15; by = (id - 4096) >> 4; }
  else if (id < 6144) { in = Wv; out = Wqkvt; C = 512;  roff = 2560; bx = (id - 5120) & 15; by = (id - 5120) >> 4; }
  else                { in = Wo; out = Wot;   C = 2048; roff = 0;    bx = (id - 6144) & 63; by = (id - 6144) >> 6; }
  const int tx = threadIdx.x, ty = threadIdx.y;   // (32,8)
  const int c0 = bx * 32, r0 = by * 32;
#pragma unroll
  for (int j = 0; j < 4; ++j)
    t[ty + j*8][tx] = in[(int64_t)(r0 + ty + j*8) * C + c0 + tx];
  __syncthreads();
#pragma unroll
  for (int j = 0; j < 4; ++j)
    out[(int64_t)(roff + c0 + ty + j*8) * 2048 + r0 + tx] = (bf16_t)t[tx][ty + j*8];
}

// V region of qkv -> Vt[b][kvh][d][s]  (LDS-tiled transpose, coalesced both sides)
__global__ void v_transpose(const bf16_t* __restrict__ qkv, bf16_t* __restrict__ Vt) {
  __shared__ bf16_t t[32][34];
  const int tx = threadIdx.x, ty = threadIdx.y;   // (32,8)
  const int c0 = blockIdx.x * 32;                 // V col within 512
  const int s0 = blockIdx.y * 32;
  const int b  = blockIdx.z;
#pragma unroll
  for (int j = 0; j < 4; ++j)
    t[ty + j*8][tx] = qkv[(int64_t)(b * S_ + s0 + ty + j*8) * NQKV + 2560 + c0 + tx];
  __syncthreads();
#pragma unroll
  for (int j = 0; j < 4; ++j)
    Vt[(int64_t)(b * 512 + c0 + ty + j*8) * S_ + s0 + tx] = t[tx][ty + j*8];
}

// ---------------- vectorized RoPE scatter (Q scaled by 0.125*log2e) ----------------
#define QSCALE 0.18033688011112042f
__global__ __launch_bounds__(256) void rope_scatter2(const bf16_t* __restrict__ qkv,
                                                     const float* __restrict__ cosb,
                                                     const float* __restrict__ sinb,
                                                     bf16_t* __restrict__ Q,
                                                     bf16_t* __restrict__ Kr) {
  const int row = blockIdx.x;            // b*S + s
  const int b = row >> 11, s = row & 2047;
  const bf16_t* src = qkv + (int64_t)row * NQKV;
  const float* cs = cosb + s * HD_;
  const float* sn = sinb + s * HD_;
  const int tid = threadIdx.x;
  {                                      // Q: 2048 elems = 256 vectors
    const int c0 = tid * 8;
    const int d0 = c0 & 63, h = c0 >> 6;
    bf16x8 own = *(const bf16x8*)(src + c0);
    bf16x8 par = *(const bf16x8*)(src + (c0 ^ 32));
    const float sgn = (d0 & 32) ? 1.f : -1.f;
    bf16x8 o;
#pragma unroll
    for (int j = 0; j < 8; ++j) {
      const int d = d0 + j;
      float val = (float)own[j] * cs[d] + sgn * (float)par[j] * sn[d];
      o[j] = (bf16_t)(val * QSCALE);
    }
    *(bf16x8*)(Q + ((int64_t)(b * H_ + h) * S_ + s) * HD_ + d0) = o;
  }
  if (tid < 64) {                        // K: 512 elems = 64 vectors
    const int c0 = 2048 + tid * 8;
    const int d0 = (tid * 8) & 63, kvh = tid >> 3;
    bf16x8 own = *(const bf16x8*)(src + c0);
    bf16x8 par = *(const bf16x8*)(src + (c0 ^ 32));
    const float sgn = (d0 & 32) ? 1.f : -1.f;
    bf16x8 o;
#pragma unroll
    for (int j = 0; j < 8; ++j) {
      const int d = d0 + j;
      float val = (float)own[j] * cs[d] + sgn * (float)par[j] * sn[d];
      o[j] = (bf16_t)val;
    }
    *(bf16x8*)(Kr + ((int64_t)(b * KV_ + kvh) * S_ + s) * HD_ + d0) = o;
  }
}

// ---------------- 256-row deep-pipelined GEMM (dedup'd reads + XCD swizzle) ----------------
// BM=256, BK=64, 8 waves (2M x 4N). EPI=0: f32 C. EPI=2: bf16 row-major C.
template <int BN, int EPI, typename OutT>
__global__ __launch_bounds__(512, 2) void gemm256(const bf16_t* __restrict__ A,
                                                  const bf16_t* __restrict__ Bt,
                                                  OutT* __restrict__ Cout,
                                                  int N, int K) {
  constexpr int NB = BN / 64;          // B stage loads per tile (3 or 2)
  constexpr int LT = 4 + NB;           // total stage loads per tile (7 or 6)
  constexpr int WCOLS = BN / 4;        // per-wave cols (48 or 32)
  constexpr int NF = WCOLS / 16;       // per-wave n fragments (3 or 2)

  __shared__ bf16_t As[2][256 * 64];
  __shared__ bf16_t Bs[2][BN * 64];

  const int tid = threadIdx.x;
  const int w = tid >> 6, lane = tid & 63;
  const int l15 = lane & 15, l4 = lane >> 4;
  const int wr = w >> 2, wc = w & 3;

  // XCD-bijective swizzle: blocks with orig%8 == j (XCD j) get a contiguous tile range
  const int nX = gridDim.x;
  const int lin = blockIdx.y * nX + blockIdx.x;
  const int cpx = (nX * gridDim.y) >> 3;
  const int swz = (lin & 7) * cpx + (lin >> 3);
  const int bm = (swz / nX) * 256, bn = (swz % nX) * BN;

  // staging source (pre-swizzled): row = L*64 + w*8 + lane>>3; granule = (lane&7)^(row&7)
  const int rw = w * 8 + (lane >> 3);
  const int srcg = ((lane & 7) ^ ((lane >> 3) & 7)) << 3;   // element offset
  const bf16_t* PA[4];
  const bf16_t* PB[NB];
#pragma unroll
  for (int L = 0; L < 4; ++L)
    PA[L] = A + (int64_t)(bm + L * 64 + rw) * K + srcg;
#pragma unroll
  for (int L = 0; L < NB; ++L)
    PB[L] = Bt + (int64_t)(bn + L * 64 + rw) * K + srcg;

  const int NK = K >> 6;
  const int xr = l15 & 7;
  const int g0 = (l4 ^ xr) << 3;          // kk=0 slot, element offset
  const int g1 = ((4 + l4) ^ xr) << 3;    // kk=1 slot

  f32x4 acc[8][NF] = {};

  auto stage = [&](int s, int buf, int toff) {
    if (s < 4) gload_lds16(PA[s] + toff, &As[buf][s * 4096 + w * 512]);
    else       gload_lds16(PB[s - 4] + toff, &Bs[buf][(s - 4) * 4096 + w * 512]);
  };

  // prologue: stage tile 0 into buf 0
#pragma unroll
  for (int s = 0; s < LT; ++s) stage(s, 0, 0);
  asm volatile("s_waitcnt vmcnt(0)" ::: "memory");
  __syncthreads();

  for (int t = 0; t < NK; ++t) {
    const int p = t & 1;
    const bool more = (t + 1) < NK;
    const int toff = (t + 1) << 6;
    const bf16_t* Ab = &As[p][0];
    const bf16_t* Bb = &Bs[p][0];

    // hoist ALL B fragments for this tile
    bf16x8 ball[NF][2];
#pragma unroll
    for (int nn = 0; nn < NF; ++nn) {
      const int rb = wc * WCOLS + nn * 16 + l15;
      ball[nn][0] = *(const bf16x8*)(Bb + rb * 64 + g0);
      ball[nn][1] = *(const bf16x8*)(Bb + rb * 64 + g1);
    }

#pragma unroll
    for (int mh = 0; mh < 2; ++mh) {
      if (more) {
        const int sb = mh * (LT / 2);
        const int se = (mh == 0) ? (LT / 2) : LT;
#pragma unroll
        for (int s = sb; s < se; ++s) stage(s, p ^ 1, toff);
      }
      bf16x8 af[4][2];
#pragma unroll
      for (int mm = 0; mm < 4; ++mm) {
        const int ra = wr * 128 + (mh * 4 + mm) * 16 + l15;
        af[mm][0] = *(const bf16x8*)(Ab + ra * 64 + g0);
        af[mm][1] = *(const bf16x8*)(Ab + ra * 64 + g1);
      }
      __builtin_amdgcn_s_setprio(1);
#pragma unroll
      for (int mm = 0; mm < 4; ++mm)
#pragma unroll
        for (int nn = 0; nn < NF; ++nn) {
          acc[mh*4+mm][nn] = __builtin_amdgcn_mfma_f32_16x16x32_bf16(
              af[mm][0], ball[nn][0], acc[mh*4+mm][nn], 0, 0, 0);
          acc[mh*4+mm][nn] = __builtin_amdgcn_mfma_f32_16x16x32_bf16(
              af[mm][1], ball[nn][1], acc[mh*4+mm][nn], 0, 0, 0);
        }
      __builtin_amdgcn_s_setprio(0);
    }
    if (more) {
      asm volatile("s_waitcnt vmcnt(0)" ::: "memory");
      __syncthreads();
    }
  }

#pragma unroll
  for (int m = 0; m < 8; ++m) {
    const int row = bm + wr * 128 + m * 16 + l4 * 4;
#pragma unroll
    for (int n = 0; n < NF; ++n) {
      const int col = bn + wc * WCOLS + n * 16 + l15;
#pragma unroll
      for (int r = 0; r < 4; ++r)
        Cout[(int64_t)(row + r) * N + col] = (OutT)acc[m][n][r];
    }
  }
}

// ---------------- flash attention: paired chunks, TRUE counted-vmcnt pipeline ----------------
// grid (16 = b*8+kvh, 32 = y). 4 waves; wave w = head kvh*4+w, chunks {y, 63-y}.
// Raw s_barrier (opaque asm, no compiler vmcnt(0) drain) + explicit
// s_waitcnt vmcnt(4) lgkmcnt(0): tile t+1's 4 loads stay in flight across the
// barrier; loads waited on were issued a full tile (~600cy) earlier.
#define SHIFT_ 8.0f
__global__ __launch_bounds__(256, 2) void attn9(const bf16_t* __restrict__ Q,
                                                const bf16_t* __restrict__ Kr,
                                                const bf16_t* __restrict__ Vt,
                                                bf16_t* __restrict__ AO) {
  const int bk = blockIdx.x;
  const int b = bk >> 3, kvh = bk & 7;
  const int y = blockIdx.y;               // 0..31
  const int q0A = y * 32, q0B = (63 - y) * 32;
  const int tid = threadIdx.x;
  const int w = tid >> 6, lane = tid & 63;
  const int l31 = lane & 31, hi = lane >> 5;
  const int h = kvh * 4 + w;

  __shared__ __align__(16) bf16_t Ks[3][64 * 64];   // [buf][kv][d] (swizzled granules)
  __shared__ __align__(16) bf16_t Vs[3][64 * 64];   // [buf][d][kv]

  const bf16_t* Kg = Kr + (int64_t)(b * KV_ + kvh) * S_ * HD_;
  const bf16_t* Vg = Vt + (int64_t)(b * KV_ + kvh) * HD_ * S_;   // [d][s]

  const int rL = (w << 3) + (lane >> 3);
  const int sgr = ((lane & 7) ^ (rL & 7)) << 3;     // element offset
  const bf16_t* Ksrc = Kg + (int64_t)rL * HD_ + sgr;
  const bf16_t* Vsrc = Vg + (int64_t)rL * S_ + sgr;

  const int NT = (63 - y) / 2 + 1;        // 64-kv tiles (chunk B reach)

  auto stage = [&](int t) {               // exactly 4 loads per wave (uniform vmcnt)
    const int tc = (t < NT) ? t : (NT - 1);
    char* Kd = (char*)Ks + (t % 3) * 8192 + w * 1024;
    char* Vd = (char*)Vs + (t % 3) * 8192 + w * 1024;
    gload_lds16(Ksrc + (int64_t)tc * 64 * HD_, Kd);
    gload_lds16(Ksrc + (int64_t)(tc * 64 + 32) * HD_, Kd + 4096);
    gload_lds16(Vsrc + tc * 64, Vd);
    gload_lds16(Vsrc + (int64_t)32 * S_ + tc * 64, Vd + 4096);
  };

  const bf16_t* QbA = Q + ((int64_t)(b * H_ + h) * S_ + q0A) * HD_;
  const bf16_t* QbB = Q + ((int64_t)(b * H_ + h) * S_ + q0B) * HD_;
  bf16x8 qfA[4], qfB[4];
#pragma unroll
  for (int ds = 0; ds < 4; ++ds) {
    qfA[ds] = *(const bf16x8*)(QbA + l31 * HD_ + ds * 16 + hi * 8);
    qfB[ds] = *(const bf16x8*)(QbB + l31 * HD_ + ds * 16 + hi * 8);
  }

  bf16x8 onesf;
#pragma unroll
  for (int i = 0; i < 8; ++i) onesf[i] = (bf16_t)1.0f;

  f32x16 aA0 = {}, aA1 = {}, aB0 = {}, aB1 = {};    // O^T partials per chunk
  f32x16 lA = {}, lB = {};                          // denominators (all regs equal)
  const int xorb = l31 & 7;

  const f32x16 sinit = {-SHIFT_, -SHIFT_, -SHIFT_, -SHIFT_,
                        -SHIFT_, -SHIFT_, -SHIFT_, -SHIFT_,
                        -SHIFT_, -SHIFT_, -SHIFT_, -SHIFT_,
                        -SHIFT_, -SHIFT_, -SHIFT_, -SHIFT_};

  auto softmax_pack = [&](const f32x16 &sacc, bool diag,
                          bf16x8 &pf0, bf16x8 &pf1) {
    float p[16];
#pragma unroll
    for (int r = 0; r < 16; ++r) {
      float sc = sacc[r];
      if (diag) {
        int kvpos = (r & 3) + 8 * (r >> 2) + 4 * hi;
        if (kvpos > l31) sc = -1e30f;
      }
      p[r] = __builtin_amdgcn_exp2f(sc);
    }
    u32 pk[8];
#pragma unroll
    for (int i = 0; i < 8; ++i) pk[i] = pkbf(p[2*i], p[2*i+1]);
    u32 a0 = pk[0], b0 = pk[2]; pl32swap(a0, b0);
    u32 a1 = pk[1], b1 = pk[3]; pl32swap(a1, b1);
    u32 a2 = pk[4], b2 = pk[6]; pl32swap(a2, b2);
    u32 a3 = pk[5], b3 = pk[7]; pl32swap(a3, b3);
    pf0 = __builtin_bit_cast(bf16x8, (u32x4){a0, a1, b0, b1});
    pf1 = __builtin_bit_cast(bf16x8, (u32x4){a2, a3, b2, b3});
  };

  stage(0);
  stage(1);

  for (int t = 0; t < NT; ++t) {
    // counted wait: tile t's loads landed; tile t+1's 4 loads may stay in flight.
    asm volatile("s_waitcnt vmcnt(4) lgkmcnt(0)" ::: "memory");
    asm volatile("s_barrier" ::: "memory");       // raw barrier: no compiler drain
    stage(t + 2);
    const char* KsB = (const char*)Ks + (t % 3) * 8192;
    const char* VsB = (const char*)Vs + (t % 3) * 8192;
#pragma unroll
    for (int sub = 0; sub < 2; ++sub) {
      const int kvbase = t * 64 + sub * 32;
      if (kvbase <= q0B) {
        const bool actA = (kvbase <= q0A);
        const char* Kbase = KsB + (sub * 32 + l31) * 128;
        bf16x8 kf[4];
#pragma unroll
        for (int ds = 0; ds < 4; ++ds)
          kf[ds] = *(const bf16x8*)(Kbase + ((((ds << 1) + hi) ^ xorb) << 4));
        f32x16 sA = sinit, sB = sinit;
        __builtin_amdgcn_s_setprio(1);
#pragma unroll
        for (int ds = 0; ds < 4; ++ds)
          sB = __builtin_amdgcn_mfma_f32_32x32x16_bf16(kf[ds], qfB[ds], sB, 0, 0, 0);
        if (actA) {
#pragma unroll
          for (int ds = 0; ds < 4; ++ds)
            sA = __builtin_amdgcn_mfma_f32_32x32x16_bf16(kf[ds], qfA[ds], sA, 0, 0, 0);
        }
        __builtin_amdgcn_s_setprio(0);
        const char* Vb0 = VsB + l31 * 128;
        const char* Vb1 = VsB + (32 + l31) * 128;
        const int c0 = (sub << 2) + hi;
        const int c1 = c0 + 2;
        bf16x8 v00 = *(const bf16x8*)(Vb0 + ((c0 ^ xorb) << 4));
        bf16x8 v01 = *(const bf16x8*)(Vb0 + ((c1 ^ xorb) << 4));
        bf16x8 v10 = *(const bf16x8*)(Vb1 + ((c0 ^ xorb) << 4));
        bf16x8 v11 = *(const bf16x8*)(Vb1 + ((c1 ^ xorb) << 4));
        bf16x8 pB0, pB1;
        softmax_pack(sB, kvbase == q0B, pB0, pB1);
        __builtin_amdgcn_s_setprio(1);
        aB0 = __builtin_amdgcn_mfma_f32_32x32x16_bf16(v00, pB0, aB0, 0, 0, 0);
        aB1 = __builtin_amdgcn_mfma_f32_32x32x16_bf16(v10, pB0, aB1, 0, 0, 0);
        aB0 = __builtin_amdgcn_mfma_f32_32x32x16_bf16(v01, pB1, aB0, 0, 0, 0);
        aB1 = __builtin_amdgcn_mfma_f32_32x32x16_bf16(v11, pB1, aB1, 0, 0, 0);
        lB  = __builtin_amdgcn_mfma_f32_32x32x16_bf16(onesf, pB0, lB, 0, 0, 0);
        lB  = __builtin_amdgcn_mfma_f32_32x32x16_bf16(onesf, pB1, lB, 0, 0, 0);
        __builtin_amdgcn_s_setprio(0);
        if (actA) {
          bf16x8 pA0, pA1;
          softmax_pack(sA, kvbase == q0A, pA0, pA1);
          __builtin_amdgcn_s_setprio(1);
          aA0 = __builtin_amdgcn_mfma_f32_32x32x16_bf16(v00, pA0, aA0, 0, 0, 0);
          aA1 = __builtin_amdgcn_mfma_f32_32x32x16_bf16(v10, pA0, aA1, 0, 0, 0);
          aA0 = __builtin_amdgcn_mfma_f32_32x32x16_bf16(v01, pA1, aA0, 0, 0, 0);
          aA1 = __builtin_amdgcn_mfma_f32_32x32x16_bf16(v11, pA1, aA1, 0, 0, 0);
          lA  = __builtin_amdgcn_mfma_f32_32x32x16_bf16(onesf, pA0, lA, 0, 0, 0);
          lA  = __builtin_amdgcn_mfma_f32_32x32x16_bf16(onesf, pA1, lA, 0, 0, 0);
          __builtin_amdgcn_s_setprio(0);
        }
      }
    }
  }

  asm volatile("s_waitcnt vmcnt(0)" ::: "memory");   // drain before exit

  auto epi = [&](const f32x16 &a0, const f32x16 &a1, float denom, int q0) {
    const float rl = 1.f / denom;
    const int64_t row = (int64_t)(b * S_ + q0 + l31);
#pragma unroll
    for (int dt = 0; dt < 2; ++dt) {
#pragma unroll
      for (int g = 0; g < 4; ++g) {
        bf16x4 ov;
#pragma unroll
        for (int j = 0; j < 4; ++j) {
          float val = (dt ? a1[4*g + j] : a0[4*g + j]) * rl;
          ov[j] = (bf16_t)val;
        }
        const int d0 = dt * 32 + g * 8 + hi * 4;
        *(bf16x4*)(AO + row * D_ + h * HD_ + d0) = ov;
      }
    }
  };
  epi(aA0, aA1, lA[0], q0A);
  epi(aB0, aB1, lB[0], q0B);
}

// ---------------- launcher ----------------
extern "C" void kernel_launch(void* const* d_in, const int* in_sizes, int n_in,
                              void* d_out, int out_size, void* d_ws, size_t ws_size,
                              hipStream_t stream) {
  const float* x    = (const float*)d_in[0];
  const float* cosb = (const float*)d_in[1];
  const float* sinb = (const float*)d_in[2];
  const float* Wq   = (const float*)d_in[3];
  const float* Wk   = (const float*)d_in[4];
  const float* Wv   = (const float*)d_in[5];
  const float* Wo   = (const float*)d_in[6];
  float* out = (float*)d_out;

  bf16_t* ws = (bf16_t*)d_ws;
  size_t o = 0;
  bf16_t* xb    = ws + o; o += (size_t)4096 * 2048;
  bf16_t* Wqkvt = ws + o; o += (size_t)3072 * 2048;
  bf16_t* Wot   = ws + o; o += (size_t)2048 * 2048;
  bf16_t* qkv   = ws + o; o += (size_t)4096 * 3072;
  bf16_t* Qr    = ws + o; o += (size_t)B_ * H_ * S_ * HD_;
  bf16_t* Krb   = ws + o; o += (size_t)B_ * KV_ * S_ * HD_;
  bf16_t* Vtb   = ws + o; o += (size_t)B_ * KV_ * S_ * HD_;
  bf16_t* AO    = ws + o; o += (size_t)4096 * 2048;

  cvt_f32_bf16<<<(8388608/4 + 255)/256, 256, 0, stream>>>(x, xb, 8388608/4);
  transpose_cvt_all<<<10240, dim3(32, 8), 0, stream>>>(Wq, Wk, Wv, Wo, Wqkvt, Wot);
  // QKV projection: BN=192 -> grid 16x16 = 256 blocks = exactly 1/CU, XCD-swizzled
  gemm256<192, 2, bf16_t><<<dim3(3072/192, 4096/256), 512, 0, stream>>>(
      xb, Wqkvt, qkv, 3072, 2048);
  // RoPE + scatter (vectorized), V transpose
  rope_scatter2<<<4096, 256, 0, stream>>>(qkv, cosb, sinb, Qr, Krb);
  v_transpose<<<dim3(16, 64, 2), dim3(32, 8), 0, stream>>>(qkv, Vtb);
  // paired-chunk attention, true counted-vmcnt pipeline
  attn9<<<dim3(16, 32), 256, 0, stream>>>(Qr, Krb, Vtb, AO);
  // output projection -> f32 (BN=128 -> 256 blocks = 1/CU, XCD-swizzled)
  gemm256<128, 0, float><<<dim3(2048/128, 4096/256), 512, 0, stream>>>(
      AO, Wot, out, 2048, 2048);
}

// Round 16
// 173.409 us; speedup vs baseline: 1.0986x; 1.0081x over previous
//
#include <hip/hip_runtime.h>
#include <hip/hip_bf16.h>
#include <stdint.h>

#define B_ 2
#define S_ 2048
#define D_ 2048
#define H_ 32
#define KV_ 8
#define HD_ 64
#define NQKV 3072   // D + 2*KV*HD

typedef __bf16 bf16_t;
typedef __bf16 bf16x8 __attribute__((ext_vector_type(8)));
typedef __bf16 bf16x4 __attribute__((ext_vector_type(4)));
typedef float  f32x4  __attribute__((ext_vector_type(4)));
typedef float  f32x16 __attribute__((ext_vector_type(16)));
typedef unsigned int u32;
typedef u32 u32x4 __attribute__((ext_vector_type(4)));

typedef const __attribute__((address_space(1))) uint32_t* gp1_t;
typedef __attribute__((address_space(3))) uint32_t* lp3_t;

// async global->LDS, 16B per lane. LDS dest is wave-uniform base + lane*16.
__device__ inline void gload_lds16(const void* g, void* l) {
  __builtin_amdgcn_global_load_lds((gp1_t)(uintptr_t)g, (lp3_t)(uint32_t)(uintptr_t)l,
                                   16, 0, 0);
}

__device__ inline u32 pkbf(float a, float b) {
  union { bf16_t h[2]; u32 u; } v;
  v.h[0] = (bf16_t)a; v.h[1] = (bf16_t)b;
  return v.u;
}

// v_permlane32_swap_b32: a = [a_lo, b_lo], b = [a_hi, b_hi]
__device__ inline void pl32swap(u32 &a, u32 &b) {
  asm("v_permlane32_swap_b32 %0, %1" : "+v"(a), "+v"(b));
}

// ---------------- fused prep: x cvt + all 4 weight transposes ----------------
__global__ void prep_all(const float* __restrict__ x, bf16_t* __restrict__ xb,
                         const float* __restrict__ Wq, const float* __restrict__ Wk,
                         const float* __restrict__ Wv, const float* __restrict__ Wo,
                         bf16_t* __restrict__ Wqkvt, bf16_t* __restrict__ Wot) {
  const int id = blockIdx.x;
  const int tid = threadIdx.y * 32 + threadIdx.x;
  if (id < 8192) {                      // x -> bf16 (2097152 float4s)
    const int i = id * 256 + tid;
    float4 v = ((const float4*)x)[i];
    bf16x4 o;
    o[0] = (bf16_t)v.x; o[1] = (bf16_t)v.y; o[2] = (bf16_t)v.z; o[3] = (bf16_t)v.w;
    ((bf16x4*)xb)[i] = o;
    return;
  }
  __shared__ float t[32][33];
  const int wid = id - 8192;
  const float* in; bf16_t* out; int C, roff, bx, by;
  if (wid < 4096)      { in = Wq; out = Wqkvt; C = 2048; roff = 0;    bx = wid & 63;          by = wid >> 6; }
  else if (wid < 5120) { in = Wk; out = Wqkvt; C = 512;  roff = 2048; bx = (wid - 4096) & 15; by = (wid - 4096) >> 4; }
  else if (wid < 6144) { in = Wv; out = Wqkvt; C = 512;  roff = 2560; bx = (wid - 5120) & 15; by = (wid - 5120) >> 4; }
  else                 { in = Wo; out = Wot;   C = 2048; roff = 0;    bx = (wid - 6144) & 63; by = (wid - 6144) >> 6; }
  const int tx = threadIdx.x, ty = threadIdx.y;   // (32,8)
  const int c0 = bx * 32, r0 = by * 32;
#pragma unroll
  for (int j = 0; j < 4; ++j)
    t[ty + j*8][tx] = in[(int64_t)(r0 + ty + j*8) * C + c0 + tx];
  __syncthreads();
#pragma unroll
  for (int j = 0; j < 4; ++j)
    out[(int64_t)(roff + c0 + ty + j*8) * 2048 + r0 + tx] = (bf16_t)t[tx][ty + j*8];
}

// V region of qkv -> Vt[b][kvh][d][s]  (LDS-tiled transpose, coalesced both sides)
__global__ void v_transpose(const bf16_t* __restrict__ qkv, bf16_t* __restrict__ Vt) {
  __shared__ bf16_t t[32][34];
  const int tx = threadIdx.x, ty = threadIdx.y;   // (32,8)
  const int c0 = blockIdx.x * 32;                 // V col within 512
  const int s0 = blockIdx.y * 32;
  const int b  = blockIdx.z;
#pragma unroll
  for (int j = 0; j < 4; ++j)
    t[ty + j*8][tx] = qkv[(int64_t)(b * S_ + s0 + ty + j*8) * NQKV + 2560 + c0 + tx];
  __syncthreads();
#pragma unroll
  for (int j = 0; j < 4; ++j)
    Vt[(int64_t)(b * 512 + c0 + ty + j*8) * S_ + s0 + tx] = t[tx][ty + j*8];
}

// ---------------- vectorized RoPE scatter (Q scaled by 0.125*log2e) ----------------
#define QSCALE 0.18033688011112042f
__global__ __launch_bounds__(256) void rope_scatter2(const bf16_t* __restrict__ qkv,
                                                     const float* __restrict__ cosb,
                                                     const float* __restrict__ sinb,
                                                     bf16_t* __restrict__ Q,
                                                     bf16_t* __restrict__ Kr) {
  const int row = blockIdx.x;            // b*S + s
  const int b = row >> 11, s = row & 2047;
  const bf16_t* src = qkv + (int64_t)row * NQKV;
  const float* cs = cosb + s * HD_;
  const float* sn = sinb + s * HD_;
  const int tid = threadIdx.x;
  {                                      // Q: 2048 elems = 256 vectors
    const int c0 = tid * 8;
    const int d0 = c0 & 63, h = c0 >> 6;
    bf16x8 own = *(const bf16x8*)(src + c0);
    bf16x8 par = *(const bf16x8*)(src + (c0 ^ 32));
    const float sgn = (d0 & 32) ? 1.f : -1.f;
    bf16x8 o;
#pragma unroll
    for (int j = 0; j < 8; ++j) {
      const int d = d0 + j;
      float val = (float)own[j] * cs[d] + sgn * (float)par[j] * sn[d];
      o[j] = (bf16_t)(val * QSCALE);
    }
    *(bf16x8*)(Q + ((int64_t)(b * H_ + h) * S_ + s) * HD_ + d0) = o;
  }
  if (tid < 64) {                        // K: 512 elems = 64 vectors
    const int c0 = 2048 + tid * 8;
    const int d0 = (tid * 8) & 63, kvh = tid >> 3;
    bf16x8 own = *(const bf16x8*)(src + c0);
    bf16x8 par = *(const bf16x8*)(src + (c0 ^ 32));
    const float sgn = (d0 & 32) ? 1.f : -1.f;
    bf16x8 o;
#pragma unroll
    for (int j = 0; j < 8; ++j) {
      const int d = d0 + j;
      float val = (float)own[j] * cs[d] + sgn * (float)par[j] * sn[d];
      o[j] = (bf16_t)val;
    }
    *(bf16x8*)(Kr + ((int64_t)(b * KV_ + kvh) * S_ + s) * HD_ + d0) = o;
  }
}

// ---------------- 256-row deep-pipelined GEMM (2-buf, drain-per-tile) ----------------
// BM=256, BK=64, 8 waves (2M x 4N). EPI=0: f32 C. EPI=2: bf16 row-major C.
template <int BN, int EPI, typename OutT>
__global__ __launch_bounds__(512, 2) void gemm256(const bf16_t* __restrict__ A,
                                                  const bf16_t* __restrict__ Bt,
                                                  OutT* __restrict__ Cout,
                                                  int N, int K) {
  constexpr int NB = BN / 64;
  constexpr int LT = 4 + NB;
  constexpr int WCOLS = BN / 4;
  constexpr int NF = WCOLS / 16;

  __shared__ bf16_t As[2][256 * 64];
  __shared__ bf16_t Bs[2][BN * 64];

  const int tid = threadIdx.x;
  const int w = tid >> 6, lane = tid & 63;
  const int l15 = lane & 15, l4 = lane >> 4;
  const int wr = w >> 2, wc = w & 3;

  const int nX = gridDim.x;
  const int lin = blockIdx.y * nX + blockIdx.x;
  const int cpx = (nX * gridDim.y) >> 3;
  const int swz = (lin & 7) * cpx + (lin >> 3);
  const int bm = (swz / nX) * 256, bn = (swz % nX) * BN;

  const int rw = w * 8 + (lane >> 3);
  const int srcg = ((lane & 7) ^ ((lane >> 3) & 7)) << 3;
  const bf16_t* PA[4];
  const bf16_t* PB[NB];
#pragma unroll
  for (int L = 0; L < 4; ++L)
    PA[L] = A + (int64_t)(bm + L * 64 + rw) * K + srcg;
#pragma unroll
  for (int L = 0; L < NB; ++L)
    PB[L] = Bt + (int64_t)(bn + L * 64 + rw) * K + srcg;

  const int NK = K >> 6;
  const int xr = l15 & 7;
  const int g0 = (l4 ^ xr) << 3;
  const int g1 = ((4 + l4) ^ xr) << 3;

  f32x4 acc[8][NF] = {};

  auto stage = [&](int s, int buf, int toff) {
    if (s < 4) gload_lds16(PA[s] + toff, &As[buf][s * 4096 + w * 512]);
    else       gload_lds16(PB[s - 4] + toff, &Bs[buf][(s - 4) * 4096 + w * 512]);
  };

#pragma unroll
  for (int s = 0; s < LT; ++s) stage(s, 0, 0);
  asm volatile("s_waitcnt vmcnt(0)" ::: "memory");
  __syncthreads();

  for (int t = 0; t < NK; ++t) {
    const int p = t & 1;
    const bool more = (t + 1) < NK;
    const int toff = (t + 1) << 6;
    const bf16_t* Ab = &As[p][0];
    const bf16_t* Bb = &Bs[p][0];

    bf16x8 ball[NF][2];
#pragma unroll
    for (int nn = 0; nn < NF; ++nn) {
      const int rb = wc * WCOLS + nn * 16 + l15;
      ball[nn][0] = *(const bf16x8*)(Bb + rb * 64 + g0);
      ball[nn][1] = *(const bf16x8*)(Bb + rb * 64 + g1);
    }

#pragma unroll
    for (int mh = 0; mh < 2; ++mh) {
      if (more) {
        const int sb = mh * (LT / 2);
        const int se = (mh == 0) ? (LT / 2) : LT;
#pragma unroll
        for (int s = sb; s < se; ++s) stage(s, p ^ 1, toff);
      }
      bf16x8 af[4][2];
#pragma unroll
      for (int mm = 0; mm < 4; ++mm) {
        const int ra = wr * 128 + (mh * 4 + mm) * 16 + l15;
        af[mm][0] = *(const bf16x8*)(Ab + ra * 64 + g0);
        af[mm][1] = *(const bf16x8*)(Ab + ra * 64 + g1);
      }
      __builtin_amdgcn_s_setprio(1);
#pragma unroll
      for (int mm = 0; mm < 4; ++mm)
#pragma unroll
        for (int nn = 0; nn < NF; ++nn) {
          acc[mh*4+mm][nn] = __builtin_amdgcn_mfma_f32_16x16x32_bf16(
              af[mm][0], ball[nn][0], acc[mh*4+mm][nn], 0, 0, 0);
          acc[mh*4+mm][nn] = __builtin_amdgcn_mfma_f32_16x16x32_bf16(
              af[mm][1], ball[nn][1], acc[mh*4+mm][nn], 0, 0, 0);
        }
      __builtin_amdgcn_s_setprio(0);
    }
    if (more) {
      asm volatile("s_waitcnt vmcnt(0)" ::: "memory");
      __syncthreads();
    }
  }

#pragma unroll
  for (int m = 0; m < 8; ++m) {
    const int row = bm + wr * 128 + m * 16 + l4 * 4;
#pragma unroll
    for (int n = 0; n < NF; ++n) {
      const int col = bn + wc * WCOLS + n * 16 + l15;
#pragma unroll
      for (int r = 0; r < 4; ++r)
        Cout[(int64_t)(row + r) * N + col] = (OutT)acc[m][n][r];
    }
  }
}

// ---------------- gemm_out3: 3-buffer TRUE counted-vmcnt GEMM (BN=128) ----------------
// Same datapath as gemm256 (dedup reads, granule-XOR swizzle); sync structure:
// per tile {s_waitcnt vmcnt(6) [loads issued 1 tile ago] -> raw s_barrier ->
// stage(t+2 -> buf (t+2)%3) -> compute buf t%3}. Never vmcnt(0) in the loop (T4).
__global__ __launch_bounds__(512, 2) void gemm_out3(const bf16_t* __restrict__ A,
                                                    const bf16_t* __restrict__ Bt,
                                                    float* __restrict__ Cout,
                                                    int N, int K) {
  constexpr int BN = 128, NB = 2, LT = 6, WCOLS = 32, NF = 2;

  __shared__ bf16_t As[3][256 * 64];   // 96 KB
  __shared__ bf16_t Bs[3][BN * 64];    // 48 KB

  const int tid = threadIdx.x;
  const int w = tid >> 6, lane = tid & 63;
  const int l15 = lane & 15, l4 = lane >> 4;
  const int wr = w >> 2, wc = w & 3;

  const int nX = gridDim.x;
  const int lin = blockIdx.y * nX + blockIdx.x;
  const int cpx = (nX * gridDim.y) >> 3;
  const int swz = (lin & 7) * cpx + (lin >> 3);
  const int bm = (swz / nX) * 256, bn = (swz % nX) * BN;

  const int rw = w * 8 + (lane >> 3);
  const int srcg = ((lane & 7) ^ ((lane >> 3) & 7)) << 3;
  const bf16_t* PA[4];
  const bf16_t* PB[NB];
#pragma unroll
  for (int L = 0; L < 4; ++L)
    PA[L] = A + (int64_t)(bm + L * 64 + rw) * K + srcg;
#pragma unroll
  for (int L = 0; L < NB; ++L)
    PB[L] = Bt + (int64_t)(bn + L * 64 + rw) * K + srcg;

  const int NK = K >> 6;
  const int xr = l15 & 7;
  const int g0 = (l4 ^ xr) << 3;
  const int g1 = ((4 + l4) ^ xr) << 3;

  f32x4 acc[8][NF] = {};

  auto stage = [&](int tsrc, int buf) {  // always LT loads (uniform vmcnt)
    const int tc = (tsrc < NK) ? tsrc : (NK - 1);
    const int toff = tc << 6;
#pragma unroll
    for (int s = 0; s < 4; ++s)
      gload_lds16(PA[s] + toff, &As[buf][s * 4096 + w * 512]);
#pragma unroll
    for (int s = 0; s < NB; ++s)
      gload_lds16(PB[s] + toff, &Bs[buf][s * 4096 + w * 512]);
  };

  // prologue: tiles 0,1 in flight (12 outstanding loads/wave)
  stage(0, 0);
  stage(1, 1);

  for (int t = 0; t < NK; ++t) {
    // tile t's 6 loads landed; tile t+1's 6 may stay in flight across the barrier
    asm volatile("s_waitcnt vmcnt(6)" ::: "memory");
    asm volatile("s_barrier" ::: "memory");          // raw: no compiler vmcnt(0) drain
    stage(t + 2, (t + 2) % 3);
    const bf16_t* Ab = &As[t % 3][0];
    const bf16_t* Bb = &Bs[t % 3][0];

    bf16x8 ball[NF][2];
#pragma unroll
    for (int nn = 0; nn < NF; ++nn) {
      const int rb = wc * WCOLS + nn * 16 + l15;
      ball[nn][0] = *(const bf16x8*)(Bb + rb * 64 + g0);
      ball[nn][1] = *(const bf16x8*)(Bb + rb * 64 + g1);
    }
#pragma unroll
    for (int mh = 0; mh < 2; ++mh) {
      bf16x8 af[4][2];
#pragma unroll
      for (int mm = 0; mm < 4; ++mm) {
        const int ra = wr * 128 + (mh * 4 + mm) * 16 + l15;
        af[mm][0] = *(const bf16x8*)(Ab + ra * 64 + g0);
        af[mm][1] = *(const bf16x8*)(Ab + ra * 64 + g1);
      }
      __builtin_amdgcn_s_setprio(1);
#pragma unroll
      for (int mm = 0; mm < 4; ++mm)
#pragma unroll
        for (int nn = 0; nn < NF; ++nn) {
          acc[mh*4+mm][nn] = __builtin_amdgcn_mfma_f32_16x16x32_bf16(
              af[mm][0], ball[nn][0], acc[mh*4+mm][nn], 0, 0, 0);
          acc[mh*4+mm][nn] = __builtin_amdgcn_mfma_f32_16x16x32_bf16(
              af[mm][1], ball[nn][1], acc[mh*4+mm][nn], 0, 0, 0);
        }
      __builtin_amdgcn_s_setprio(0);
    }
  }
  asm volatile("s_waitcnt vmcnt(0)" ::: "memory");   // drain before exit

#pragma unroll
  for (int m = 0; m < 8; ++m) {
    const int row = bm + wr * 128 + m * 16 + l4 * 4;
#pragma unroll
    for (int n = 0; n < NF; ++n) {
      const int col = bn + wc * WCOLS + n * 16 + l15;
#pragma unroll
      for (int r = 0; r < 4; ++r)
        Cout[(int64_t)(row + r) * N + col] = acc[m][n][r];
    }
  }
}

// ---------------- flash attention: paired chunks + MFMA denominators ----------------
#define SHIFT_ 8.0f
__global__ __launch_bounds__(256, 2) void attn9(const bf16_t* __restrict__ Q,
                                                const bf16_t* __restrict__ Kr,
                                                const bf16_t* __restrict__ Vt,
                                                bf16_t* __restrict__ AO) {
  const int bk = blockIdx.x;
  const int b = bk >> 3, kvh = bk & 7;
  const int y = blockIdx.y;               // 0..31
  const int q0A = y * 32, q0B = (63 - y) * 32;
  const int tid = threadIdx.x;
  const int w = tid >> 6, lane = tid & 63;
  const int l31 = lane & 31, hi = lane >> 5;
  const int h = kvh * 4 + w;

  __shared__ __align__(16) bf16_t Ks[3][64 * 64];
  __shared__ __align__(16) bf16_t Vs[3][64 * 64];

  const bf16_t* Kg = Kr + (int64_t)(b * KV_ + kvh) * S_ * HD_;
  const bf16_t* Vg = Vt + (int64_t)(b * KV_ + kvh) * HD_ * S_;

  const int rL = (w << 3) + (lane >> 3);
  const int sgr = ((lane & 7) ^ (rL & 7)) << 3;
  const bf16_t* Ksrc = Kg + (int64_t)rL * HD_ + sgr;
  const bf16_t* Vsrc = Vg + (int64_t)rL * S_ + sgr;

  const int NT = (63 - y) / 2 + 1;

  auto stage = [&](int t) {
    const int tc = (t < NT) ? t : (NT - 1);
    char* Kd = (char*)Ks + (t % 3) * 8192 + w * 1024;
    char* Vd = (char*)Vs + (t % 3) * 8192 + w * 1024;
    gload_lds16(Ksrc + (int64_t)tc * 64 * HD_, Kd);
    gload_lds16(Ksrc + (int64_t)(tc * 64 + 32) * HD_, Kd + 4096);
    gload_lds16(Vsrc + tc * 64, Vd);
    gload_lds16(Vsrc + (int64_t)32 * S_ + tc * 64, Vd + 4096);
  };

  const bf16_t* QbA = Q + ((int64_t)(b * H_ + h) * S_ + q0A) * HD_;
  const bf16_t* QbB = Q + ((int64_t)(b * H_ + h) * S_ + q0B) * HD_;
  bf16x8 qfA[4], qfB[4];
#pragma unroll
  for (int ds = 0; ds < 4; ++ds) {
    qfA[ds] = *(const bf16x8*)(QbA + l31 * HD_ + ds * 16 + hi * 8);
    qfB[ds] = *(const bf16x8*)(QbB + l31 * HD_ + ds * 16 + hi * 8);
  }

  bf16x8 onesf;
#pragma unroll
  for (int i = 0; i < 8; ++i) onesf[i] = (bf16_t)1.0f;

  f32x16 aA0 = {}, aA1 = {}, aB0 = {}, aB1 = {};
  f32x16 lA = {}, lB = {};
  const int xorb = l31 & 7;

  const f32x16 sinit = {-SHIFT_, -SHIFT_, -SHIFT_, -SHIFT_,
                        -SHIFT_, -SHIFT_, -SHIFT_, -SHIFT_,
                        -SHIFT_, -SHIFT_, -SHIFT_, -SHIFT_,
                        -SHIFT_, -SHIFT_, -SHIFT_, -SHIFT_};

  auto softmax_pack = [&](const f32x16 &sacc, bool diag,
                          bf16x8 &pf0, bf16x8 &pf1) {
    float p[16];
#pragma unroll
    for (int r = 0; r < 16; ++r) {
      float sc = sacc[r];
      if (diag) {
        int kvpos = (r & 3) + 8 * (r >> 2) + 4 * hi;
        if (kvpos > l31) sc = -1e30f;
      }
      p[r] = __builtin_amdgcn_exp2f(sc);
    }
    u32 pk[8];
#pragma unroll
    for (int i = 0; i < 8; ++i) pk[i] = pkbf(p[2*i], p[2*i+1]);
    u32 a0 = pk[0], b0 = pk[2]; pl32swap(a0, b0);
    u32 a1 = pk[1], b1 = pk[3]; pl32swap(a1, b1);
    u32 a2 = pk[4], b2 = pk[6]; pl32swap(a2, b2);
    u32 a3 = pk[5], b3 = pk[7]; pl32swap(a3, b3);
    pf0 = __builtin_bit_cast(bf16x8, (u32x4){a0, a1, b0, b1});
    pf1 = __builtin_bit_cast(bf16x8, (u32x4){a2, a3, b2, b3});
  };

  stage(0);
  stage(1);

  for (int t = 0; t < NT; ++t) {
    asm volatile("s_waitcnt vmcnt(4) lgkmcnt(0)" ::: "memory");
    asm volatile("s_barrier" ::: "memory");
    stage(t + 2);
    const char* KsB = (const char*)Ks + (t % 3) * 8192;
    const char* VsB = (const char*)Vs + (t % 3) * 8192;
#pragma unroll
    for (int sub = 0; sub < 2; ++sub) {
      const int kvbase = t * 64 + sub * 32;
      if (kvbase <= q0B) {
        const bool actA = (kvbase <= q0A);
        const char* Kbase = KsB + (sub * 32 + l31) * 128;
        bf16x8 kf[4];
#pragma unroll
        for (int ds = 0; ds < 4; ++ds)
          kf[ds] = *(const bf16x8*)(Kbase + ((((ds << 1) + hi) ^ xorb) << 4));
        f32x16 sA = sinit, sB = sinit;
        __builtin_amdgcn_s_setprio(1);
#pragma unroll
        for (int ds = 0; ds < 4; ++ds)
          sB = __builtin_amdgcn_mfma_f32_32x32x16_bf16(kf[ds], qfB[ds], sB, 0, 0, 0);
        if (actA) {
#pragma unroll
          for (int ds = 0; ds < 4; ++ds)
            sA = __builtin_amdgcn_mfma_f32_32x32x16_bf16(kf[ds], qfA[ds], sA, 0, 0, 0);
        }
        __builtin_amdgcn_s_setprio(0);
        const char* Vb0 = VsB + l31 * 128;
        const char* Vb1 = VsB + (32 + l31) * 128;
        const int c0 = (sub << 2) + hi;
        const int c1 = c0 + 2;
        bf16x8 v00 = *(const bf16x8*)(Vb0 + ((c0 ^ xorb) << 4));
        bf16x8 v01 = *(const bf16x8*)(Vb0 + ((c1 ^ xorb) << 4));
        bf16x8 v10 = *(const bf16x8*)(Vb1 + ((c0 ^ xorb) << 4));
        bf16x8 v11 = *(const bf16x8*)(Vb1 + ((c1 ^ xorb) << 4));
        bf16x8 pB0, pB1;
        softmax_pack(sB, kvbase == q0B, pB0, pB1);
        __builtin_amdgcn_s_setprio(1);
        aB0 = __builtin_amdgcn_mfma_f32_32x32x16_bf16(v00, pB0, aB0, 0, 0, 0);
        aB1 = __builtin_amdgcn_mfma_f32_32x32x16_bf16(v10, pB0, aB1, 0, 0, 0);
        aB0 = __builtin_amdgcn_mfma_f32_32x32x16_bf16(v01, pB1, aB0, 0, 0, 0);
        aB1 = __builtin_amdgcn_mfma_f32_32x32x16_bf16(v11, pB1, aB1, 0, 0, 0);
        lB  = __builtin_amdgcn_mfma_f32_32x32x16_bf16(onesf, pB0, lB, 0, 0, 0);
        lB  = __builtin_amdgcn_mfma_f32_32x32x16_bf16(onesf, pB1, lB, 0, 0, 0);
        __builtin_amdgcn_s_setprio(0);
        if (actA) {
          bf16x8 pA0, pA1;
          softmax_pack(sA, kvbase == q0A, pA0, pA1);
          __builtin_amdgcn_s_setprio(1);
          aA0 = __builtin_amdgcn_mfma_f32_32x32x16_bf16(v00, pA0, aA0, 0, 0, 0);
          aA1 = __builtin_amdgcn_mfma_f32_32x32x16_bf16(v10, pA0, aA1, 0, 0, 0);
          aA0 = __builtin_amdgcn_mfma_f32_32x32x16_bf16(v01, pA1, aA0, 0, 0, 0);
          aA1 = __builtin_amdgcn_mfma_f32_32x32x16_bf16(v11, pA1, aA1, 0, 0, 0);
          lA  = __builtin_amdgcn_mfma_f32_32x32x16_bf16(onesf, pA0, lA, 0, 0, 0);
          lA  = __builtin_amdgcn_mfma_f32_32x32x16_bf16(onesf, pA1, lA, 0, 0, 0);
          __builtin_amdgcn_s_setprio(0);
        }
      }
    }
  }

  asm volatile("s_waitcnt vmcnt(0)" ::: "memory");

  auto epi = [&](const f32x16 &a0, const f32x16 &a1, float denom, int q0) {
    const float rl = 1.f / denom;
    const int64_t row = (int64_t)(b * S_ + q0 + l31);
#pragma unroll
    for (int dt = 0; dt < 2; ++dt) {
#pragma unroll
      for (int g = 0; g < 4; ++g) {
        bf16x4 ov;
#pragma unroll
        for (int j = 0; j < 4; ++j) {
          float val = (dt ? a1[4*g + j] : a0[4*g + j]) * rl;
          ov[j] = (bf16_t)val;
        }
        const int d0 = dt * 32 + g * 8 + hi * 4;
        *(bf16x4*)(AO + row * D_ + h * HD_ + d0) = ov;
      }
    }
  };
  epi(aA0, aA1, lA[0], q0A);
  epi(aB0, aB1, lB[0], q0B);
}

// ---------------- launcher ----------------
extern "C" void kernel_launch(void* const* d_in, const int* in_sizes, int n_in,
                              void* d_out, int out_size, void* d_ws, size_t ws_size,
                              hipStream_t stream) {
  const float* x    = (const float*)d_in[0];
  const float* cosb = (const float*)d_in[1];
  const float* sinb = (const float*)d_in[2];
  const float* Wq   = (const float*)d_in[3];
  const float* Wk   = (const float*)d_in[4];
  const float* Wv   = (const float*)d_in[5];
  const float* Wo   = (const float*)d_in[6];
  float* out = (float*)d_out;

  bf16_t* ws = (bf16_t*)d_ws;
  size_t o = 0;
  bf16_t* xb    = ws + o; o += (size_t)4096 * 2048;
  bf16_t* Wqkvt = ws + o; o += (size_t)3072 * 2048;
  bf16_t* Wot   = ws + o; o += (size_t)2048 * 2048;
  bf16_t* qkv   = ws + o; o += (size_t)4096 * 3072;
  bf16_t* Qr    = ws + o; o += (size_t)B_ * H_ * S_ * HD_;
  bf16_t* Krb   = ws + o; o += (size_t)B_ * KV_ * S_ * HD_;
  bf16_t* Vtb   = ws + o; o += (size_t)B_ * KV_ * S_ * HD_;
  bf16_t* AO    = ws + o; o += (size_t)4096 * 2048;

  // fused prep: x->bf16 + all weight transposes (one launch)
  prep_all<<<18432, dim3(32, 8), 0, stream>>>(x, xb, Wq, Wk, Wv, Wo, Wqkvt, Wot);
  // QKV projection: BN=192 -> 256 blocks = 1/CU, XCD-swizzled (proven 2-buf)
  gemm256<192, 2, bf16_t><<<dim3(3072/192, 4096/256), 512, 0, stream>>>(
      xb, Wqkvt, qkv, 3072, 2048);
  // RoPE + scatter (vectorized), V transpose
  rope_scatter2<<<4096, 256, 0, stream>>>(qkv, cosb, sinb, Qr, Krb);
  v_transpose<<<dim3(16, 64, 2), dim3(32, 8), 0, stream>>>(qkv, Vtb);
  // paired-chunk attention (unchanged)
  attn9<<<dim3(16, 32), 256, 0, stream>>>(Qr, Krb, Vtb, AO);
  // output projection -> f32: 3-buffer TRUE counted-vmcnt pipeline (the clean T4 test)
  gemm_out3<<<dim3(2048/128, 4096/256), 512, 0, stream>>>(AO, Wot, out, 2048, 2048);
}

// Round 17
// 172.229 us; speedup vs baseline: 1.1062x; 1.0069x over previous
//
#include <hip/hip_runtime.h>
#include <hip/hip_bf16.h>
#include <stdint.h>

#define B_ 2
#define S_ 2048
#define D_ 2048
#define H_ 32
#define KV_ 8
#define HD_ 64
#define NQKV 3072   // D + 2*KV*HD

typedef __bf16 bf16_t;
typedef __bf16 bf16x8 __attribute__((ext_vector_type(8)));
typedef __bf16 bf16x4 __attribute__((ext_vector_type(4)));
typedef float  f32x4  __attribute__((ext_vector_type(4)));
typedef float  f32x16 __attribute__((ext_vector_type(16)));
typedef unsigned int u32;
typedef u32 u32x4 __attribute__((ext_vector_type(4)));

typedef const __attribute__((address_space(1))) uint32_t* gp1_t;
typedef __attribute__((address_space(3))) uint32_t* lp3_t;

// async global->LDS, 16B per lane. LDS dest is wave-uniform base + lane*16.
__device__ inline void gload_lds16(const void* g, void* l) {
  __builtin_amdgcn_global_load_lds((gp1_t)(uintptr_t)g, (lp3_t)(uint32_t)(uintptr_t)l,
                                   16, 0, 0);
}

__device__ inline u32 pkbf(float a, float b) {
  union { bf16_t h[2]; u32 u; } v;
  v.h[0] = (bf16_t)a; v.h[1] = (bf16_t)b;
  return v.u;
}

// v_permlane32_swap_b32: a = [a_lo, b_lo], b = [a_hi, b_hi]
__device__ inline void pl32swap(u32 &a, u32 &b) {
  asm("v_permlane32_swap_b32 %0, %1" : "+v"(a), "+v"(b));
}

// ---------------- fused prep: x cvt + all 4 weight transposes ----------------
__global__ void prep_all(const float* __restrict__ x, bf16_t* __restrict__ xb,
                         const float* __restrict__ Wq, const float* __restrict__ Wk,
                         const float* __restrict__ Wv, const float* __restrict__ Wo,
                         bf16_t* __restrict__ Wqkvt, bf16_t* __restrict__ Wot) {
  const int id = blockIdx.x;
  const int tid = threadIdx.y * 32 + threadIdx.x;
  if (id < 8192) {                      // x -> bf16 (2097152 float4s)
    const int i = id * 256 + tid;
    float4 v = ((const float4*)x)[i];
    bf16x4 o;
    o[0] = (bf16_t)v.x; o[1] = (bf16_t)v.y; o[2] = (bf16_t)v.z; o[3] = (bf16_t)v.w;
    ((bf16x4*)xb)[i] = o;
    return;
  }
  __shared__ float t[32][33];
  const int wid = id - 8192;
  const float* in; bf16_t* out; int C, roff, bx, by;
  if (wid < 4096)      { in = Wq; out = Wqkvt; C = 2048; roff = 0;    bx = wid & 63;          by = wid >> 6; }
  else if (wid < 5120) { in = Wk; out = Wqkvt; C = 512;  roff = 2048; bx = (wid - 4096) & 15; by = (wid - 4096) >> 4; }
  else if (wid < 6144) { in = Wv; out = Wqkvt; C = 512;  roff = 2560; bx = (wid - 5120) & 15; by = (wid - 5120) >> 4; }
  else                 { in = Wo; out = Wot;   C = 2048; roff = 0;    bx = (wid - 6144) & 63; by = (wid - 6144) >> 6; }
  const int tx = threadIdx.x, ty = threadIdx.y;   // (32,8)
  const int c0 = bx * 32, r0 = by * 32;
#pragma unroll
  for (int j = 0; j < 4; ++j)
    t[ty + j*8][tx] = in[(int64_t)(r0 + ty + j*8) * C + c0 + tx];
  __syncthreads();
#pragma unroll
  for (int j = 0; j < 4; ++j)
    out[(int64_t)(roff + c0 + ty + j*8) * 2048 + r0 + tx] = (bf16_t)t[tx][ty + j*8];
}

// ---------------- fused scatter: RoPE Q/K + V transpose ----------------
#define QSCALE 0.18033688011112042f
__global__ __launch_bounds__(256) void scatter_all(const bf16_t* __restrict__ qkv,
                                                   const float* __restrict__ cosb,
                                                   const float* __restrict__ sinb,
                                                   bf16_t* __restrict__ Q,
                                                   bf16_t* __restrict__ Kr,
                                                   bf16_t* __restrict__ Vt) {
  const int id = blockIdx.x;
  const int tid = threadIdx.x;
  if (id < 4096) {                       // RoPE rows
    const int row = id;                  // b*S + s
    const int b = row >> 11, s = row & 2047;
    const bf16_t* src = qkv + (int64_t)row * NQKV;
    const float* cs = cosb + s * HD_;
    const float* sn = sinb + s * HD_;
    {                                    // Q
      const int c0 = tid * 8;
      const int d0 = c0 & 63, h = c0 >> 6;
      bf16x8 own = *(const bf16x8*)(src + c0);
      bf16x8 par = *(const bf16x8*)(src + (c0 ^ 32));
      const float sgn = (d0 & 32) ? 1.f : -1.f;
      bf16x8 o;
#pragma unroll
      for (int j = 0; j < 8; ++j) {
        const int d = d0 + j;
        float val = (float)own[j] * cs[d] + sgn * (float)par[j] * sn[d];
        o[j] = (bf16_t)(val * QSCALE);
      }
      *(bf16x8*)(Q + ((int64_t)(b * H_ + h) * S_ + s) * HD_ + d0) = o;
    }
    if (tid < 64) {                      // K
      const int c0 = 2048 + tid * 8;
      const int d0 = (tid * 8) & 63, kvh = tid >> 3;
      bf16x8 own = *(const bf16x8*)(src + c0);
      bf16x8 par = *(const bf16x8*)(src + (c0 ^ 32));
      const float sgn = (d0 & 32) ? 1.f : -1.f;
      bf16x8 o;
#pragma unroll
      for (int j = 0; j < 8; ++j) {
        const int d = d0 + j;
        float val = (float)own[j] * cs[d] + sgn * (float)par[j] * sn[d];
        o[j] = (bf16_t)val;
      }
      *(bf16x8*)(Kr + ((int64_t)(b * KV_ + kvh) * S_ + s) * HD_ + d0) = o;
    }
    return;
  }
  // V transpose tiles: wid = c-tile(16) x s-tile(64) x b(2)
  __shared__ bf16_t t[32][34];
  const int wid = id - 4096;
  const int c0 = (wid & 15) * 32;
  const int s0 = ((wid >> 4) & 63) * 32;
  const int b  = wid >> 10;
  const int tx = tid & 31, ty = tid >> 5;   // (32,8)
#pragma unroll
  for (int j = 0; j < 4; ++j)
    t[ty + j*8][tx] = qkv[(int64_t)(b * S_ + s0 + ty + j*8) * NQKV + 2560 + c0 + tx];
  __syncthreads();
#pragma unroll
  for (int j = 0; j < 4; ++j)
    Vt[(int64_t)(b * 512 + c0 + ty + j*8) * S_ + s0 + tx] = t[tx][ty + j*8];
}

// ---------------- 256-row deep-pipelined GEMM (2-buf, XCD swizzle) ----------------
template <int BN, int EPI, typename OutT>
__global__ __launch_bounds__(512, 2) void gemm256(const bf16_t* __restrict__ A,
                                                  const bf16_t* __restrict__ Bt,
                                                  OutT* __restrict__ Cout,
                                                  int N, int K) {
  constexpr int NB = BN / 64;
  constexpr int LT = 4 + NB;
  constexpr int WCOLS = BN / 4;
  constexpr int NF = WCOLS / 16;

  __shared__ bf16_t As[2][256 * 64];
  __shared__ bf16_t Bs[2][BN * 64];

  const int tid = threadIdx.x;
  const int w = tid >> 6, lane = tid & 63;
  const int l15 = lane & 15, l4 = lane >> 4;
  const int wr = w >> 2, wc = w & 3;

  const int nX = gridDim.x;
  const int lin = blockIdx.y * nX + blockIdx.x;
  const int cpx = (nX * gridDim.y) >> 3;
  const int swz = (lin & 7) * cpx + (lin >> 3);
  const int bm = (swz / nX) * 256, bn = (swz % nX) * BN;

  const int rw = w * 8 + (lane >> 3);
  const int srcg = ((lane & 7) ^ ((lane >> 3) & 7)) << 3;
  const bf16_t* PA[4];
  const bf16_t* PB[NB];
#pragma unroll
  for (int L = 0; L < 4; ++L)
    PA[L] = A + (int64_t)(bm + L * 64 + rw) * K + srcg;
#pragma unroll
  for (int L = 0; L < NB; ++L)
    PB[L] = Bt + (int64_t)(bn + L * 64 + rw) * K + srcg;

  const int NK = K >> 6;
  const int xr = l15 & 7;
  const int g0 = (l4 ^ xr) << 3;
  const int g1 = ((4 + l4) ^ xr) << 3;

  f32x4 acc[8][NF] = {};

  auto stage = [&](int s, int buf, int toff) {
    if (s < 4) gload_lds16(PA[s] + toff, &As[buf][s * 4096 + w * 512]);
    else       gload_lds16(PB[s - 4] + toff, &Bs[buf][(s - 4) * 4096 + w * 512]);
  };

#pragma unroll
  for (int s = 0; s < LT; ++s) stage(s, 0, 0);
  asm volatile("s_waitcnt vmcnt(0)" ::: "memory");
  __syncthreads();

  for (int t = 0; t < NK; ++t) {
    const int p = t & 1;
    const bool more = (t + 1) < NK;
    const int toff = (t + 1) << 6;
    const bf16_t* Ab = &As[p][0];
    const bf16_t* Bb = &Bs[p][0];

    bf16x8 ball[NF][2];
#pragma unroll
    for (int nn = 0; nn < NF; ++nn) {
      const int rb = wc * WCOLS + nn * 16 + l15;
      ball[nn][0] = *(const bf16x8*)(Bb + rb * 64 + g0);
      ball[nn][1] = *(const bf16x8*)(Bb + rb * 64 + g1);
    }

#pragma unroll
    for (int mh = 0; mh < 2; ++mh) {
      if (more) {
        const int sb = mh * (LT / 2);
        const int se = (mh == 0) ? (LT / 2) : LT;
#pragma unroll
        for (int s = sb; s < se; ++s) stage(s, p ^ 1, toff);
      }
      bf16x8 af[4][2];
#pragma unroll
      for (int mm = 0; mm < 4; ++mm) {
        const int ra = wr * 128 + (mh * 4 + mm) * 16 + l15;
        af[mm][0] = *(const bf16x8*)(Ab + ra * 64 + g0);
        af[mm][1] = *(const bf16x8*)(Ab + ra * 64 + g1);
      }
      __builtin_amdgcn_s_setprio(1);
#pragma unroll
      for (int mm = 0; mm < 4; ++mm)
#pragma unroll
        for (int nn = 0; nn < NF; ++nn) {
          acc[mh*4+mm][nn] = __builtin_amdgcn_mfma_f32_16x16x32_bf16(
              af[mm][0], ball[nn][0], acc[mh*4+mm][nn], 0, 0, 0);
          acc[mh*4+mm][nn] = __builtin_amdgcn_mfma_f32_16x16x32_bf16(
              af[mm][1], ball[nn][1], acc[mh*4+mm][nn], 0, 0, 0);
        }
      __builtin_amdgcn_s_setprio(0);
    }
    if (more) {
      asm volatile("s_waitcnt vmcnt(0)" ::: "memory");
      __syncthreads();
    }
  }

#pragma unroll
  for (int m = 0; m < 8; ++m) {
    const int row = bm + wr * 128 + m * 16 + l4 * 4;
#pragma unroll
    for (int n = 0; n < NF; ++n) {
      const int col = bn + wc * WCOLS + n * 16 + l15;
#pragma unroll
      for (int r = 0; r < 4; ++r)
        Cout[(int64_t)(row + r) * N + col] = (OutT)acc[m][n][r];
    }
  }
}

// ---------------- flash attention: paired chunks, branch-free full tiles ----------------
// grid (16 = b*8+kvh, 32 = y). 4 waves; wave w = head kvh*4+w, chunks {y, 63-y}.
// Full tile (kv0+32 <= q0B): straight-line QK(B0,B1)->SM(B)->QK(A)||PV(B)->SM(A)->PV(A)
// (4 independent MFMA chains hide softmax VALU). Tail: B sub0 only (A provably inactive).
#define SHIFT_ 8.0f
__global__ __launch_bounds__(256, 2) void attn10(const bf16_t* __restrict__ Q,
                                                 const bf16_t* __restrict__ Kr,
                                                 const bf16_t* __restrict__ Vt,
                                                 bf16_t* __restrict__ AO) {
  const int bk = blockIdx.x;
  const int b = bk >> 3, kvh = bk & 7;
  const int y = blockIdx.y;               // 0..31
  const int q0A = y * 32, q0B = (63 - y) * 32;
  const int tid = threadIdx.x;
  const int w = tid >> 6, lane = tid & 63;
  const int l31 = lane & 31, hi = lane >> 5;
  const int h = kvh * 4 + w;

  __shared__ __align__(16) bf16_t Ks[3][64 * 64];
  __shared__ __align__(16) bf16_t Vs[3][64 * 64];

  const bf16_t* Kg = Kr + (int64_t)(b * KV_ + kvh) * S_ * HD_;
  const bf16_t* Vg = Vt + (int64_t)(b * KV_ + kvh) * HD_ * S_;

  const int rL = (w << 3) + (lane >> 3);
  const int sgr = ((lane & 7) ^ (rL & 7)) << 3;
  const bf16_t* Ksrc = Kg + (int64_t)rL * HD_ + sgr;
  const bf16_t* Vsrc = Vg + (int64_t)rL * S_ + sgr;

  const int NT = (63 - y) / 2 + 1;

  auto stage = [&](int t) {               // exactly 4 loads per wave (uniform vmcnt)
    const int tc = (t < NT) ? t : (NT - 1);
    char* Kd = (char*)Ks + (t % 3) * 8192 + w * 1024;
    char* Vd = (char*)Vs + (t % 3) * 8192 + w * 1024;
    gload_lds16(Ksrc + (int64_t)tc * 64 * HD_, Kd);
    gload_lds16(Ksrc + (int64_t)(tc * 64 + 32) * HD_, Kd + 4096);
    gload_lds16(Vsrc + tc * 64, Vd);
    gload_lds16(Vsrc + (int64_t)32 * S_ + tc * 64, Vd + 4096);
  };

  const bf16_t* QbA = Q + ((int64_t)(b * H_ + h) * S_ + q0A) * HD_;
  const bf16_t* QbB = Q + ((int64_t)(b * H_ + h) * S_ + q0B) * HD_;
  bf16x8 qfA[4], qfB[4];
#pragma unroll
  for (int ds = 0; ds < 4; ++ds) {
    qfA[ds] = *(const bf16x8*)(QbA + l31 * HD_ + ds * 16 + hi * 8);
    qfB[ds] = *(const bf16x8*)(QbB + l31 * HD_ + ds * 16 + hi * 8);
  }

  bf16x8 onesf;
#pragma unroll
  for (int i = 0; i < 8; ++i) onesf[i] = (bf16_t)1.0f;

  f32x16 aA0 = {}, aA1 = {}, aB0 = {}, aB1 = {};
  f32x16 lA = {}, lB = {};
  const int xorb = l31 & 7;

  const f32x16 sinit = {-SHIFT_, -SHIFT_, -SHIFT_, -SHIFT_,
                        -SHIFT_, -SHIFT_, -SHIFT_, -SHIFT_,
                        -SHIFT_, -SHIFT_, -SHIFT_, -SHIFT_,
                        -SHIFT_, -SHIFT_, -SHIFT_, -SHIFT_};

  auto softmax_pack = [&](const f32x16 &sacc, bool diag,
                          bf16x8 &pf0, bf16x8 &pf1) {
    float p[16];
#pragma unroll
    for (int r = 0; r < 16; ++r) {
      float sc = sacc[r];
      if (diag) {
        int kvpos = (r & 3) + 8 * (r >> 2) + 4 * hi;
        if (kvpos > l31) sc = -1e30f;
      }
      p[r] = __builtin_amdgcn_exp2f(sc);
    }
    u32 pk[8];
#pragma unroll
    for (int i = 0; i < 8; ++i) pk[i] = pkbf(p[2*i], p[2*i+1]);
    u32 a0 = pk[0], b0 = pk[2]; pl32swap(a0, b0);
    u32 a1 = pk[1], b1 = pk[3]; pl32swap(a1, b1);
    u32 a2 = pk[4], b2 = pk[6]; pl32swap(a2, b2);
    u32 a3 = pk[5], b3 = pk[7]; pl32swap(a3, b3);
    pf0 = __builtin_bit_cast(bf16x8, (u32x4){a0, a1, b0, b1});
    pf1 = __builtin_bit_cast(bf16x8, (u32x4){a2, a3, b2, b3});
  };

  stage(0);
  stage(1);

  for (int t = 0; t < NT; ++t) {
    asm volatile("s_waitcnt vmcnt(4) lgkmcnt(0)" ::: "memory");
    asm volatile("s_barrier" ::: "memory");
    stage(t + 2);
    const char* KsB = (const char*)Ks + (t % 3) * 8192;
    const char* VsB = (const char*)Vs + (t % 3) * 8192;
    const int kv0 = t * 64;
    const char* Vb0 = VsB + l31 * 128;
    const char* Vb1 = VsB + (32 + l31) * 128;
    auto vld = [&](const char* base, int c) {
      return *(const bf16x8*)(base + ((c ^ xorb) << 4));
    };

    if (kv0 + 32 <= q0B) {
      // ---- full tile: both subs for B; A guarded but usually both-active ----
      const bool actA0 = (kv0 <= q0A), actA1 = (kv0 + 32 <= q0A);
      const bool dB1 = (kv0 + 32 == q0B);
      const bool dA0 = (kv0 == q0A), dA1 = (kv0 + 32 == q0A);
      const char* Kb0 = KsB + l31 * 128;
      const char* Kb1 = KsB + (32 + l31) * 128;
      bf16x8 kf0[4], kf1[4];
#pragma unroll
      for (int ds = 0; ds < 4; ++ds) {
        kf0[ds] = *(const bf16x8*)(Kb0 + ((((ds << 1) + hi) ^ xorb) << 4));
        kf1[ds] = *(const bf16x8*)(Kb1 + ((((ds << 1) + hi) ^ xorb) << 4));
      }
      // QK for B, both subs (2 independent chains)
      f32x16 s0 = sinit, s1 = sinit;
      __builtin_amdgcn_s_setprio(1);
#pragma unroll
      for (int ds = 0; ds < 4; ++ds) {
        s0 = __builtin_amdgcn_mfma_f32_32x32x16_bf16(kf0[ds], qfB[ds], s0, 0, 0, 0);
        s1 = __builtin_amdgcn_mfma_f32_32x32x16_bf16(kf1[ds], qfB[ds], s1, 0, 0, 0);
      }
      __builtin_amdgcn_s_setprio(0);
      // SM(B0), SM(B1)
      bf16x8 pB00, pB01, pB10, pB11;
      softmax_pack(s0, false, pB00, pB01);
      softmax_pack(s1, dB1, pB10, pB11);
      // QK for A (reuses s0/s1 regs) — independent of PV(B), overlaps SM/PV
      f32x16 t0 = sinit, t1 = sinit;
      __builtin_amdgcn_s_setprio(1);
      if (actA0) {
#pragma unroll
        for (int ds = 0; ds < 4; ++ds)
          t0 = __builtin_amdgcn_mfma_f32_32x32x16_bf16(kf0[ds], qfA[ds], t0, 0, 0, 0);
      }
      if (actA1) {
#pragma unroll
        for (int ds = 0; ds < 4; ++ds)
          t1 = __builtin_amdgcn_mfma_f32_32x32x16_bf16(kf1[ds], qfA[ds], t1, 0, 0, 0);
      }
      // PV(B) both subs
      bf16x8 v00 = vld(Vb0, hi),     v01 = vld(Vb0, 2 + hi);
      bf16x8 v10 = vld(Vb1, hi),     v11 = vld(Vb1, 2 + hi);
      bf16x8 w00 = vld(Vb0, 4 + hi), w01 = vld(Vb0, 6 + hi);
      bf16x8 w10 = vld(Vb1, 4 + hi), w11 = vld(Vb1, 6 + hi);
      aB0 = __builtin_amdgcn_mfma_f32_32x32x16_bf16(v00, pB00, aB0, 0, 0, 0);
      aB1 = __builtin_amdgcn_mfma_f32_32x32x16_bf16(v10, pB00, aB1, 0, 0, 0);
      aB0 = __builtin_amdgcn_mfma_f32_32x32x16_bf16(v01, pB01, aB0, 0, 0, 0);
      aB1 = __builtin_amdgcn_mfma_f32_32x32x16_bf16(v11, pB01, aB1, 0, 0, 0);
      aB0 = __builtin_amdgcn_mfma_f32_32x32x16_bf16(w00, pB10, aB0, 0, 0, 0);
      aB1 = __builtin_amdgcn_mfma_f32_32x32x16_bf16(w10, pB10, aB1, 0, 0, 0);
      aB0 = __builtin_amdgcn_mfma_f32_32x32x16_bf16(w01, pB11, aB0, 0, 0, 0);
      aB1 = __builtin_amdgcn_mfma_f32_32x32x16_bf16(w11, pB11, aB1, 0, 0, 0);
      lB  = __builtin_amdgcn_mfma_f32_32x32x16_bf16(onesf, pB00, lB, 0, 0, 0);
      lB  = __builtin_amdgcn_mfma_f32_32x32x16_bf16(onesf, pB01, lB, 0, 0, 0);
      lB  = __builtin_amdgcn_mfma_f32_32x32x16_bf16(onesf, pB10, lB, 0, 0, 0);
      lB  = __builtin_amdgcn_mfma_f32_32x32x16_bf16(onesf, pB11, lB, 0, 0, 0);
      __builtin_amdgcn_s_setprio(0);
      // SM(A) + PV(A)
      if (actA0) {
        bf16x8 pA0, pA1;
        softmax_pack(t0, dA0, pA0, pA1);
        __builtin_amdgcn_s_setprio(1);
        aA0 = __builtin_amdgcn_mfma_f32_32x32x16_bf16(v00, pA0, aA0, 0, 0, 0);
        aA1 = __builtin_amdgcn_mfma_f32_32x32x16_bf16(v10, pA0, aA1, 0, 0, 0);
        aA0 = __builtin_amdgcn_mfma_f32_32x32x16_bf16(v01, pA1, aA0, 0, 0, 0);
        aA1 = __builtin_amdgcn_mfma_f32_32x32x16_bf16(v11, pA1, aA1, 0, 0, 0);
        lA  = __builtin_amdgcn_mfma_f32_32x32x16_bf16(onesf, pA0, lA, 0, 0, 0);
        lA  = __builtin_amdgcn_mfma_f32_32x32x16_bf16(onesf, pA1, lA, 0, 0, 0);
        __builtin_amdgcn_s_setprio(0);
      }
      if (actA1) {
        bf16x8 pA0, pA1;
        softmax_pack(t1, dA1, pA0, pA1);
        __builtin_amdgcn_s_setprio(1);
        aA0 = __builtin_amdgcn_mfma_f32_32x32x16_bf16(w00, pA0, aA0, 0, 0, 0);
        aA1 = __builtin_amdgcn_mfma_f32_32x32x16_bf16(w10, pA0, aA1, 0, 0, 0);
        aA0 = __builtin_amdgcn_mfma_f32_32x32x16_bf16(w01, pA1, aA0, 0, 0, 0);
        aA1 = __builtin_amdgcn_mfma_f32_32x32x16_bf16(w11, pA1, aA1, 0, 0, 0);
        lA  = __builtin_amdgcn_mfma_f32_32x32x16_bf16(onesf, pA0, lA, 0, 0, 0);
        lA  = __builtin_amdgcn_mfma_f32_32x32x16_bf16(onesf, pA1, lA, 0, 0, 0);
        __builtin_amdgcn_s_setprio(0);
      }
    } else if (kv0 <= q0B) {
      // ---- tail: B sub0 only (A provably inactive: q0A <= q0B-32 < kv0) ----
      const char* Kb0 = KsB + l31 * 128;
      bf16x8 kf0[4];
#pragma unroll
      for (int ds = 0; ds < 4; ++ds)
        kf0[ds] = *(const bf16x8*)(Kb0 + ((((ds << 1) + hi) ^ xorb) << 4));
      f32x16 s0 = sinit;
      __builtin_amdgcn_s_setprio(1);
#pragma unroll
      for (int ds = 0; ds < 4; ++ds)
        s0 = __builtin_amdgcn_mfma_f32_32x32x16_bf16(kf0[ds], qfB[ds], s0, 0, 0, 0);
      __builtin_amdgcn_s_setprio(0);
      bf16x8 pB0, pB1;
      softmax_pack(s0, kv0 == q0B, pB0, pB1);
      bf16x8 v00 = vld(Vb0, hi), v01 = vld(Vb0, 2 + hi);
      bf16x8 v10 = vld(Vb1, hi), v11 = vld(Vb1, 2 + hi);
      __builtin_amdgcn_s_setprio(1);
      aB0 = __builtin_amdgcn_mfma_f32_32x32x16_bf16(v00, pB0, aB0, 0, 0, 0);
      aB1 = __builtin_amdgcn_mfma_f32_32x32x16_bf16(v10, pB0, aB1, 0, 0, 0);
      aB0 = __builtin_amdgcn_mfma_f32_32x32x16_bf16(v01, pB1, aB0, 0, 0, 0);
      aB1 = __builtin_amdgcn_mfma_f32_32x32x16_bf16(v11, pB1, aB1, 0, 0, 0);
      lB  = __builtin_amdgcn_mfma_f32_32x32x16_bf16(onesf, pB0, lB, 0, 0, 0);
      lB  = __builtin_amdgcn_mfma_f32_32x32x16_bf16(onesf, pB1, lB, 0, 0, 0);
      __builtin_amdgcn_s_setprio(0);
    }
  }

  asm volatile("s_waitcnt vmcnt(0)" ::: "memory");

  auto epi = [&](const f32x16 &a0, const f32x16 &a1, float denom, int q0) {
    const float rl = 1.f / denom;
    const int64_t row = (int64_t)(b * S_ + q0 + l31);
#pragma unroll
    for (int dt = 0; dt < 2; ++dt) {
#pragma unroll
      for (int g = 0; g < 4; ++g) {
        bf16x4 ov;
#pragma unroll
        for (int j = 0; j < 4; ++j) {
          float val = (dt ? a1[4*g + j] : a0[4*g + j]) * rl;
          ov[j] = (bf16_t)val;
        }
        const int d0 = dt * 32 + g * 8 + hi * 4;
        *(bf16x4*)(AO + row * D_ + h * HD_ + d0) = ov;
      }
    }
  };
  epi(aA0, aA1, lA[0], q0A);
  epi(aB0, aB1, lB[0], q0B);
}

// ---------------- launcher ----------------
extern "C" void kernel_launch(void* const* d_in, const int* in_sizes, int n_in,
                              void* d_out, int out_size, void* d_ws, size_t ws_size,
                              hipStream_t stream) {
  const float* x    = (const float*)d_in[0];
  const float* cosb = (const float*)d_in[1];
  const float* sinb = (const float*)d_in[2];
  const float* Wq   = (const float*)d_in[3];
  const float* Wk   = (const float*)d_in[4];
  const float* Wv   = (const float*)d_in[5];
  const float* Wo   = (const float*)d_in[6];
  float* out = (float*)d_out;

  bf16_t* ws = (bf16_t*)d_ws;
  size_t o = 0;
  bf16_t* xb    = ws + o; o += (size_t)4096 * 2048;
  bf16_t* Wqkvt = ws + o; o += (size_t)3072 * 2048;
  bf16_t* Wot   = ws + o; o += (size_t)2048 * 2048;
  bf16_t* qkv   = ws + o; o += (size_t)4096 * 3072;
  bf16_t* Qr    = ws + o; o += (size_t)B_ * H_ * S_ * HD_;
  bf16_t* Krb   = ws + o; o += (size_t)B_ * KV_ * S_ * HD_;
  bf16_t* Vtb   = ws + o; o += (size_t)B_ * KV_ * S_ * HD_;
  bf16_t* AO    = ws + o; o += (size_t)4096 * 2048;

  // fused prep: x->bf16 + all weight transposes
  prep_all<<<18432, dim3(32, 8), 0, stream>>>(x, xb, Wq, Wk, Wv, Wo, Wqkvt, Wot);
  // QKV projection: BN=192 -> 256 blocks = 1/CU, XCD-swizzled
  gemm256<192, 2, bf16_t><<<dim3(3072/192, 4096/256), 512, 0, stream>>>(
      xb, Wqkvt, qkv, 3072, 2048);
  // fused RoPE scatter + V transpose
  scatter_all<<<6144, 256, 0, stream>>>(qkv, cosb, sinb, Qr, Krb, Vtb);
  // paired-chunk attention with branch-free full tiles
  attn10<<<dim3(16, 32), 256, 0, stream>>>(Qr, Krb, Vtb, AO);
  // output projection -> f32 (BN=128 -> 256 blocks = 1/CU, XCD-swizzled)
  gemm256<128, 0, float><<<dim3(2048/128, 4096/256), 512, 0, stream>>>(
      AO, Wot, out, 2048, 2048);
}

// Round 18
// 172.069 us; speedup vs baseline: 1.1072x; 1.0009x over previous
//
#include <hip/hip_runtime.h>
#include <hip/hip_bf16.h>
#include <stdint.h>

#define B_ 2
#define S_ 2048
#define D_ 2048
#define H_ 32
#define KV_ 8
#define HD_ 64
#define NQKV 3072   // D + 2*KV*HD

typedef __bf16 bf16_t;
typedef __bf16 bf16x8 __attribute__((ext_vector_type(8)));
typedef __bf16 bf16x4 __attribute__((ext_vector_type(4)));
typedef float  f32x4  __attribute__((ext_vector_type(4)));
typedef float  f32x16 __attribute__((ext_vector_type(16)));
typedef unsigned int u32;
typedef u32 u32x4 __attribute__((ext_vector_type(4)));

typedef const __attribute__((address_space(1))) uint32_t* gp1_t;
typedef __attribute__((address_space(3))) uint32_t* lp3_t;

// async global->LDS, 16B per lane. LDS dest is wave-uniform base + lane*16.
__device__ inline void gload_lds16(const void* g, void* l) {
  __builtin_amdgcn_global_load_lds((gp1_t)(uintptr_t)g, (lp3_t)(uint32_t)(uintptr_t)l,
                                   16, 0, 0);
}

__device__ inline u32 pkbf(float a, float b) {
  union { bf16_t h[2]; u32 u; } v;
  v.h[0] = (bf16_t)a; v.h[1] = (bf16_t)b;
  return v.u;
}

// v_permlane32_swap_b32: a = [a_lo, b_lo], b = [a_hi, b_hi]
__device__ inline void pl32swap(u32 &a, u32 &b) {
  asm("v_permlane32_swap_b32 %0, %1" : "+v"(a), "+v"(b));
}

// ---------------- fused prep: x cvt + all 4 weight transposes ----------------
__global__ void prep_all(const float* __restrict__ x, bf16_t* __restrict__ xb,
                         const float* __restrict__ Wq, const float* __restrict__ Wk,
                         const float* __restrict__ Wv, const float* __restrict__ Wo,
                         bf16_t* __restrict__ Wqkvt, bf16_t* __restrict__ Wot) {
  const int id = blockIdx.x;
  const int tid = threadIdx.y * 32 + threadIdx.x;
  if (id < 8192) {                      // x -> bf16 (2097152 float4s)
    const int i = id * 256 + tid;
    float4 v = ((const float4*)x)[i];
    bf16x4 o;
    o[0] = (bf16_t)v.x; o[1] = (bf16_t)v.y; o[2] = (bf16_t)v.z; o[3] = (bf16_t)v.w;
    ((bf16x4*)xb)[i] = o;
    return;
  }
  __shared__ float t[32][33];
  const int wid = id - 8192;
  const float* in; bf16_t* out; int C, roff, bx, by;
  if (wid < 4096)      { in = Wq; out = Wqkvt; C = 2048; roff = 0;    bx = wid & 63;          by = wid >> 6; }
  else if (wid < 5120) { in = Wk; out = Wqkvt; C = 512;  roff = 2048; bx = (wid - 4096) & 15; by = (wid - 4096) >> 4; }
  else if (wid < 6144) { in = Wv; out = Wqkvt; C = 512;  roff = 2560; bx = (wid - 5120) & 15; by = (wid - 5120) >> 4; }
  else                 { in = Wo; out = Wot;   C = 2048; roff = 0;    bx = (wid - 6144) & 63; by = (wid - 6144) >> 6; }
  const int tx = threadIdx.x, ty = threadIdx.y;   // (32,8)
  const int c0 = bx * 32, r0 = by * 32;
#pragma unroll
  for (int j = 0; j < 4; ++j)
    t[ty + j*8][tx] = in[(int64_t)(r0 + ty + j*8) * C + c0 + tx];
  __syncthreads();
#pragma unroll
  for (int j = 0; j < 4; ++j)
    out[(int64_t)(roff + c0 + ty + j*8) * 2048 + r0 + tx] = (bf16_t)t[tx][ty + j*8];
}

// ---------------- fused scatter: RoPE Q/K + V transpose ----------------
#define QSCALE 0.18033688011112042f
__global__ __launch_bounds__(256) void scatter_all(const bf16_t* __restrict__ qkv,
                                                   const float* __restrict__ cosb,
                                                   const float* __restrict__ sinb,
                                                   bf16_t* __restrict__ Q,
                                                   bf16_t* __restrict__ Kr,
                                                   bf16_t* __restrict__ Vt) {
  const int id = blockIdx.x;
  const int tid = threadIdx.x;
  if (id < 4096) {                       // RoPE rows
    const int row = id;                  // b*S + s
    const int b = row >> 11, s = row & 2047;
    const bf16_t* src = qkv + (int64_t)row * NQKV;
    const float* cs = cosb + s * HD_;
    const float* sn = sinb + s * HD_;
    {                                    // Q
      const int c0 = tid * 8;
      const int d0 = c0 & 63, h = c0 >> 6;
      bf16x8 own = *(const bf16x8*)(src + c0);
      bf16x8 par = *(const bf16x8*)(src + (c0 ^ 32));
      const float sgn = (d0 & 32) ? 1.f : -1.f;
      bf16x8 o;
#pragma unroll
      for (int j = 0; j < 8; ++j) {
        const int d = d0 + j;
        float val = (float)own[j] * cs[d] + sgn * (float)par[j] * sn[d];
        o[j] = (bf16_t)(val * QSCALE);
      }
      *(bf16x8*)(Q + ((int64_t)(b * H_ + h) * S_ + s) * HD_ + d0) = o;
    }
    if (tid < 64) {                      // K
      const int c0 = 2048 + tid * 8;
      const int d0 = (tid * 8) & 63, kvh = tid >> 3;
      bf16x8 own = *(const bf16x8*)(src + c0);
      bf16x8 par = *(const bf16x8*)(src + (c0 ^ 32));
      const float sgn = (d0 & 32) ? 1.f : -1.f;
      bf16x8 o;
#pragma unroll
      for (int j = 0; j < 8; ++j) {
        const int d = d0 + j;
        float val = (float)own[j] * cs[d] + sgn * (float)par[j] * sn[d];
        o[j] = (bf16_t)val;
      }
      *(bf16x8*)(Kr + ((int64_t)(b * KV_ + kvh) * S_ + s) * HD_ + d0) = o;
    }
    return;
  }
  // V transpose tiles: wid = c-tile(16) x s-tile(64) x b(2)
  __shared__ bf16_t t[32][34];
  const int wid = id - 4096;
  const int c0 = (wid & 15) * 32;
  const int s0 = ((wid >> 4) & 63) * 32;
  const int b  = wid >> 10;
  const int tx = tid & 31, ty = tid >> 5;   // (32,8)
#pragma unroll
  for (int j = 0; j < 4; ++j)
    t[ty + j*8][tx] = qkv[(int64_t)(b * S_ + s0 + ty + j*8) * NQKV + 2560 + c0 + tx];
  __syncthreads();
#pragma unroll
  for (int j = 0; j < 4; ++j)
    Vt[(int64_t)(b * 512 + c0 + ty + j*8) * S_ + s0 + tx] = t[tx][ty + j*8];
}

// ---------------- 256-row deep-pipelined GEMM (2-buf, XCD swizzle) ----------------
template <int BN, int EPI, typename OutT>
__global__ __launch_bounds__(512, 2) void gemm256(const bf16_t* __restrict__ A,
                                                  const bf16_t* __restrict__ Bt,
                                                  OutT* __restrict__ Cout,
                                                  int N, int K) {
  constexpr int NB = BN / 64;
  constexpr int LT = 4 + NB;
  constexpr int WCOLS = BN / 4;
  constexpr int NF = WCOLS / 16;

  __shared__ bf16_t As[2][256 * 64];
  __shared__ bf16_t Bs[2][BN * 64];

  const int tid = threadIdx.x;
  const int w = tid >> 6, lane = tid & 63;
  const int l15 = lane & 15, l4 = lane >> 4;
  const int wr = w >> 2, wc = w & 3;

  const int nX = gridDim.x;
  const int lin = blockIdx.y * nX + blockIdx.x;
  const int cpx = (nX * gridDim.y) >> 3;
  const int swz = (lin & 7) * cpx + (lin >> 3);
  const int bm = (swz / nX) * 256, bn = (swz % nX) * BN;

  const int rw = w * 8 + (lane >> 3);
  const int srcg = ((lane & 7) ^ ((lane >> 3) & 7)) << 3;
  const bf16_t* PA[4];
  const bf16_t* PB[NB];
#pragma unroll
  for (int L = 0; L < 4; ++L)
    PA[L] = A + (int64_t)(bm + L * 64 + rw) * K + srcg;
#pragma unroll
  for (int L = 0; L < NB; ++L)
    PB[L] = Bt + (int64_t)(bn + L * 64 + rw) * K + srcg;

  const int NK = K >> 6;
  const int xr = l15 & 7;
  const int g0 = (l4 ^ xr) << 3;
  const int g1 = ((4 + l4) ^ xr) << 3;

  f32x4 acc[8][NF] = {};

  auto stage = [&](int s, int buf, int toff) {
    if (s < 4) gload_lds16(PA[s] + toff, &As[buf][s * 4096 + w * 512]);
    else       gload_lds16(PB[s - 4] + toff, &Bs[buf][(s - 4) * 4096 + w * 512]);
  };

#pragma unroll
  for (int s = 0; s < LT; ++s) stage(s, 0, 0);
  asm volatile("s_waitcnt vmcnt(0)" ::: "memory");
  __syncthreads();

  for (int t = 0; t < NK; ++t) {
    const int p = t & 1;
    const bool more = (t + 1) < NK;
    const int toff = (t + 1) << 6;
    const bf16_t* Ab = &As[p][0];
    const bf16_t* Bb = &Bs[p][0];

    bf16x8 ball[NF][2];
#pragma unroll
    for (int nn = 0; nn < NF; ++nn) {
      const int rb = wc * WCOLS + nn * 16 + l15;
      ball[nn][0] = *(const bf16x8*)(Bb + rb * 64 + g0);
      ball[nn][1] = *(const bf16x8*)(Bb + rb * 64 + g1);
    }

#pragma unroll
    for (int mh = 0; mh < 2; ++mh) {
      if (more) {
        const int sb = mh * (LT / 2);
        const int se = (mh == 0) ? (LT / 2) : LT;
#pragma unroll
        for (int s = sb; s < se; ++s) stage(s, p ^ 1, toff);
      }
      bf16x8 af[4][2];
#pragma unroll
      for (int mm = 0; mm < 4; ++mm) {
        const int ra = wr * 128 + (mh * 4 + mm) * 16 + l15;
        af[mm][0] = *(const bf16x8*)(Ab + ra * 64 + g0);
        af[mm][1] = *(const bf16x8*)(Ab + ra * 64 + g1);
      }
      __builtin_amdgcn_s_setprio(1);
#pragma unroll
      for (int mm = 0; mm < 4; ++mm)
#pragma unroll
        for (int nn = 0; nn < NF; ++nn) {
          acc[mh*4+mm][nn] = __builtin_amdgcn_mfma_f32_16x16x32_bf16(
              af[mm][0], ball[nn][0], acc[mh*4+mm][nn], 0, 0, 0);
          acc[mh*4+mm][nn] = __builtin_amdgcn_mfma_f32_16x16x32_bf16(
              af[mm][1], ball[nn][1], acc[mh*4+mm][nn], 0, 0, 0);
        }
      __builtin_amdgcn_s_setprio(0);
    }
    if (more) {
      asm volatile("s_waitcnt vmcnt(0)" ::: "memory");
      __syncthreads();
    }
  }

#pragma unroll
  for (int m = 0; m < 8; ++m) {
    const int row = bm + wr * 128 + m * 16 + l4 * 4;
#pragma unroll
    for (int n = 0; n < NF; ++n) {
      const int col = bn + wc * WCOLS + n * 16 + l15;
#pragma unroll
      for (int r = 0; r < 4; ++r)
        Cout[(int64_t)(row + r) * N + col] = (OutT)acc[m][n][r];
    }
  }
}

// ---------------- flash attention: paired chunks + MFMA denominators ----------------
// grid (16 = b*8+kvh, 32 = y). 4 waves; wave w = head kvh*4+w, chunks {y, 63-y}.
// Counted vmcnt(4) + raw s_barrier: next tile's loads stay in flight across barrier.
#define SHIFT_ 8.0f
__global__ __launch_bounds__(256, 2) void attn9(const bf16_t* __restrict__ Q,
                                                const bf16_t* __restrict__ Kr,
                                                const bf16_t* __restrict__ Vt,
                                                bf16_t* __restrict__ AO) {
  const int bk = blockIdx.x;
  const int b = bk >> 3, kvh = bk & 7;
  const int y = blockIdx.y;               // 0..31
  const int q0A = y * 32, q0B = (63 - y) * 32;
  const int tid = threadIdx.x;
  const int w = tid >> 6, lane = tid & 63;
  const int l31 = lane & 31, hi = lane >> 5;
  const int h = kvh * 4 + w;

  __shared__ __align__(16) bf16_t Ks[3][64 * 64];
  __shared__ __align__(16) bf16_t Vs[3][64 * 64];

  const bf16_t* Kg = Kr + (int64_t)(b * KV_ + kvh) * S_ * HD_;
  const bf16_t* Vg = Vt + (int64_t)(b * KV_ + kvh) * HD_ * S_;

  const int rL = (w << 3) + (lane >> 3);
  const int sgr = ((lane & 7) ^ (rL & 7)) << 3;
  const bf16_t* Ksrc = Kg + (int64_t)rL * HD_ + sgr;
  const bf16_t* Vsrc = Vg + (int64_t)rL * S_ + sgr;

  const int NT = (63 - y) / 2 + 1;

  auto stage = [&](int t) {
    const int tc = (t < NT) ? t : (NT - 1);
    char* Kd = (char*)Ks + (t % 3) * 8192 + w * 1024;
    char* Vd = (char*)Vs + (t % 3) * 8192 + w * 1024;
    gload_lds16(Ksrc + (int64_t)tc * 64 * HD_, Kd);
    gload_lds16(Ksrc + (int64_t)(tc * 64 + 32) * HD_, Kd + 4096);
    gload_lds16(Vsrc + tc * 64, Vd);
    gload_lds16(Vsrc + (int64_t)32 * S_ + tc * 64, Vd + 4096);
  };

  const bf16_t* QbA = Q + ((int64_t)(b * H_ + h) * S_ + q0A) * HD_;
  const bf16_t* QbB = Q + ((int64_t)(b * H_ + h) * S_ + q0B) * HD_;
  bf16x8 qfA[4], qfB[4];
#pragma unroll
  for (int ds = 0; ds < 4; ++ds) {
    qfA[ds] = *(const bf16x8*)(QbA + l31 * HD_ + ds * 16 + hi * 8);
    qfB[ds] = *(const bf16x8*)(QbB + l31 * HD_ + ds * 16 + hi * 8);
  }

  bf16x8 onesf;
#pragma unroll
  for (int i = 0; i < 8; ++i) onesf[i] = (bf16_t)1.0f;

  f32x16 aA0 = {}, aA1 = {}, aB0 = {}, aB1 = {};
  f32x16 lA = {}, lB = {};
  const int xorb = l31 & 7;

  const f32x16 sinit = {-SHIFT_, -SHIFT_, -SHIFT_, -SHIFT_,
                        -SHIFT_, -SHIFT_, -SHIFT_, -SHIFT_,
                        -SHIFT_, -SHIFT_, -SHIFT_, -SHIFT_,
                        -SHIFT_, -SHIFT_, -SHIFT_, -SHIFT_};

  auto softmax_pack = [&](const f32x16 &sacc, bool diag,
                          bf16x8 &pf0, bf16x8 &pf1) {
    float p[16];
#pragma unroll
    for (int r = 0; r < 16; ++r) {
      float sc = sacc[r];
      if (diag) {
        int kvpos = (r & 3) + 8 * (r >> 2) + 4 * hi;
        if (kvpos > l31) sc = -1e30f;
      }
      p[r] = __builtin_amdgcn_exp2f(sc);
    }
    u32 pk[8];
#pragma unroll
    for (int i = 0; i < 8; ++i) pk[i] = pkbf(p[2*i], p[2*i+1]);
    u32 a0 = pk[0], b0 = pk[2]; pl32swap(a0, b0);
    u32 a1 = pk[1], b1 = pk[3]; pl32swap(a1, b1);
    u32 a2 = pk[4], b2 = pk[6]; pl32swap(a2, b2);
    u32 a3 = pk[5], b3 = pk[7]; pl32swap(a3, b3);
    pf0 = __builtin_bit_cast(bf16x8, (u32x4){a0, a1, b0, b1});
    pf1 = __builtin_bit_cast(bf16x8, (u32x4){a2, a3, b2, b3});
  };

  stage(0);
  stage(1);

  for (int t = 0; t < NT; ++t) {
    asm volatile("s_waitcnt vmcnt(4) lgkmcnt(0)" ::: "memory");
    asm volatile("s_barrier" ::: "memory");
    stage(t + 2);
    const char* KsB = (const char*)Ks + (t % 3) * 8192;
    const char* VsB = (const char*)Vs + (t % 3) * 8192;
#pragma unroll
    for (int sub = 0; sub < 2; ++sub) {
      const int kvbase = t * 64 + sub * 32;
      if (kvbase <= q0B) {
        const bool actA = (kvbase <= q0A);
        const char* Kbase = KsB + (sub * 32 + l31) * 128;
        bf16x8 kf[4];
#pragma unroll
        for (int ds = 0; ds < 4; ++ds)
          kf[ds] = *(const bf16x8*)(Kbase + ((((ds << 1) + hi) ^ xorb) << 4));
        f32x16 sA = sinit, sB = sinit;
        __builtin_amdgcn_s_setprio(1);
#pragma unroll
        for (int ds = 0; ds < 4; ++ds)
          sB = __builtin_amdgcn_mfma_f32_32x32x16_bf16(kf[ds], qfB[ds], sB, 0, 0, 0);
        if (actA) {
#pragma unroll
          for (int ds = 0; ds < 4; ++ds)
            sA = __builtin_amdgcn_mfma_f32_32x32x16_bf16(kf[ds], qfA[ds], sA, 0, 0, 0);
        }
        __builtin_amdgcn_s_setprio(0);
        const char* Vb0 = VsB + l31 * 128;
        const char* Vb1 = VsB + (32 + l31) * 128;
        const int c0 = (sub << 2) + hi;
        const int c1 = c0 + 2;
        bf16x8 v00 = *(const bf16x8*)(Vb0 + ((c0 ^ xorb) << 4));
        bf16x8 v01 = *(const bf16x8*)(Vb0 + ((c1 ^ xorb) << 4));
        bf16x8 v10 = *(const bf16x8*)(Vb1 + ((c0 ^ xorb) << 4));
        bf16x8 v11 = *(const bf16x8*)(Vb1 + ((c1 ^ xorb) << 4));
        bf16x8 pB0, pB1;
        softmax_pack(sB, kvbase == q0B, pB0, pB1);
        __builtin_amdgcn_s_setprio(1);
        aB0 = __builtin_amdgcn_mfma_f32_32x32x16_bf16(v00, pB0, aB0, 0, 0, 0);
        aB1 = __builtin_amdgcn_mfma_f32_32x32x16_bf16(v10, pB0, aB1, 0, 0, 0);
        aB0 = __builtin_amdgcn_mfma_f32_32x32x16_bf16(v01, pB1, aB0, 0, 0, 0);
        aB1 = __builtin_amdgcn_mfma_f32_32x32x16_bf16(v11, pB1, aB1, 0, 0, 0);
        lB  = __builtin_amdgcn_mfma_f32_32x32x16_bf16(onesf, pB0, lB, 0, 0, 0);
        lB  = __builtin_amdgcn_mfma_f32_32x32x16_bf16(onesf, pB1, lB, 0, 0, 0);
        __builtin_amdgcn_s_setprio(0);
        if (actA) {
          bf16x8 pA0, pA1;
          softmax_pack(sA, kvbase == q0A, pA0, pA1);
          __builtin_amdgcn_s_setprio(1);
          aA0 = __builtin_amdgcn_mfma_f32_32x32x16_bf16(v00, pA0, aA0, 0, 0, 0);
          aA1 = __builtin_amdgcn_mfma_f32_32x32x16_bf16(v10, pA0, aA1, 0, 0, 0);
          aA0 = __builtin_amdgcn_mfma_f32_32x32x16_bf16(v01, pA1, aA0, 0, 0, 0);
          aA1 = __builtin_amdgcn_mfma_f32_32x32x16_bf16(v11, pA1, aA1, 0, 0, 0);
          lA  = __builtin_amdgcn_mfma_f32_32x32x16_bf16(onesf, pA0, lA, 0, 0, 0);
          lA  = __builtin_amdgcn_mfma_f32_32x32x16_bf16(onesf, pA1, lA, 0, 0, 0);
          __builtin_amdgcn_s_setprio(0);
        }
      }
    }
  }

  asm volatile("s_waitcnt vmcnt(0)" ::: "memory");

  auto epi = [&](const f32x16 &a0, const f32x16 &a1, float denom, int q0) {
    const float rl = 1.f / denom;
    const int64_t row = (int64_t)(b * S_ + q0 + l31);
#pragma unroll
    for (int dt = 0; dt < 2; ++dt) {
#pragma unroll
      for (int g = 0; g < 4; ++g) {
        bf16x4 ov;
#pragma unroll
        for (int j = 0; j < 4; ++j) {
          float val = (dt ? a1[4*g + j] : a0[4*g + j]) * rl;
          ov[j] = (bf16_t)val;
        }
        const int d0 = dt * 32 + g * 8 + hi * 4;
        *(bf16x4*)(AO + row * D_ + h * HD_ + d0) = ov;
      }
    }
  };
  epi(aA0, aA1, lA[0], q0A);
  epi(aB0, aB1, lB[0], q0B);
}

// ---------------- launcher ----------------
extern "C" void kernel_launch(void* const* d_in, const int* in_sizes, int n_in,
                              void* d_out, int out_size, void* d_ws, size_t ws_size,
                              hipStream_t stream) {
  const float* x    = (const float*)d_in[0];
  const float* cosb = (const float*)d_in[1];
  const float* sinb = (const float*)d_in[2];
  const float* Wq   = (const float*)d_in[3];
  const float* Wk   = (const float*)d_in[4];
  const float* Wv   = (const float*)d_in[5];
  const float* Wo   = (const float*)d_in[6];
  float* out = (float*)d_out;

  bf16_t* ws = (bf16_t*)d_ws;
  size_t o = 0;
  bf16_t* xb    = ws + o; o += (size_t)4096 * 2048;
  bf16_t* Wqkvt = ws + o; o += (size_t)3072 * 2048;
  bf16_t* Wot   = ws + o; o += (size_t)2048 * 2048;
  bf16_t* qkv   = ws + o; o += (size_t)4096 * 3072;
  bf16_t* Qr    = ws + o; o += (size_t)B_ * H_ * S_ * HD_;
  bf16_t* Krb   = ws + o; o += (size_t)B_ * KV_ * S_ * HD_;
  bf16_t* Vtb   = ws + o; o += (size_t)B_ * KV_ * S_ * HD_;
  bf16_t* AO    = ws + o; o += (size_t)4096 * 2048;

  // fused prep: x->bf16 + all weight transposes
  prep_all<<<18432, dim3(32, 8), 0, stream>>>(x, xb, Wq, Wk, Wv, Wo, Wqkvt, Wot);
  // QKV projection: BN=192 -> 256 blocks = 1/CU, XCD-swizzled
  gemm256<192, 2, bf16_t><<<dim3(3072/192, 4096/256), 512, 0, stream>>>(
      xb, Wqkvt, qkv, 3072, 2048);
  // fused RoPE scatter + V transpose
  scatter_all<<<6144, 256, 0, stream>>>(qkv, cosb, sinb, Qr, Krb, Vtb);
  // paired-chunk attention (best measured variant)
  attn9<<<dim3(16, 32), 256, 0, stream>>>(Qr, Krb, Vtb, AO);
  // output projection -> f32 (BN=128 -> 256 blocks = 1/CU, XCD-swizzled)
  gemm256<128, 0, float><<<dim3(2048/128, 4096/256), 512, 0, stream>>>(
      AO, Wot, out, 2048, 2048);
}